// Round 1
// baseline (2898.893 us; speedup 1.0000x reference)
//
#include <hip/hip_runtime.h>
#include <math.h>

#define D_MODEL 1024
#define D_STATE 16
#define D_CONV  4
#define D_INNER 2048
#define DT_RANK 64
#define BATCH   2
#define SEQLEN  1024
#define MROWS   (BATCH * SEQLEN)   // 2048
#define XDBL_N  (DT_RANK + 2 * D_STATE)  // 96

static __device__ __forceinline__ float sigmoidf_(float x) {
    return 1.f / (1.f + __expf(-x));
}

// ---------------------------------------------------------------------------
// Generic tiled fp32 GEMM: C[M,N] = act(A[M,K] @ W[N,K]^T + bias[N])
// M is always MROWS (2048, multiple of 64). N may not be a multiple of 64.
// FLIPA: read A row (b, t) as (b, L-1-t)  (time-reversed input)
// FLIPC: write C row (b, t) to (b, L-1-t) (flip back the backward direction)
// ACT: 0 = none, 1 = softplus
// ---------------------------------------------------------------------------
template<bool FLIPA, bool FLIPC, int ACT>
__global__ __launch_bounds__(256)
void gemm_kernel(const float* __restrict__ A, int lda,
                 const float* __restrict__ W, int ldw,
                 const float* __restrict__ bias,
                 float* __restrict__ C, int ldc,
                 int N, int K)
{
    constexpr int TS = 64, KS = 16;
    __shared__ float As[KS][TS + 4];
    __shared__ float Ws[KS][TS + 4];
    const int tid = threadIdx.x;
    const int bm = blockIdx.y * TS;
    const int bn = blockIdx.x * TS;
    const int tr = (tid >> 4) << 2;   // 0..60 step 4 (row of 4x4 micro-tile)
    const int tc = (tid & 15) << 2;   // 0..60 step 4 (col)
    const int la_r = tid >> 2;        // 0..63 tile row for loads
    const int la_c = (tid & 3) << 2;  // 0,4,8,12 tile col for loads

    int arow = bm + la_r;
    if (FLIPA) { int b = arow / SEQLEN, t = arow % SEQLEN; arow = b * SEQLEN + (SEQLEN - 1 - t); }
    const int wrow = bn + la_r;
    const bool wok = (wrow < N);

    float acc[4][4] = {};

    for (int k0 = 0; k0 < K; k0 += KS) {
        float4 av = *(const float4*)(A + (size_t)arow * lda + (k0 + la_c));
        float4 wv = make_float4(0.f, 0.f, 0.f, 0.f);
        if (wok) wv = *(const float4*)(W + (size_t)wrow * ldw + (k0 + la_c));
        As[la_c + 0][la_r] = av.x;
        As[la_c + 1][la_r] = av.y;
        As[la_c + 2][la_r] = av.z;
        As[la_c + 3][la_r] = av.w;
        Ws[la_c + 0][la_r] = wv.x;
        Ws[la_c + 1][la_r] = wv.y;
        Ws[la_c + 2][la_r] = wv.z;
        Ws[la_c + 3][la_r] = wv.w;
        __syncthreads();
        #pragma unroll
        for (int k = 0; k < KS; ++k) {
            float a0 = As[k][tr + 0], a1 = As[k][tr + 1], a2 = As[k][tr + 2], a3 = As[k][tr + 3];
            float w0 = Ws[k][tc + 0], w1 = Ws[k][tc + 1], w2 = Ws[k][tc + 2], w3 = Ws[k][tc + 3];
            acc[0][0] += a0 * w0; acc[0][1] += a0 * w1; acc[0][2] += a0 * w2; acc[0][3] += a0 * w3;
            acc[1][0] += a1 * w0; acc[1][1] += a1 * w1; acc[1][2] += a1 * w2; acc[1][3] += a1 * w3;
            acc[2][0] += a2 * w0; acc[2][1] += a2 * w1; acc[2][2] += a2 * w2; acc[2][3] += a2 * w3;
            acc[3][0] += a3 * w0; acc[3][1] += a3 * w1; acc[3][2] += a3 * w2; acc[3][3] += a3 * w3;
        }
        __syncthreads();
    }

    #pragma unroll
    for (int i = 0; i < 4; ++i) {
        int row = bm + tr + i;
        int crow = row;
        if (FLIPC) { int b = row / SEQLEN, t = row % SEQLEN; crow = b * SEQLEN + (SEQLEN - 1 - t); }
        #pragma unroll
        for (int j = 0; j < 4; ++j) {
            int col = bn + tc + j;
            if (col < N) {
                float v = acc[i][j];
                if (bias) v += bias[col];
                if (ACT == 1) v = (v > 20.f) ? v : log1pf(__expf(v));
                C[(size_t)crow * ldc + col] = v;
            }
        }
    }
}

// ---------------------------------------------------------------------------
// Causal depthwise conv (width 4, left zero-pad) + SiLU.
// xz layout (MROWS, 2*D_INNER); xin = cols [0, D_INNER).
// u layout (MROWS, D_INNER).
// ---------------------------------------------------------------------------
__global__ __launch_bounds__(256)
void conv_silu_kernel(const float* __restrict__ xz,
                      const float* __restrict__ convw,
                      const float* __restrict__ convb,
                      float* __restrict__ u)
{
    int idx = blockIdx.x * 256 + threadIdx.x;   // over MROWS * D_INNER
    int d = idx % D_INNER;
    int r = idx / D_INNER;                      // b*L + t
    int t = r % SEQLEN;
    float acc = convb[d];
    #pragma unroll
    for (int k = 0; k < D_CONV; ++k) {
        int back = D_CONV - 1 - k;              // 3,2,1,0
        if (t - back >= 0)
            acc += xz[(size_t)(r - back) * (2 * D_INNER) + d] * convw[d * D_CONV + k];
    }
    u[(size_t)r * D_INNER + d] = acc * sigmoidf_(acc);
}

// ---------------------------------------------------------------------------
// Selective scan. 16 lanes per channel (one lane per state n).
// Each block: 256 threads = 16 channels. Grid: BATCH*D_INNER/16 = 256 blocks.
// Fuses the output gate y *= silu(z) (z = xz cols [D_INNER, 2*D_INNER)).
// ---------------------------------------------------------------------------
__global__ __launch_bounds__(256)
void scan_kernel(const float* __restrict__ u,      // (MROWS, D_INNER)
                 const float* __restrict__ delta,  // (MROWS, D_INNER)
                 const float* __restrict__ xdbl,   // (MROWS, 96): dt|B|C
                 const float* __restrict__ Alog,   // (D_INNER, D_STATE)
                 const float* __restrict__ Dsk,    // (D_INNER,)
                 const float* __restrict__ xz,     // (MROWS, 2*D_INNER) for z
                 float* __restrict__ yz)           // (MROWS, D_INNER)
{
    const int tid = threadIdx.x;
    const int ch = blockIdx.x * 16 + (tid >> 4);  // 0..4095
    const int n  = tid & 15;
    const int b  = ch / D_INNER;
    const int d  = ch % D_INNER;

    const float Av = -__expf(Alog[d * D_STATE + n]);
    const float Dv = Dsk[d];
    float h = 0.f;

    for (int t = 0; t < SEQLEN; ++t) {
        const size_t r = (size_t)b * SEQLEN + t;
        float dlt = delta[r * D_INNER + d];
        float uu  = u[r * D_INNER + d];
        float Bv  = xdbl[r * XDBL_N + DT_RANK + n];
        float Cv  = xdbl[r * XDBL_N + DT_RANK + D_STATE + n];
        float dA  = __expf(dlt * Av);
        h = h * dA + (dlt * uu) * Bv;
        float p = h * Cv;
        p += __shfl_xor(p, 1, 16);
        p += __shfl_xor(p, 2, 16);
        p += __shfl_xor(p, 4, 16);
        p += __shfl_xor(p, 8, 16);
        if (n == 0) {
            float zv = xz[r * (2 * D_INNER) + D_INNER + d];
            yz[r * D_INNER + d] = (p + uu * Dv) * (zv * sigmoidf_(zv));
        }
    }
}

// ---------------------------------------------------------------------------
extern "C" void kernel_launch(void* const* d_in, const int* in_sizes, int n_in,
                              void* d_out, int out_size, void* d_ws, size_t ws_size,
                              hipStream_t stream)
{
    const float* x = (const float*)d_in[0];
    const float* proj_W = (const float*)d_in[23];
    const float* proj_b = (const float*)d_in[24];

    // workspace layout (floats)
    float* xz    = (float*)d_ws;                           // MROWS * 2*D_INNER
    float* u     = xz    + (size_t)MROWS * 2 * D_INNER;    // MROWS * D_INNER
    float* xdbl  = u     + (size_t)MROWS * D_INNER;        // MROWS * 96
    float* delta = xdbl  + (size_t)MROWS * XDBL_N;         // MROWS * D_INNER
    float* yz    = delta + (size_t)MROWS * D_INNER;        // MROWS * D_INNER
    float* tmp   = yz    + (size_t)MROWS * D_INNER;        // MROWS * 2*D_MODEL
    float* out   = (float*)d_out;

    dim3 blk(256);

    for (int dir = 0; dir < 2; ++dir) {
        const int base = 1 + dir * 11;
        const float* Win   = (const float*)d_in[base + 0];
        const float* bin_  = (const float*)d_in[base + 1];
        const float* convw = (const float*)d_in[base + 2];
        const float* convb = (const float*)d_in[base + 3];
        const float* Wx    = (const float*)d_in[base + 4];
        const float* Wdt   = (const float*)d_in[base + 5];
        const float* bdt   = (const float*)d_in[base + 6];
        const float* Alog  = (const float*)d_in[base + 7];
        const float* Dsk   = (const float*)d_in[base + 8];
        const float* Wout  = (const float*)d_in[base + 9];
        const float* bout  = (const float*)d_in[base + 10];

        // 1. xz = (flip?) x @ Win^T + bin : (2048, 4096)
        if (dir == 0)
            gemm_kernel<false, false, 0><<<dim3(4096 / 64, MROWS / 64), blk, 0, stream>>>(
                x, D_MODEL, Win, D_MODEL, bin_, xz, 2 * D_INNER, 2 * D_INNER, D_MODEL);
        else
            gemm_kernel<true, false, 0><<<dim3(4096 / 64, MROWS / 64), blk, 0, stream>>>(
                x, D_MODEL, Win, D_MODEL, bin_, xz, 2 * D_INNER, 2 * D_INNER, D_MODEL);

        // 2. u = silu(causal_conv(xin) + convb) : (2048, 2048)
        conv_silu_kernel<<<(MROWS * D_INNER) / 256, blk, 0, stream>>>(xz, convw, convb, u);

        // 3. xdbl = u @ Wx^T : (2048, 96)
        gemm_kernel<false, false, 0><<<dim3(2, MROWS / 64), blk, 0, stream>>>(
            u, D_INNER, Wx, D_INNER, nullptr, xdbl, XDBL_N, XDBL_N, D_INNER);

        // 4. delta = softplus(dt @ Wdt^T + bdt) : (2048, 2048); dt = xdbl[:, :64]
        gemm_kernel<false, false, 1><<<dim3(D_INNER / 64, MROWS / 64), blk, 0, stream>>>(
            xdbl, XDBL_N, Wdt, DT_RANK, bdt, delta, D_INNER, D_INNER, DT_RANK);

        // 5. selective scan + gate: yz : (2048, 2048)
        scan_kernel<<<(BATCH * D_INNER) / 16, blk, 0, stream>>>(
            u, delta, xdbl, Alog, Dsk, xz, yz);

        // 6. tmp[:, dir*1024 : ] = (flip-back?) yz @ Wout^T + bout : (2048, 1024)
        if (dir == 0)
            gemm_kernel<false, false, 0><<<dim3(D_MODEL / 64, MROWS / 64), blk, 0, stream>>>(
                yz, D_INNER, Wout, D_INNER, bout, tmp, 2 * D_MODEL, D_MODEL, D_INNER);
        else
            gemm_kernel<false, true, 0><<<dim3(D_MODEL / 64, MROWS / 64), blk, 0, stream>>>(
                yz, D_INNER, Wout, D_INNER, bout, tmp + D_MODEL, 2 * D_MODEL, D_MODEL, D_INNER);
    }

    // 7. out = tmp @ proj_W^T + proj_b : (2048, 1024)
    gemm_kernel<false, false, 0><<<dim3(D_MODEL / 64, MROWS / 64), blk, 0, stream>>>(
        tmp, 2 * D_MODEL, proj_W, 2 * D_MODEL, proj_b, out, D_MODEL, D_MODEL, 2 * D_MODEL);
}

// Round 2
// 1690.195 us; speedup vs baseline: 1.7151x; 1.7151x over previous
//
#include <hip/hip_runtime.h>
#include <math.h>

#define D_MODEL 1024
#define D_STATE 16
#define D_CONV  4
#define D_INNER 2048
#define DT_RANK 64
#define BATCH   2
#define SEQLEN  1024
#define MROWS   (BATCH * SEQLEN)   // 2048
#define XDBL_N  (DT_RANK + 2 * D_STATE)  // 96
#define NCHUNK  8
#define CLEN    (SEQLEN / NCHUNK)  // 128

static __device__ __forceinline__ float sigmoidf_(float x) {
    return 1.f / (1.f + __expf(-x));
}

// ---------------------------------------------------------------------------
// Generic tiled fp32 GEMM: C[M,N] = act(A[M,K] @ W[N,K]^T + bias[N])
// ---------------------------------------------------------------------------
template<bool FLIPA, bool FLIPC, int ACT>
__global__ __launch_bounds__(256)
void gemm_kernel(const float* __restrict__ A, int lda,
                 const float* __restrict__ W, int ldw,
                 const float* __restrict__ bias,
                 float* __restrict__ C, int ldc,
                 int N, int K)
{
    constexpr int TS = 64, KS = 16;
    __shared__ float As[KS][TS + 4];
    __shared__ float Ws[KS][TS + 4];
    const int tid = threadIdx.x;
    const int bm = blockIdx.y * TS;
    const int bn = blockIdx.x * TS;
    const int tr = (tid >> 4) << 2;
    const int tc = (tid & 15) << 2;
    const int la_r = tid >> 2;
    const int la_c = (tid & 3) << 2;

    int arow = bm + la_r;
    if (FLIPA) { int b = arow / SEQLEN, t = arow % SEQLEN; arow = b * SEQLEN + (SEQLEN - 1 - t); }
    const int wrow = bn + la_r;
    const bool wok = (wrow < N);

    float acc[4][4] = {};

    for (int k0 = 0; k0 < K; k0 += KS) {
        float4 av = *(const float4*)(A + (size_t)arow * lda + (k0 + la_c));
        float4 wv = make_float4(0.f, 0.f, 0.f, 0.f);
        if (wok) wv = *(const float4*)(W + (size_t)wrow * ldw + (k0 + la_c));
        As[la_c + 0][la_r] = av.x;
        As[la_c + 1][la_r] = av.y;
        As[la_c + 2][la_r] = av.z;
        As[la_c + 3][la_r] = av.w;
        Ws[la_c + 0][la_r] = wv.x;
        Ws[la_c + 1][la_r] = wv.y;
        Ws[la_c + 2][la_r] = wv.z;
        Ws[la_c + 3][la_r] = wv.w;
        __syncthreads();
        #pragma unroll
        for (int k = 0; k < KS; ++k) {
            float a0 = As[k][tr + 0], a1 = As[k][tr + 1], a2 = As[k][tr + 2], a3 = As[k][tr + 3];
            float w0 = Ws[k][tc + 0], w1 = Ws[k][tc + 1], w2 = Ws[k][tc + 2], w3 = Ws[k][tc + 3];
            acc[0][0] += a0 * w0; acc[0][1] += a0 * w1; acc[0][2] += a0 * w2; acc[0][3] += a0 * w3;
            acc[1][0] += a1 * w0; acc[1][1] += a1 * w1; acc[1][2] += a1 * w2; acc[1][3] += a1 * w3;
            acc[2][0] += a2 * w0; acc[2][1] += a2 * w1; acc[2][2] += a2 * w2; acc[2][3] += a2 * w3;
            acc[3][0] += a3 * w0; acc[3][1] += a3 * w1; acc[3][2] += a3 * w2; acc[3][3] += a3 * w3;
        }
        __syncthreads();
    }

    #pragma unroll
    for (int i = 0; i < 4; ++i) {
        int row = bm + tr + i;
        int crow = row;
        if (FLIPC) { int b = row / SEQLEN, t = row % SEQLEN; crow = b * SEQLEN + (SEQLEN - 1 - t); }
        #pragma unroll
        for (int j = 0; j < 4; ++j) {
            int col = bn + tc + j;
            if (col < N) {
                float v = acc[i][j];
                if (bias) v += bias[col];
                if (ACT == 1) v = (v > 20.f) ? v : log1pf(__expf(v));
                C[(size_t)crow * ldc + col] = v;
            }
        }
    }
}

// ---------------------------------------------------------------------------
// Causal depthwise conv (width 4, left zero-pad) + SiLU.
// ---------------------------------------------------------------------------
__global__ __launch_bounds__(256)
void conv_silu_kernel(const float* __restrict__ xz,
                      const float* __restrict__ convw,
                      const float* __restrict__ convb,
                      float* __restrict__ u)
{
    int idx = blockIdx.x * 256 + threadIdx.x;
    int d = idx % D_INNER;
    int r = idx / D_INNER;
    int t = r % SEQLEN;
    float acc = convb[d];
    #pragma unroll
    for (int k = 0; k < D_CONV; ++k) {
        int back = D_CONV - 1 - k;
        if (t - back >= 0)
            acc += xz[(size_t)(r - back) * (2 * D_INNER) + d] * convw[d * D_CONV + k];
    }
    u[(size_t)r * D_INNER + d] = acc * sigmoidf_(acc);
}

// ---------------------------------------------------------------------------
// Chunked selective scan.
// Thread = (b, d, n); 16 lanes per channel (n in lanes). NCHUNK chunks in
// blockIdx.y give NCHUNK x parallelism -> full occupancy.
//
// Phase 1: per chunk, local scan with h_in = 0. Emit (prod dA, h_local_end).
// Phase 2: per (b,d,n), 8-step serial combine -> h_in per chunk.
// Phase 3: re-run chunk recurrence from true h_in (identical FMA sequence to
//          the monolithic scan), reduce y over n, fuse SiLU(z) gate.
// ---------------------------------------------------------------------------
__global__ __launch_bounds__(256)
void scan_phase1(const float* __restrict__ delta,
                 const float* __restrict__ u,
                 const float* __restrict__ xdbl,
                 const float* __restrict__ Alog,
                 float* __restrict__ aprod,
                 float* __restrict__ hfin)
{
    const int tid = threadIdx.x;
    const int ch = blockIdx.x * 16 + (tid >> 4);  // 0..4095
    const int n  = tid & 15;
    const int chunk = blockIdx.y;
    const int b = ch / D_INNER;
    const int d = ch % D_INNER;

    const float Av = -__expf(Alog[d * D_STATE + n]);
    float h = 0.f, ap = 1.f;
    const int t0 = chunk * CLEN;

    for (int t = t0; t < t0 + CLEN; ++t) {
        const size_t r = (size_t)b * SEQLEN + t;
        float dlt = delta[r * D_INNER + d];
        float uu  = u[r * D_INNER + d];
        float Bv  = xdbl[r * XDBL_N + DT_RANK + n];
        float dA  = __expf(dlt * Av);
        h = h * dA + (dlt * uu) * Bv;
        ap *= dA;
    }
    const size_t idx = ((size_t)ch * D_STATE + n) * NCHUNK + chunk;
    aprod[idx] = ap;
    hfin[idx]  = h;
}

__global__ __launch_bounds__(256)
void scan_phase2(const float* __restrict__ aprod,
                 const float* __restrict__ hfin,
                 float* __restrict__ hin)
{
    const int gid = blockIdx.x * 256 + threadIdx.x;   // 0..65535
    const size_t base = (size_t)gid * NCHUNK;
    float h = 0.f;
    #pragma unroll
    for (int c = 0; c < NCHUNK; ++c) {
        hin[base + c] = h;
        h = aprod[base + c] * h + hfin[base + c];
    }
}

__global__ __launch_bounds__(256)
void scan_phase3(const float* __restrict__ delta,
                 const float* __restrict__ u,
                 const float* __restrict__ xdbl,
                 const float* __restrict__ Alog,
                 const float* __restrict__ Dsk,
                 const float* __restrict__ xz,
                 const float* __restrict__ hin,
                 float* __restrict__ yz)
{
    const int tid = threadIdx.x;
    const int ch = blockIdx.x * 16 + (tid >> 4);
    const int n  = tid & 15;
    const int chunk = blockIdx.y;
    const int b = ch / D_INNER;
    const int d = ch % D_INNER;

    const float Av = -__expf(Alog[d * D_STATE + n]);
    const float Dv = Dsk[d];
    float h = hin[((size_t)ch * D_STATE + n) * NCHUNK + chunk];
    const int t0 = chunk * CLEN;

    for (int t = t0; t < t0 + CLEN; ++t) {
        const size_t r = (size_t)b * SEQLEN + t;
        float dlt = delta[r * D_INNER + d];
        float uu  = u[r * D_INNER + d];
        float Bv  = xdbl[r * XDBL_N + DT_RANK + n];
        float Cv  = xdbl[r * XDBL_N + DT_RANK + D_STATE + n];
        float dA  = __expf(dlt * Av);
        h = h * dA + (dlt * uu) * Bv;
        float p = h * Cv;
        p += __shfl_xor(p, 1, 16);
        p += __shfl_xor(p, 2, 16);
        p += __shfl_xor(p, 4, 16);
        p += __shfl_xor(p, 8, 16);
        if (n == 0) {
            float zv = xz[r * (2 * D_INNER) + D_INNER + d];
            yz[r * D_INNER + d] = (p + uu * Dv) * (zv * sigmoidf_(zv));
        }
    }
}

// ---------------------------------------------------------------------------
extern "C" void kernel_launch(void* const* d_in, const int* in_sizes, int n_in,
                              void* d_out, int out_size, void* d_ws, size_t ws_size,
                              hipStream_t stream)
{
    const float* x = (const float*)d_in[0];
    const float* proj_W = (const float*)d_in[23];
    const float* proj_b = (const float*)d_in[24];

    // workspace layout (floats)
    float* xz    = (float*)d_ws;                           // MROWS * 2*D_INNER
    float* u     = xz    + (size_t)MROWS * 2 * D_INNER;    // MROWS * D_INNER
    float* xdbl  = u     + (size_t)MROWS * D_INNER;        // MROWS * 96
    float* delta = xdbl  + (size_t)MROWS * XDBL_N;         // MROWS * D_INNER
    float* yz    = delta + (size_t)MROWS * D_INNER;        // MROWS * D_INNER
    float* tmp   = yz    + (size_t)MROWS * D_INNER;        // MROWS * 2*D_MODEL
    float* aprod = tmp   + (size_t)MROWS * 2 * D_MODEL;    // B*Di*N*NCHUNK
    float* hfin  = aprod + (size_t)BATCH * D_INNER * D_STATE * NCHUNK;
    float* hin   = hfin  + (size_t)BATCH * D_INNER * D_STATE * NCHUNK;
    float* out   = (float*)d_out;

    dim3 blk(256);
    const dim3 scan_grid(BATCH * D_INNER / 16, NCHUNK);

    for (int dir = 0; dir < 2; ++dir) {
        const int base = 1 + dir * 11;
        const float* Win   = (const float*)d_in[base + 0];
        const float* bin_  = (const float*)d_in[base + 1];
        const float* convw = (const float*)d_in[base + 2];
        const float* convb = (const float*)d_in[base + 3];
        const float* Wx    = (const float*)d_in[base + 4];
        const float* Wdt   = (const float*)d_in[base + 5];
        const float* bdt   = (const float*)d_in[base + 6];
        const float* Alog  = (const float*)d_in[base + 7];
        const float* Dsk   = (const float*)d_in[base + 8];
        const float* Wout  = (const float*)d_in[base + 9];
        const float* bout  = (const float*)d_in[base + 10];

        // 1. xz = (flip?) x @ Win^T + bin : (2048, 4096)
        if (dir == 0)
            gemm_kernel<false, false, 0><<<dim3(4096 / 64, MROWS / 64), blk, 0, stream>>>(
                x, D_MODEL, Win, D_MODEL, bin_, xz, 2 * D_INNER, 2 * D_INNER, D_MODEL);
        else
            gemm_kernel<true, false, 0><<<dim3(4096 / 64, MROWS / 64), blk, 0, stream>>>(
                x, D_MODEL, Win, D_MODEL, bin_, xz, 2 * D_INNER, 2 * D_INNER, D_MODEL);

        // 2. u = silu(causal_conv(xin) + convb) : (2048, 2048)
        conv_silu_kernel<<<(MROWS * D_INNER) / 256, blk, 0, stream>>>(xz, convw, convb, u);

        // 3. xdbl = u @ Wx^T : (2048, 96)
        gemm_kernel<false, false, 0><<<dim3(2, MROWS / 64), blk, 0, stream>>>(
            u, D_INNER, Wx, D_INNER, nullptr, xdbl, XDBL_N, XDBL_N, D_INNER);

        // 4. delta = softplus(dt @ Wdt^T + bdt) : (2048, 2048)
        gemm_kernel<false, false, 1><<<dim3(D_INNER / 64, MROWS / 64), blk, 0, stream>>>(
            xdbl, XDBL_N, Wdt, DT_RANK, bdt, delta, D_INNER, D_INNER, DT_RANK);

        // 5. chunked selective scan + gate: yz : (2048, 2048)
        scan_phase1<<<scan_grid, blk, 0, stream>>>(delta, u, xdbl, Alog, aprod, hfin);
        scan_phase2<<<BATCH * D_INNER * D_STATE / 256, blk, 0, stream>>>(aprod, hfin, hin);
        scan_phase3<<<scan_grid, blk, 0, stream>>>(delta, u, xdbl, Alog, Dsk, xz, hin, yz);

        // 6. tmp[:, dir*1024 :] = (flip-back?) yz @ Wout^T + bout : (2048, 1024)
        if (dir == 0)
            gemm_kernel<false, false, 0><<<dim3(D_MODEL / 64, MROWS / 64), blk, 0, stream>>>(
                yz, D_INNER, Wout, D_INNER, bout, tmp, 2 * D_MODEL, D_MODEL, D_INNER);
        else
            gemm_kernel<false, true, 0><<<dim3(D_MODEL / 64, MROWS / 64), blk, 0, stream>>>(
                yz, D_INNER, Wout, D_INNER, bout, tmp + D_MODEL, 2 * D_MODEL, D_MODEL, D_INNER);
    }

    // 7. out = tmp @ proj_W^T + proj_b : (2048, 1024)
    gemm_kernel<false, false, 0><<<dim3(D_MODEL / 64, MROWS / 64), blk, 0, stream>>>(
        tmp, 2 * D_MODEL, proj_W, 2 * D_MODEL, proj_b, out, D_MODEL, D_MODEL, 2 * D_MODEL);
}

// Round 3
// 1137.056 us; speedup vs baseline: 2.5495x; 1.4865x over previous
//
#include <hip/hip_runtime.h>
#include <math.h>

#define D_MODEL 1024
#define D_STATE 16
#define D_CONV  4
#define D_INNER 2048
#define DT_RANK 64
#define BATCH   2
#define SEQLEN  1024
#define MROWS   2048
#define XDBL_LD 128              // padded (dt:64 | B:16 | C:16 | pad:32)
#define NCHUNK  8
#define CLEN    (SEQLEN / NCHUNK)

typedef __attribute__((ext_vector_type(8))) short bf16x8;
typedef __attribute__((ext_vector_type(4))) float f32x4;

static __device__ __forceinline__ float sigmoidf_(float x) {
    return 1.f / (1.f + __expf(-x));
}
static __device__ __forceinline__ unsigned short bf16rn(float f) {
    unsigned u = __float_as_uint(f);
    return (unsigned short)((u + 0x7FFFu + ((u >> 16) & 1u)) >> 16);
}

// ---------------------------------------------------------------------------
// fp32 (R x C, ldin) -> bf16 (Rout x 2C): cols [0,C)=hi, [C,2C)=lo.
// Rows >= R are zero-filled (used to pad Wx from 96 to 128 rows).
// FLIP: read time-reversed rows (row = b*1024 + t -> b*1024 + 1023-t).
// ---------------------------------------------------------------------------
template<bool FLIP>
__global__ __launch_bounds__(256)
void split_hl_kernel(const float* __restrict__ in, int R, int C, int ldin,
                     unsigned short* __restrict__ out, int Rout)
{
    int q = blockIdx.x * 256 + threadIdx.x;
    int qpr = C >> 2;
    int row = q / qpr;
    int c4 = (q - row * qpr) << 2;
    if (row >= Rout) return;
    unsigned short h[4] = {0, 0, 0, 0}, l[4] = {0, 0, 0, 0};
    if (row < R) {
        int sr = row;
        if (FLIP) { int b = row >> 10, t = row & 1023; sr = (b << 10) + (1023 - t); }
        float4 v = *(const float4*)(in + (size_t)sr * ldin + c4);
        float f[4] = {v.x, v.y, v.z, v.w};
        #pragma unroll
        for (int i = 0; i < 4; ++i) {
            h[i] = bf16rn(f[i]);
            float hf = __uint_as_float((unsigned)h[i] << 16);
            l[i] = bf16rn(f[i] - hf);
        }
    }
    size_t ob = (size_t)row * (2 * C);
    *(ushort4*)(out + ob + c4)     = make_ushort4(h[0], h[1], h[2], h[3]);
    *(ushort4*)(out + ob + C + c4) = make_ushort4(l[0], l[1], l[2], l[3]);
}

// ---------------------------------------------------------------------------
// bf16x3 MFMA GEMM: C[M=2048,N] = act(sum_seg A_seg @ W_seg^T + bias)
// A: [2048][2K] bf16 (hi|lo), W: [N][2K] bf16 (hi|lo).
// Segments: (Ahi,Whi), (Alo,Whi), (Ahi,Wlo)  == fp32-accurate product.
// 128x128 tile, BK=32, 4 waves (2x2, 64x64 each, 4x4 16x16x32 frags).
// Staging: global_load_lds dwordx4, pre-swizzled global source so linear
// LDS writes land XOR-swizzled; ds_read_b128 conflict-free.
// ---------------------------------------------------------------------------
template<bool FLIPC, int ACT>
__global__ __launch_bounds__(256)
void gemm_mfma(const unsigned short* __restrict__ A,
               const unsigned short* __restrict__ W,
               const float* __restrict__ bias,
               float* __restrict__ C, int ldc,
               int N, int K)
{
    __shared__ __align__(16) unsigned short As[128 * 32];
    __shared__ __align__(16) unsigned short Bs[128 * 32];

    const int tid = threadIdx.x;
    const int lane = tid & 63;
    const int wid = tid >> 6;

    // XCD-aware block swizzle (all grids are multiples of 8 blocks)
    const int nbx = gridDim.x;
    const int nwg = nbx * gridDim.y;
    int bid = blockIdx.y * nbx + blockIdx.x;
    int q8 = nwg >> 3;
    int swz = (bid & 7) * q8 + (bid >> 3);
    const int bm = (swz / nbx) * 128;
    const int bn = (swz % nbx) * 128;

    const int ldg = 2 * K;

    f32x4 acc[4][4];
    #pragma unroll
    for (int i = 0; i < 4; ++i)
        #pragma unroll
        for (int j = 0; j < 4; ++j) {
            f32x4 z = {0.f, 0.f, 0.f, 0.f};
            acc[i][j] = z;
        }

    // staging: 2 issues per operand; issue j covers linear 16B-slots
    // s = j*256 + tid; local row = s>>2, lds kslot = s&3,
    // global kslot = (s&3) ^ ((row>>1)&3)  (pre-swizzled source)
    const int r0 = tid >> 2;            // issue 0: rows 0..63
    const int k0s = (tid & 3) ^ ((r0 >> 1) & 3);
    const int r1 = (256 + tid) >> 2;    // issue 1: rows 64..127
    const int k1s = (tid & 3) ^ ((r1 >> 1) & 3);

    unsigned short* As_w0 = &As[(wid << 6) * 8];
    unsigned short* As_w1 = &As[(256 + (wid << 6)) * 8];
    unsigned short* Bs_w0 = &Bs[(wid << 6) * 8];
    unsigned short* Bs_w1 = &Bs[(256 + (wid << 6)) * 8];

    const int wm = (wid >> 1) * 64;
    const int wn = (wid & 1) * 64;
    const int fr = lane & 15;
    const int fs = lane >> 4;

    const int KS = K >> 5;
    #pragma unroll 1
    for (int seg = 0; seg < 3; ++seg) {
        const int aoff = (seg == 1) ? K : 0;
        const int boff = (seg == 2) ? K : 0;
        #pragma unroll 1
        for (int kt = 0; kt < KS; ++kt) {
            const int kk = kt << 5;
            const unsigned short* ga0 = A + (size_t)(bm + r0) * ldg + aoff + kk + k0s * 8;
            const unsigned short* ga1 = A + (size_t)(bm + r1) * ldg + aoff + kk + k1s * 8;
            const unsigned short* gw0 = W + (size_t)(bn + r0) * ldg + boff + kk + k0s * 8;
            const unsigned short* gw1 = W + (size_t)(bn + r1) * ldg + boff + kk + k1s * 8;
            __builtin_amdgcn_global_load_lds(
                (const __attribute__((address_space(1))) void*)ga0,
                (__attribute__((address_space(3))) void*)As_w0, 16, 0, 0);
            __builtin_amdgcn_global_load_lds(
                (const __attribute__((address_space(1))) void*)ga1,
                (__attribute__((address_space(3))) void*)As_w1, 16, 0, 0);
            __builtin_amdgcn_global_load_lds(
                (const __attribute__((address_space(1))) void*)gw0,
                (__attribute__((address_space(3))) void*)Bs_w0, 16, 0, 0);
            __builtin_amdgcn_global_load_lds(
                (const __attribute__((address_space(1))) void*)gw1,
                (__attribute__((address_space(3))) void*)Bs_w1, 16, 0, 0);
            __syncthreads();   // drains vmcnt -> tiles resident

            bf16x8 aF[4], bF[4];
            #pragma unroll
            for (int f = 0; f < 4; ++f) {
                int ra = wm + f * 16 + fr;
                int sa = fs ^ ((ra >> 1) & 3);
                aF[f] = *(const bf16x8*)&As[ra * 32 + sa * 8];
                int rb = wn + f * 16 + fr;
                int sb = fs ^ ((rb >> 1) & 3);
                bF[f] = *(const bf16x8*)&Bs[rb * 32 + sb * 8];
            }
            #pragma unroll
            for (int i = 0; i < 4; ++i)
                #pragma unroll
                for (int j = 0; j < 4; ++j)
                    acc[i][j] = __builtin_amdgcn_mfma_f32_16x16x32_bf16(
                        aF[i], bF[j], acc[i][j], 0, 0, 0);
            __syncthreads();   // all reads done before next stage
        }
    }

    // epilogue: C/D frag layout col = lane&15, row = (lane>>4)*4 + reg
    #pragma unroll
    for (int i = 0; i < 4; ++i) {
        #pragma unroll
        for (int j = 0; j < 4; ++j) {
            int coln = bn + wn + j * 16 + fr;
            float bv = bias ? bias[coln] : 0.f;
            #pragma unroll
            for (int r = 0; r < 4; ++r) {
                int rowm = bm + wm + i * 16 + fs * 4 + r;
                float v = acc[i][j][r] + bv;
                if (ACT == 1) v = (v > 20.f) ? v : log1pf(__expf(v));
                int crow = rowm;
                if (FLIPC) { int b = rowm >> 10, t = rowm & 1023; crow = (b << 10) + 1023 - t; }
                C[(size_t)crow * ldc + coln] = v;
            }
        }
    }
}

// ---------------------------------------------------------------------------
// Causal depthwise conv (width 4) + SiLU.
// ---------------------------------------------------------------------------
__global__ __launch_bounds__(256)
void conv_silu_kernel(const float* __restrict__ xz,
                      const float* __restrict__ convw,
                      const float* __restrict__ convb,
                      float* __restrict__ u)
{
    int idx = blockIdx.x * 256 + threadIdx.x;
    int d = idx % D_INNER;
    int r = idx / D_INNER;
    int t = r % SEQLEN;
    float acc = convb[d];
    #pragma unroll
    for (int k = 0; k < D_CONV; ++k) {
        int back = D_CONV - 1 - k;
        if (t - back >= 0)
            acc += xz[(size_t)(r - back) * (2 * D_INNER) + d] * convw[d * D_CONV + k];
    }
    u[(size_t)r * D_INNER + d] = acc * sigmoidf_(acc);
}

// ---------------------------------------------------------------------------
// Chunked selective scan (3 phases), xdbl has ld = XDBL_LD (dt|B|C|pad).
// ---------------------------------------------------------------------------
__global__ __launch_bounds__(256)
void scan_phase1(const float* __restrict__ delta,
                 const float* __restrict__ u,
                 const float* __restrict__ xdbl,
                 const float* __restrict__ Alog,
                 float* __restrict__ aprod,
                 float* __restrict__ hfin)
{
    const int tid = threadIdx.x;
    const int ch = blockIdx.x * 16 + (tid >> 4);
    const int n = tid & 15;
    const int chunk = blockIdx.y;
    const int b = ch / D_INNER;
    const int d = ch % D_INNER;

    const float Av = -__expf(Alog[d * D_STATE + n]);
    float h = 0.f, ap = 1.f;
    const int t0 = chunk * CLEN;
    for (int t = t0; t < t0 + CLEN; ++t) {
        const size_t r = (size_t)b * SEQLEN + t;
        float dlt = delta[r * D_INNER + d];
        float uu = u[r * D_INNER + d];
        float Bv = xdbl[r * XDBL_LD + DT_RANK + n];
        float dA = __expf(dlt * Av);
        h = h * dA + (dlt * uu) * Bv;
        ap *= dA;
    }
    const size_t idx = ((size_t)ch * D_STATE + n) * NCHUNK + chunk;
    aprod[idx] = ap;
    hfin[idx] = h;
}

__global__ __launch_bounds__(256)
void scan_phase2(const float* __restrict__ aprod,
                 const float* __restrict__ hfin,
                 float* __restrict__ hin)
{
    const int gid = blockIdx.x * 256 + threadIdx.x;
    const size_t base = (size_t)gid * NCHUNK;
    float h = 0.f;
    #pragma unroll
    for (int c = 0; c < NCHUNK; ++c) {
        hin[base + c] = h;
        h = aprod[base + c] * h + hfin[base + c];
    }
}

__global__ __launch_bounds__(256)
void scan_phase3(const float* __restrict__ delta,
                 const float* __restrict__ u,
                 const float* __restrict__ xdbl,
                 const float* __restrict__ Alog,
                 const float* __restrict__ Dsk,
                 const float* __restrict__ xz,
                 const float* __restrict__ hin,
                 float* __restrict__ yz)
{
    const int tid = threadIdx.x;
    const int ch = blockIdx.x * 16 + (tid >> 4);
    const int n = tid & 15;
    const int chunk = blockIdx.y;
    const int b = ch / D_INNER;
    const int d = ch % D_INNER;

    const float Av = -__expf(Alog[d * D_STATE + n]);
    const float Dv = Dsk[d];
    float h = hin[((size_t)ch * D_STATE + n) * NCHUNK + chunk];
    const int t0 = chunk * CLEN;
    for (int t = t0; t < t0 + CLEN; ++t) {
        const size_t r = (size_t)b * SEQLEN + t;
        float dlt = delta[r * D_INNER + d];
        float uu = u[r * D_INNER + d];
        float Bv = xdbl[r * XDBL_LD + DT_RANK + n];
        float Cv = xdbl[r * XDBL_LD + DT_RANK + D_STATE + n];
        float dA = __expf(dlt * Av);
        h = h * dA + (dlt * uu) * Bv;
        float p = h * Cv;
        p += __shfl_xor(p, 1, 16);
        p += __shfl_xor(p, 2, 16);
        p += __shfl_xor(p, 4, 16);
        p += __shfl_xor(p, 8, 16);
        if (n == 0) {
            float zv = xz[r * (2 * D_INNER) + D_INNER + d];
            yz[r * D_INNER + d] = (p + uu * Dv) * (zv * sigmoidf_(zv));
        }
    }
}

// ---------------------------------------------------------------------------
extern "C" void kernel_launch(void* const* d_in, const int* in_sizes, int n_in,
                              void* d_out, int out_size, void* d_ws, size_t ws_size,
                              hipStream_t stream)
{
    const float* x = (const float*)d_in[0];
    const float* proj_W = (const float*)d_in[23];
    const float* proj_b = (const float*)d_in[24];
    float* out = (float*)d_out;

    char* p = (char*)d_ws;
    auto alloc = [&](size_t bytes) { void* r = (void*)p; p += (bytes + 255) & ~(size_t)255; return r; };

    // fp32 buffers
    float* xz    = (float*)alloc(sizeof(float) * MROWS * 2 * D_INNER);   // 32MB (also reused for tmp'/projW')
    float* u     = (float*)alloc(sizeof(float) * MROWS * D_INNER);
    float* xdbl  = (float*)alloc(sizeof(float) * MROWS * XDBL_LD);
    float* delta = (float*)alloc(sizeof(float) * MROWS * D_INNER);       // 16MB (reused for yz')
    float* yz    = (float*)alloc(sizeof(float) * MROWS * D_INNER);
    float* tmp   = (float*)alloc(sizeof(float) * MROWS * 2 * D_MODEL);
    float* aprod = (float*)alloc(sizeof(float) * BATCH * D_INNER * D_STATE * NCHUNK);
    float* hfin  = (float*)alloc(sizeof(float) * BATCH * D_INNER * D_STATE * NCHUNK);
    float* hin   = (float*)alloc(sizeof(float) * BATCH * D_INNER * D_STATE * NCHUNK);

    // bf16 (hi|lo) buffers
    unsigned short* xc0  = (unsigned short*)alloc(2ull * MROWS * 2 * D_MODEL);
    unsigned short* xc1  = (unsigned short*)alloc(2ull * MROWS * 2 * D_MODEL);
    unsigned short* Winb = (unsigned short*)alloc(2ull * 2 * D_INNER * 2 * D_MODEL);
    unsigned short* ub   = (unsigned short*)alloc(2ull * MROWS * 2 * D_INNER);
    unsigned short* Wxb  = (unsigned short*)alloc(2ull * XDBL_LD * 2 * D_INNER);
    unsigned short* dtb  = (unsigned short*)alloc(2ull * MROWS * 2 * DT_RANK);
    unsigned short* Wdtb = (unsigned short*)alloc(2ull * D_INNER * 2 * DT_RANK);
    unsigned short* Woutb= (unsigned short*)alloc(2ull * D_MODEL * 2 * D_INNER);

    // overlays on dead fp32 regions (see lifetimes in launch order)
    unsigned short* yzb  = (unsigned short*)delta;   // yz' after scan: delta dead
    unsigned short* tmpb = (unsigned short*)xz;      // tmp' at end: xz dead
    unsigned short* pWb  = (unsigned short*)(xz + (size_t)MROWS * D_INNER);  // fits in xz's 2nd half

    dim3 blk(256);
    const dim3 scan_grid(BATCH * D_INNER / 16, NCHUNK);

    // x -> hi|lo (both directions, flip folded into conversion)
    split_hl_kernel<false><<<2048, blk, 0, stream>>>(x, MROWS, D_MODEL, D_MODEL, xc0, MROWS);
    split_hl_kernel<true ><<<2048, blk, 0, stream>>>(x, MROWS, D_MODEL, D_MODEL, xc1, MROWS);

    for (int dir = 0; dir < 2; ++dir) {
        const int base = 1 + dir * 11;
        const float* Win   = (const float*)d_in[base + 0];
        const float* bin_  = (const float*)d_in[base + 1];
        const float* convw = (const float*)d_in[base + 2];
        const float* convb = (const float*)d_in[base + 3];
        const float* Wx    = (const float*)d_in[base + 4];
        const float* Wdt   = (const float*)d_in[base + 5];
        const float* bdt   = (const float*)d_in[base + 6];
        const float* Alog  = (const float*)d_in[base + 7];
        const float* Dsk   = (const float*)d_in[base + 8];
        const float* Wout  = (const float*)d_in[base + 9];
        const float* bout  = (const float*)d_in[base + 10];
        const unsigned short* xcd = dir ? xc1 : xc0;

        // 1. input proj: xz = x' @ Win'^T + bin : (2048, 4096)
        split_hl_kernel<false><<<4096, blk, 0, stream>>>(Win, 2 * D_INNER, D_MODEL, D_MODEL, Winb, 2 * D_INNER);
        gemm_mfma<false, 0><<<dim3(32, 16), blk, 0, stream>>>(
            xcd, Winb, bin_, xz, 2 * D_INNER, 2 * D_INNER, D_MODEL);

        // 2. conv + silu
        conv_silu_kernel<<<(MROWS * D_INNER) / 256, blk, 0, stream>>>(xz, convw, convb, u);

        // 3. xdbl = u @ Wx^T (N padded 96->128)
        split_hl_kernel<false><<<4096, blk, 0, stream>>>(u, MROWS, D_INNER, D_INNER, ub, MROWS);
        split_hl_kernel<false><<<256, blk, 0, stream>>>(Wx, DT_RANK + 2 * D_STATE, D_INNER, D_INNER, Wxb, XDBL_LD);
        gemm_mfma<false, 0><<<dim3(1, 16), blk, 0, stream>>>(
            ub, Wxb, nullptr, xdbl, XDBL_LD, XDBL_LD, D_INNER);

        // 4. delta = softplus(dt @ Wdt^T + bdt) : (2048, 2048)
        split_hl_kernel<false><<<128, blk, 0, stream>>>(xdbl, MROWS, DT_RANK, XDBL_LD, dtb, MROWS);
        split_hl_kernel<false><<<128, blk, 0, stream>>>(Wdt, D_INNER, DT_RANK, DT_RANK, Wdtb, D_INNER);
        gemm_mfma<false, 1><<<dim3(16, 16), blk, 0, stream>>>(
            dtb, Wdtb, bdt, delta, D_INNER, D_INNER, DT_RANK);

        // 5. chunked selective scan + gate
        scan_phase1<<<scan_grid, blk, 0, stream>>>(delta, u, xdbl, Alog, aprod, hfin);
        scan_phase2<<<BATCH * D_INNER * D_STATE / 256, blk, 0, stream>>>(aprod, hfin, hin);
        scan_phase3<<<scan_grid, blk, 0, stream>>>(delta, u, xdbl, Alog, Dsk, xz, hin, yz);

        // 6. out proj -> tmp halves (delta dead here; yzb overlays it)
        split_hl_kernel<false><<<4096, blk, 0, stream>>>(yz, MROWS, D_INNER, D_INNER, yzb, MROWS);
        split_hl_kernel<false><<<2048, blk, 0, stream>>>(Wout, D_MODEL, D_INNER, D_INNER, Woutb, D_MODEL);
        if (dir == 0)
            gemm_mfma<false, 0><<<dim3(8, 16), blk, 0, stream>>>(
                yzb, Woutb, bout, tmp, 2 * D_MODEL, D_MODEL, D_INNER);
        else
            gemm_mfma<true, 0><<<dim3(8, 16), blk, 0, stream>>>(
                yzb, Woutb, bout, tmp + D_MODEL, 2 * D_MODEL, D_MODEL, D_INNER);
    }

    // 7. out = tmp @ proj_W^T + proj_b (xz dead; tmpb/pWb overlay it)
    split_hl_kernel<false><<<4096, blk, 0, stream>>>(tmp, MROWS, 2 * D_MODEL, 2 * D_MODEL, tmpb, MROWS);
    split_hl_kernel<false><<<2048, blk, 0, stream>>>(proj_W, D_MODEL, 2 * D_MODEL, 2 * D_MODEL, pWb, D_MODEL);
    gemm_mfma<false, 0><<<dim3(8, 16), blk, 0, stream>>>(
        tmpb, pWb, proj_b, out, D_MODEL, D_MODEL, 2 * D_MODEL);
}

// Round 5
// 760.002 us; speedup vs baseline: 3.8143x; 1.4961x over previous
//
#include <hip/hip_runtime.h>
#include <math.h>

#define D_MODEL 1024
#define D_STATE 16
#define D_CONV  4
#define D_INNER 2048
#define DT_RANK 64
#define BATCH   2
#define SEQLEN  1024
#define MROWS   2048
#define XDBL_LD 128
#define NCHUNK  8
#define CLEN    (SEQLEN / NCHUNK)

typedef __attribute__((ext_vector_type(8))) short bf16x8;
typedef __attribute__((ext_vector_type(4))) float f32x4;

static __device__ __forceinline__ float sigmoidf_(float x) {
    return 1.f / (1.f + __expf(-x));
}
static __device__ __forceinline__ unsigned short bf16rn(float f) {
    unsigned u = __float_as_uint(f);
    return (unsigned short)((u + 0x7FFFu + ((u >> 16) & 1u)) >> 16);
}
static __device__ __forceinline__ void hl_split(float f, unsigned short& h, unsigned short& l) {
    h = bf16rn(f);
    l = bf16rn(f - __uint_as_float((unsigned)h << 16));
}
static __device__ __forceinline__ float us2f(unsigned short u) {
    return __uint_as_float((unsigned)u << 16);
}

// ---------------------------------------------------------------------------
// fp32 (R x C, ldin) -> bf16 (Rout x 2C): cols [0,C)=hi, [C,2C)=lo.
// Rows >= R zero-filled. FLIP: time-reverse source rows.
// ---------------------------------------------------------------------------
template<bool FLIP>
__global__ __launch_bounds__(256)
void split_hl_kernel(const float* __restrict__ in, int R, int C, int ldin,
                     unsigned short* __restrict__ out, int Rout)
{
    int q = blockIdx.x * 256 + threadIdx.x;
    int qpr = C >> 2;
    int row = q / qpr;
    int c4 = (q - row * qpr) << 2;
    if (row >= Rout) return;
    unsigned short h[4] = {0, 0, 0, 0}, l[4] = {0, 0, 0, 0};
    if (row < R) {
        int sr = row;
        if (FLIP) { int b = row >> 10, t = row & 1023; sr = (b << 10) + (1023 - t); }
        float4 v = *(const float4*)(in + (size_t)sr * ldin + c4);
        float f[4] = {v.x, v.y, v.z, v.w};
        #pragma unroll
        for (int i = 0; i < 4; ++i) hl_split(f[i], h[i], l[i]);
    }
    size_t ob = (size_t)row * (2 * C);
    *(ushort4*)(out + ob + c4)     = make_ushort4(h[0], h[1], h[2], h[3]);
    *(ushort4*)(out + ob + C + c4) = make_ushort4(l[0], l[1], l[2], l[3]);
}

// ---------------------------------------------------------------------------
// bf16x3 MFMA GEMM, dual-direction (blockIdx.z/nks picks dir) + split-K.
// A: [2048][2K] (hi|lo), W: [N][2K] (hi|lo). 3 segments = fp32-accurate.
// 128x128 tile, BK=32, 4 waves; global_load_lds w/ pre-swizzled source.
// PART: raw fp32 partial to part[blockIdx.z]; else bias+ACT epilogue to C.
// ---------------------------------------------------------------------------
template<int ACT, bool PART>
__global__ __launch_bounds__(256)
void gemm_mfma(const unsigned short* __restrict__ A0,
               const unsigned short* __restrict__ A1,
               const unsigned short* __restrict__ W0,
               const unsigned short* __restrict__ W1,
               const float* __restrict__ bias0,
               const float* __restrict__ bias1,
               float* __restrict__ C0, float* __restrict__ C1,
               float* __restrict__ part,
               int ldc, int N, int K, int nks)
{
    __shared__ __align__(16) unsigned short As[128 * 32];
    __shared__ __align__(16) unsigned short Bs[128 * 32];

    const int tid = threadIdx.x;
    const int lane = tid & 63;
    const int wid = tid >> 6;

    const int z = blockIdx.z;
    const int dir = z / nks;
    const int ks = z - dir * nks;
    const unsigned short* A = dir ? A1 : A0;
    const unsigned short* W = dir ? W1 : W0;

    const int nbx = gridDim.x;
    const int nwg = nbx * gridDim.y;
    int bid = blockIdx.y * nbx + blockIdx.x;
    int q8 = nwg >> 3;
    int swz = (nwg >= 8) ? (bid & 7) * q8 + (bid >> 3) : bid;
    const int bm = (swz / nbx) * 128;
    const int bn = (swz % nbx) * 128;

    const int ldg = 2 * K;
    const int Kc = K / nks;
    const int kbase = ks * Kc;

    f32x4 acc[4][4];
    #pragma unroll
    for (int i = 0; i < 4; ++i)
        #pragma unroll
        for (int j = 0; j < 4; ++j) {
            f32x4 zv = {0.f, 0.f, 0.f, 0.f};
            acc[i][j] = zv;
        }

    const int r0 = tid >> 2;
    const int k0s = (tid & 3) ^ ((r0 >> 1) & 3);
    const int r1 = (256 + tid) >> 2;
    const int k1s = (tid & 3) ^ ((r1 >> 1) & 3);

    unsigned short* As_w0 = &As[(wid << 6) * 8];
    unsigned short* As_w1 = &As[(256 + (wid << 6)) * 8];
    unsigned short* Bs_w0 = &Bs[(wid << 6) * 8];
    unsigned short* Bs_w1 = &Bs[(256 + (wid << 6)) * 8];

    const int wm = (wid >> 1) * 64;
    const int wn = (wid & 1) * 64;
    const int fr = lane & 15;
    const int fs = lane >> 4;

    const int KS = Kc >> 5;
    #pragma unroll 1
    for (int seg = 0; seg < 3; ++seg) {
        const int aoff = ((seg == 1) ? K : 0) + kbase;
        const int boff = ((seg == 2) ? K : 0) + kbase;
        #pragma unroll 1
        for (int kt = 0; kt < KS; ++kt) {
            const int kk = kt << 5;
            const unsigned short* ga0 = A + (size_t)(bm + r0) * ldg + aoff + kk + k0s * 8;
            const unsigned short* ga1 = A + (size_t)(bm + r1) * ldg + aoff + kk + k1s * 8;
            const unsigned short* gw0 = W + (size_t)(bn + r0) * ldg + boff + kk + k0s * 8;
            const unsigned short* gw1 = W + (size_t)(bn + r1) * ldg + boff + kk + k1s * 8;
            __builtin_amdgcn_global_load_lds(
                (const __attribute__((address_space(1))) void*)ga0,
                (__attribute__((address_space(3))) void*)As_w0, 16, 0, 0);
            __builtin_amdgcn_global_load_lds(
                (const __attribute__((address_space(1))) void*)ga1,
                (__attribute__((address_space(3))) void*)As_w1, 16, 0, 0);
            __builtin_amdgcn_global_load_lds(
                (const __attribute__((address_space(1))) void*)gw0,
                (__attribute__((address_space(3))) void*)Bs_w0, 16, 0, 0);
            __builtin_amdgcn_global_load_lds(
                (const __attribute__((address_space(1))) void*)gw1,
                (__attribute__((address_space(3))) void*)Bs_w1, 16, 0, 0);
            __syncthreads();

            bf16x8 aF[4], bF[4];
            #pragma unroll
            for (int f = 0; f < 4; ++f) {
                int ra = wm + f * 16 + fr;
                int sa = fs ^ ((ra >> 1) & 3);
                aF[f] = *(const bf16x8*)&As[ra * 32 + sa * 8];
                int rb = wn + f * 16 + fr;
                int sb = fs ^ ((rb >> 1) & 3);
                bF[f] = *(const bf16x8*)&Bs[rb * 32 + sb * 8];
            }
            #pragma unroll
            for (int i = 0; i < 4; ++i)
                #pragma unroll
                for (int j = 0; j < 4; ++j)
                    acc[i][j] = __builtin_amdgcn_mfma_f32_16x16x32_bf16(
                        aF[i], bF[j], acc[i][j], 0, 0, 0);
            __syncthreads();
        }
    }

    if (PART) {
        float* P = part + (size_t)z * ((size_t)MROWS * N);
        #pragma unroll
        for (int i = 0; i < 4; ++i)
            #pragma unroll
            for (int j = 0; j < 4; ++j) {
                int coln = bn + wn + j * 16 + fr;
                #pragma unroll
                for (int r = 0; r < 4; ++r) {
                    int rowm = bm + wm + i * 16 + fs * 4 + r;
                    P[(size_t)rowm * N + coln] = acc[i][j][r];
                }
            }
    } else {
        const float* bias = dir ? bias1 : bias0;
        float* C = dir ? C1 : C0;
        #pragma unroll
        for (int i = 0; i < 4; ++i)
            #pragma unroll
            for (int j = 0; j < 4; ++j) {
                int coln = bn + wn + j * 16 + fr;
                float bv = bias ? bias[coln] : 0.f;
                #pragma unroll
                for (int r = 0; r < 4; ++r) {
                    int rowm = bm + wm + i * 16 + fs * 4 + r;
                    float v = acc[i][j][r] + bv;
                    if (ACT == 1) v = (v > 20.f) ? v : log1pf(__expf(v));
                    C[(size_t)rowm * ldc + coln] = v;
                }
            }
    }
}

// ---------------------------------------------------------------------------
// Split-K reduces (deterministic order) with fused epilogues.
// ---------------------------------------------------------------------------
__global__ __launch_bounds__(256)
void reduce_xdbl_k(const float* __restrict__ part,
                   float* __restrict__ xdbl, unsigned short* __restrict__ dtb)
{
    int i = blockIdx.x * 256 + threadIdx.x;
    int row = i >> 5;
    int c4 = (i & 31) << 2;
    float4 s = make_float4(0.f, 0.f, 0.f, 0.f);
    #pragma unroll
    for (int k = 0; k < 16; ++k) {
        float4 v = *(const float4*)(part + (size_t)k * MROWS * XDBL_LD + (size_t)row * XDBL_LD + c4);
        s.x += v.x; s.y += v.y; s.z += v.z; s.w += v.w;
    }
    *(float4*)(xdbl + (size_t)row * XDBL_LD + c4) = s;
    if (c4 < DT_RANK) {
        float f[4] = {s.x, s.y, s.z, s.w};
        unsigned short h[4], l[4];
        #pragma unroll
        for (int j = 0; j < 4; ++j) hl_split(f[j], h[j], l[j]);
        *(ushort4*)(dtb + (size_t)row * (2 * DT_RANK) + c4) = make_ushort4(h[0], h[1], h[2], h[3]);
        *(ushort4*)(dtb + (size_t)row * (2 * DT_RANK) + DT_RANK + c4) = make_ushort4(l[0], l[1], l[2], l[3]);
    }
}

template<bool FLIP>
__global__ __launch_bounds__(256)
void reduce_tmpb_k(const float* __restrict__ part, const float* __restrict__ bias,
                   unsigned short* __restrict__ tmpb, int colofs)
{
    int i = blockIdx.x * 256 + threadIdx.x;
    int row = i >> 8;
    int c4 = (i & 255) << 2;
    float4 a = *(const float4*)(part + (size_t)row * D_MODEL + c4);
    float4 b = *(const float4*)(part + (size_t)MROWS * D_MODEL + (size_t)row * D_MODEL + c4);
    float f[4] = {a.x + b.x + bias[c4], a.y + b.y + bias[c4 + 1],
                  a.z + b.z + bias[c4 + 2], a.w + b.w + bias[c4 + 3]};
    int orow = row;
    if (FLIP) { int bb = row >> 10, t = row & 1023; orow = (bb << 10) + 1023 - t; }
    unsigned short h[4], l[4];
    #pragma unroll
    for (int j = 0; j < 4; ++j) hl_split(f[j], h[j], l[j]);
    *(ushort4*)(tmpb + (size_t)orow * 4096 + colofs + c4) = make_ushort4(h[0], h[1], h[2], h[3]);
    *(ushort4*)(tmpb + (size_t)orow * 4096 + 2048 + colofs + c4) = make_ushort4(l[0], l[1], l[2], l[3]);
}

__global__ __launch_bounds__(256)
void reduce_out_k(const float* __restrict__ part, const float* __restrict__ bias,
                  float* __restrict__ out)
{
    int i = blockIdx.x * 256 + threadIdx.x;
    int row = i >> 8;
    int c4 = (i & 255) << 2;
    float4 s = make_float4(bias[c4], bias[c4 + 1], bias[c4 + 2], bias[c4 + 3]);
    #pragma unroll
    for (int k = 0; k < 4; ++k) {
        float4 v = *(const float4*)(part + (size_t)k * MROWS * D_MODEL + (size_t)row * D_MODEL + c4);
        s.x += v.x; s.y += v.y; s.z += v.z; s.w += v.w;
    }
    *(float4*)(out + (size_t)row * D_MODEL + c4) = s;
}

// ---------------------------------------------------------------------------
// Causal depthwise conv + SiLU -> ub (hi|lo bf16 only; scan reconstructs).
// ---------------------------------------------------------------------------
__global__ __launch_bounds__(256)
void conv_silu_kernel(const float* __restrict__ xz,
                      const float* __restrict__ convw,
                      const float* __restrict__ convb,
                      unsigned short* __restrict__ ub)
{
    int idx = blockIdx.x * 256 + threadIdx.x;
    int d = idx % D_INNER;
    int r = idx / D_INNER;
    int t = r % SEQLEN;
    float acc = convb[d];
    #pragma unroll
    for (int k = 0; k < D_CONV; ++k) {
        int back = D_CONV - 1 - k;
        if (t - back >= 0)
            acc += xz[(size_t)(r - back) * (2 * D_INNER) + d] * convw[d * D_CONV + k];
    }
    float v = acc * sigmoidf_(acc);
    unsigned short h, l;
    hl_split(v, h, l);
    ub[(size_t)r * (2 * D_INNER) + d] = h;
    ub[(size_t)r * (2 * D_INNER) + D_INNER + d] = l;
}

// ---------------------------------------------------------------------------
// Chunked selective scan (3 phases). u read as hi+lo bf16 reconstruct.
// ---------------------------------------------------------------------------
__global__ __launch_bounds__(256)
void scan_phase1(const float* __restrict__ delta,
                 const unsigned short* __restrict__ ub,
                 const float* __restrict__ xdbl,
                 const float* __restrict__ Alog,
                 float* __restrict__ aprod,
                 float* __restrict__ hfin)
{
    const int tid = threadIdx.x;
    const int ch = blockIdx.x * 16 + (tid >> 4);
    const int n = tid & 15;
    const int chunk = blockIdx.y;
    const int b = ch / D_INNER;
    const int d = ch % D_INNER;

    const float Av = -__expf(Alog[d * D_STATE + n]);
    float h = 0.f, ap = 1.f;
    const int t0 = chunk * CLEN;
    for (int t = t0; t < t0 + CLEN; ++t) {
        const size_t r = (size_t)b * SEQLEN + t;
        float dlt = delta[r * D_INNER + d];
        float uu = us2f(ub[r * (2 * D_INNER) + d]) + us2f(ub[r * (2 * D_INNER) + D_INNER + d]);
        float Bv = xdbl[r * XDBL_LD + DT_RANK + n];
        float dA = __expf(dlt * Av);
        h = h * dA + (dlt * uu) * Bv;
        ap *= dA;
    }
    const size_t idx = ((size_t)ch * D_STATE + n) * NCHUNK + chunk;
    aprod[idx] = ap;
    hfin[idx] = h;
}

__global__ __launch_bounds__(256)
void scan_phase2(const float* __restrict__ aprod,
                 const float* __restrict__ hfin,
                 float* __restrict__ hin)
{
    const int gid = blockIdx.x * 256 + threadIdx.x;
    const size_t base = (size_t)gid * NCHUNK;
    float h = 0.f;
    #pragma unroll
    for (int c = 0; c < NCHUNK; ++c) {
        hin[base + c] = h;
        h = aprod[base + c] * h + hfin[base + c];
    }
}

// phase3: in-place over ub (reads u(r,d) before lane-0 same-iter store; channels
// and chunks are disjoint in (r,d) so no cross-thread hazard).
__global__ __launch_bounds__(256)
void scan_phase3(const float* __restrict__ delta,
                 unsigned short* __restrict__ ub,     // in: u hi/lo, out: yz hi/lo
                 const float* __restrict__ xdbl,
                 const float* __restrict__ Alog,
                 const float* __restrict__ Dsk,
                 const float* __restrict__ xz,
                 const float* __restrict__ hin)
{
    const int tid = threadIdx.x;
    const int ch = blockIdx.x * 16 + (tid >> 4);
    const int n = tid & 15;
    const int chunk = blockIdx.y;
    const int b = ch / D_INNER;
    const int d = ch % D_INNER;

    const float Av = -__expf(Alog[d * D_STATE + n]);
    const float Dv = Dsk[d];
    float h = hin[((size_t)ch * D_STATE + n) * NCHUNK + chunk];
    const int t0 = chunk * CLEN;
    for (int t = t0; t < t0 + CLEN; ++t) {
        const size_t r = (size_t)b * SEQLEN + t;
        float dlt = delta[r * D_INNER + d];
        float uu = us2f(ub[r * (2 * D_INNER) + d]) + us2f(ub[r * (2 * D_INNER) + D_INNER + d]);
        float Bv = xdbl[r * XDBL_LD + DT_RANK + n];
        float Cv = xdbl[r * XDBL_LD + DT_RANK + D_STATE + n];
        float dA = __expf(dlt * Av);
        h = h * dA + (dlt * uu) * Bv;
        float p = h * Cv;
        p += __shfl_xor(p, 1, 16);
        p += __shfl_xor(p, 2, 16);
        p += __shfl_xor(p, 4, 16);
        p += __shfl_xor(p, 8, 16);
        if (n == 0) {
            float zv = xz[r * (2 * D_INNER) + D_INNER + d];
            float v = (p + uu * Dv) * (zv * sigmoidf_(zv));
            unsigned short hh, ll;
            hl_split(v, hh, ll);
            ub[r * (2 * D_INNER) + d] = hh;
            ub[r * (2 * D_INNER) + D_INNER + d] = ll;
        }
    }
}

// ---------------------------------------------------------------------------
extern "C" void kernel_launch(void* const* d_in, const int* in_sizes, int n_in,
                              void* d_out, int out_size, void* d_ws, size_t ws_size,
                              hipStream_t stream)
{
    const float* x = (const float*)d_in[0];
    const float* proj_W = (const float*)d_in[23];
    const float* proj_b = (const float*)d_in[24];
    float* out = (float*)d_out;

    const float *Win[2], *bin_[2], *convw[2], *convb[2], *Wx[2], *Wdt[2], *bdt[2],
                *Alog[2], *Dsk[2], *Wout[2], *bout[2];
    for (int dir = 0; dir < 2; ++dir) {
        const int base = 1 + dir * 11;
        Win[dir]   = (const float*)d_in[base + 0];
        bin_[dir]  = (const float*)d_in[base + 1];
        convw[dir] = (const float*)d_in[base + 2];
        convb[dir] = (const float*)d_in[base + 3];
        Wx[dir]    = (const float*)d_in[base + 4];
        Wdt[dir]   = (const float*)d_in[base + 5];
        bdt[dir]   = (const float*)d_in[base + 6];
        Alog[dir]  = (const float*)d_in[base + 7];
        Dsk[dir]   = (const float*)d_in[base + 8];
        Wout[dir]  = (const float*)d_in[base + 9];
        bout[dir]  = (const float*)d_in[base + 10];
    }

    // ---- explicit arena, 162 MiB total (lifetime-checked overlays) ----
    char* ws = (char*)d_ws;
    const size_t MB = 1ull << 20;
    float* xz[2]            = {(float*)(ws + 0 * MB),   (float*)(ws + 32 * MB)};   // [0,64)
    unsigned short* ub[2]   = {(unsigned short*)(ws + 64 * MB),
                               (unsigned short*)(ws + 80 * MB)};                   // [64,96)
    unsigned short* Winb[2] = {(unsigned short*)(ws + 96 * MB),
                               (unsigned short*)(ws + 112 * MB)};                  // [96,128)
    unsigned short* xc[2]   = {(unsigned short*)(ws + 128 * MB),
                               (unsigned short*)(ws + 136 * MB)};                  // [128,144)
    // overlays:
    float* part             = (float*)(ws + 112 * MB);          // [112,144) after gemm1
    float* delta[2]         = {(float*)(ws + 112 * MB), (float*)(ws + 128 * MB)};
    unsigned short* Woutb[2]= {(unsigned short*)(ws + 96 * MB),
                               (unsigned short*)(ws + 104 * MB)};                  // in Winb0
    unsigned short* yzb[2]  = {ub[0], ub[1]};                   // in-place scan3
    unsigned short* tmpb    = ub[0];                            // after gemm6
    unsigned short* pWb     = ub[1];
    // smalls [144,162):
    unsigned short* Wxb[2]  = {(unsigned short*)(ws + 144 * MB), (unsigned short*)(ws + 145 * MB)};
    unsigned short* Wdtb[2] = {(unsigned short*)(ws + 146 * MB), (unsigned short*)(ws + 146 * MB + 512 * 1024)};
    unsigned short* dtb[2]  = {(unsigned short*)(ws + 147 * MB), (unsigned short*)(ws + 147 * MB + 512 * 1024)};
    float* xdbl[2]          = {(float*)(ws + 148 * MB), (float*)(ws + 149 * MB)};
    float* aprod[2]         = {(float*)(ws + 150 * MB), (float*)(ws + 156 * MB)};
    float* hfin[2]          = {(float*)(ws + 152 * MB), (float*)(ws + 158 * MB)};
    float* hin[2]           = {(float*)(ws + 154 * MB), (float*)(ws + 160 * MB)};

    dim3 blk(256);
    const dim3 scan_grid(BATCH * D_INNER / 16, NCHUNK);

    // --- conversions needed before gemm1 ---
    split_hl_kernel<false><<<2048, blk, 0, stream>>>(x, MROWS, D_MODEL, D_MODEL, xc[0], MROWS);
    split_hl_kernel<true ><<<2048, blk, 0, stream>>>(x, MROWS, D_MODEL, D_MODEL, xc[1], MROWS);
    for (int d = 0; d < 2; ++d) {
        split_hl_kernel<false><<<4096, blk, 0, stream>>>(Win[d], 4096, D_MODEL, D_MODEL, Winb[d], 4096);
        split_hl_kernel<false><<<256,  blk, 0, stream>>>(Wx[d], DT_RANK + 2 * D_STATE, D_INNER, D_INNER, Wxb[d], XDBL_LD);
        split_hl_kernel<false><<<128,  blk, 0, stream>>>(Wdt[d], D_INNER, DT_RANK, DT_RANK, Wdtb[d], D_INNER);
    }

    // --- 1. input proj, both dirs: xz = x' @ Win'^T + bin : (2048, 4096) ---
    gemm_mfma<0, false><<<dim3(32, 16, 2), blk, 0, stream>>>(
        xc[0], xc[1], Winb[0], Winb[1], bin_[0], bin_[1], xz[0], xz[1],
        nullptr, 4096, 4096, D_MODEL, 1);

    // Wout conversions (into Winb0 region — after gemm1 in stream order)
    for (int d = 0; d < 2; ++d)
        split_hl_kernel<false><<<2048, blk, 0, stream>>>(Wout[d], D_MODEL, D_INNER, D_INNER, Woutb[d], D_MODEL);

    // --- 2. conv + silu -> ub hi/lo ---
    for (int d = 0; d < 2; ++d)
        conv_silu_kernel<<<(MROWS * D_INNER) / 256, blk, 0, stream>>>(
            xz[d], convw[d], convb[d], ub[d]);

    // --- 3. xproj split-K (nks=16, both dirs): part -> xdbl + dtb ---
    gemm_mfma<0, true><<<dim3(1, 16, 32), blk, 0, stream>>>(
        ub[0], ub[1], Wxb[0], Wxb[1], nullptr, nullptr, nullptr, nullptr,
        part, XDBL_LD, XDBL_LD, D_INNER, 16);
    for (int d = 0; d < 2; ++d)
        reduce_xdbl_k<<<256, blk, 0, stream>>>(
            part + (size_t)d * 16 * MROWS * XDBL_LD, xdbl[d], dtb[d]);

    // --- 4. dt proj, both dirs: delta = softplus(dt @ Wdt^T + bdt) ---
    gemm_mfma<1, false><<<dim3(16, 16, 2), blk, 0, stream>>>(
        dtb[0], dtb[1], Wdtb[0], Wdtb[1], bdt[0], bdt[1], delta[0], delta[1],
        nullptr, D_INNER, D_INNER, DT_RANK, 1);

    // --- 5. chunked scan + gate (in-place ub -> yzb) ---
    for (int d = 0; d < 2; ++d) {
        scan_phase1<<<scan_grid, blk, 0, stream>>>(delta[d], ub[d], xdbl[d], Alog[d], aprod[d], hfin[d]);
        scan_phase2<<<BATCH * D_INNER * D_STATE / 256, blk, 0, stream>>>(aprod[d], hfin[d], hin[d]);
        scan_phase3<<<scan_grid, blk, 0, stream>>>(delta[d], ub[d], xdbl[d], Alog[d], Dsk[d], xz[d], hin[d]);
    }

    // --- 6. out proj split-K (nks=2, both dirs) -> tmpb hi/lo ---
    gemm_mfma<0, true><<<dim3(8, 16, 4), blk, 0, stream>>>(
        yzb[0], yzb[1], Woutb[0], Woutb[1], nullptr, nullptr, nullptr, nullptr,
        part, D_MODEL, D_MODEL, D_INNER, 2);
    reduce_tmpb_k<false><<<2048, blk, 0, stream>>>(part, bout[0], tmpb, 0);
    reduce_tmpb_k<true ><<<2048, blk, 0, stream>>>(
        part + (size_t)2 * MROWS * D_MODEL, bout[1], tmpb, D_MODEL);

    // pW conversion (into ub1 region — yzb1 dead after gemm6)
    split_hl_kernel<false><<<2048, blk, 0, stream>>>(proj_W, D_MODEL, 2 * D_MODEL, 2 * D_MODEL, pWb, D_MODEL);

    // --- 7. final proj split-K (nks=4): out = tmp @ proj_W^T + proj_b ---
    gemm_mfma<0, true><<<dim3(8, 16, 4), blk, 0, stream>>>(
        tmpb, nullptr, pWb, nullptr, nullptr, nullptr, nullptr, nullptr,
        part, D_MODEL, D_MODEL, 2 * D_MODEL, 4);
    reduce_out_k<<<2048, blk, 0, stream>>>(part, proj_b, out);
}

// Round 6
// 738.836 us; speedup vs baseline: 3.9236x; 1.0286x over previous
//
#include <hip/hip_runtime.h>
#include <math.h>

#define D_MODEL 1024
#define D_STATE 16
#define D_CONV  4
#define D_INNER 2048
#define DT_RANK 64
#define BATCH   2
#define SEQLEN  1024
#define MROWS   2048
#define XDBL_LD 128
#define NCHUNK  8
#define CLEN    (SEQLEN / NCHUNK)

typedef __attribute__((ext_vector_type(8))) short bf16x8;
typedef __attribute__((ext_vector_type(4))) float f32x4;

#define BARR() asm volatile("s_barrier" ::: "memory")
#define VMW(n) asm volatile("s_waitcnt vmcnt(" #n ")" ::: "memory")

static __device__ __forceinline__ float sigmoidf_(float x) {
    return 1.f / (1.f + __expf(-x));
}
static __device__ __forceinline__ unsigned short bf16rn(float f) {
    unsigned u = __float_as_uint(f);
    return (unsigned short)((u + 0x7FFFu + ((u >> 16) & 1u)) >> 16);
}
static __device__ __forceinline__ void hl_split(float f, unsigned short& h, unsigned short& l) {
    h = bf16rn(f);
    l = bf16rn(f - __uint_as_float((unsigned)h << 16));
}
static __device__ __forceinline__ float us2f(unsigned short u) {
    return __uint_as_float((unsigned)u << 16);
}

// ---------------------------------------------------------------------------
// fp32 -> bf16 hi|lo split (cols [0,C)=hi, [C,2C)=lo). FLIP = time-reverse.
// ---------------------------------------------------------------------------
template<bool FLIP>
__global__ __launch_bounds__(256)
void split_hl_kernel(const float* __restrict__ in, int R, int C, int ldin,
                     unsigned short* __restrict__ out, int Rout)
{
    int q = blockIdx.x * 256 + threadIdx.x;
    int qpr = C >> 2;
    int row = q / qpr;
    int c4 = (q - row * qpr) << 2;
    if (row >= Rout) return;
    unsigned short h[4] = {0, 0, 0, 0}, l[4] = {0, 0, 0, 0};
    if (row < R) {
        int sr = row;
        if (FLIP) { int b = row >> 10, t = row & 1023; sr = (b << 10) + (1023 - t); }
        float4 v = *(const float4*)(in + (size_t)sr * ldin + c4);
        float f[4] = {v.x, v.y, v.z, v.w};
        #pragma unroll
        for (int i = 0; i < 4; ++i) hl_split(f[i], h[i], l[i]);
    }
    size_t ob = (size_t)row * (2 * C);
    *(ushort4*)(out + ob + c4)     = make_ushort4(h[0], h[1], h[2], h[3]);
    *(ushort4*)(out + ob + C + c4) = make_ushort4(l[0], l[1], l[2], l[3]);
}

// ---------------------------------------------------------------------------
// 256x256 8-phase bf16x3 MFMA GEMM (T2+T3+T4+T5), dual-dir + split-K.
// 512 threads = 8 waves (2M x 4N), BK=64 in 2 kk-halves of 32.
// LDS: AS/BS [2 dbuf][2 kk][256 rows][32] = 64KB each (128KB total).
// Per K-tile 4 phases: P1(kk0,m0: 8 ds_read + stage A-kk1(t+1)),
// P2(vmcnt(8); kk0,m1: 4 reads + stage B-kk0(t+2)), P3(kk1,m0 + stage
// A-kk0(t+2)), P4(vmcnt(8); kk1,m1 + stage B-kk1(t+2)). Counted vmcnt keeps
// 4 half-tiles in flight; never drains to 0 in steady state.
// Swizzle: 16B slot ^= (row&3) on read; inverse applied to global source.
// ---------------------------------------------------------------------------
#define RDA(p, kk, row) (*(const bf16x8*)&AS[p][kk][row][(fs ^ ((row) & 3)) << 3])
#define RDB(p, kk, row) (*(const bf16x8*)&BS[p][kk][row][(fs ^ ((row) & 3)) << 3])

#define KTILE(MODE, kt) do { \
    const int p_ = (kt) & 1; \
    bf16x8 bF[4]; \
    { /* P1 */ \
        bf16x8 aF[4]; \
        _Pragma("unroll") for (int f = 0; f < 4; ++f) { int rw = wm + f * 16 + fr; aF[f] = RDA(p_, 0, rw); } \
        _Pragma("unroll") for (int g = 0; g < 4; ++g) { int rw = wn + g * 16 + fr; bF[g] = RDB(p_, 0, rw); } \
        if (MODE < 2) stageA((kt) + 1, 1); \
        BARR(); __builtin_amdgcn_s_setprio(1); \
        _Pragma("unroll") for (int f = 0; f < 4; ++f) \
        _Pragma("unroll") for (int g = 0; g < 4; ++g) \
            acc[f][g] = __builtin_amdgcn_mfma_f32_16x16x32_bf16(aF[f], bF[g], acc[f][g], 0, 0, 0); \
        __builtin_amdgcn_s_setprio(0); BARR(); \
    } \
    { /* P2 */ \
        if (MODE == 2) { VMW(0); } else { VMW(8); } \
        bf16x8 aF[4]; \
        _Pragma("unroll") for (int f = 0; f < 4; ++f) { int rw = wm + 64 + f * 16 + fr; aF[f] = RDA(p_, 0, rw); } \
        if (MODE == 0) stageB((kt) + 2, 0); \
        BARR(); __builtin_amdgcn_s_setprio(1); \
        _Pragma("unroll") for (int f = 0; f < 4; ++f) \
        _Pragma("unroll") for (int g = 0; g < 4; ++g) \
            acc[4 + f][g] = __builtin_amdgcn_mfma_f32_16x16x32_bf16(aF[f], bF[g], acc[4 + f][g], 0, 0, 0); \
        __builtin_amdgcn_s_setprio(0); BARR(); \
    } \
    { /* P3 */ \
        bf16x8 aF[4]; \
        _Pragma("unroll") for (int f = 0; f < 4; ++f) { int rw = wm + f * 16 + fr; aF[f] = RDA(p_, 1, rw); } \
        _Pragma("unroll") for (int g = 0; g < 4; ++g) { int rw = wn + g * 16 + fr; bF[g] = RDB(p_, 1, rw); } \
        if (MODE == 0) stageA((kt) + 2, 0); \
        BARR(); __builtin_amdgcn_s_setprio(1); \
        _Pragma("unroll") for (int f = 0; f < 4; ++f) \
        _Pragma("unroll") for (int g = 0; g < 4; ++g) \
            acc[f][g] = __builtin_amdgcn_mfma_f32_16x16x32_bf16(aF[f], bF[g], acc[f][g], 0, 0, 0); \
        __builtin_amdgcn_s_setprio(0); BARR(); \
    } \
    { /* P4 */ \
        if (MODE == 0) { VMW(8); } else if (MODE == 1) { VMW(4); } \
        bf16x8 aF[4]; \
        _Pragma("unroll") for (int f = 0; f < 4; ++f) { int rw = wm + 64 + f * 16 + fr; aF[f] = RDA(p_, 1, rw); } \
        if (MODE == 0) stageB((kt) + 2, 1); \
        BARR(); __builtin_amdgcn_s_setprio(1); \
        _Pragma("unroll") for (int f = 0; f < 4; ++f) \
        _Pragma("unroll") for (int g = 0; g < 4; ++g) \
            acc[4 + f][g] = __builtin_amdgcn_mfma_f32_16x16x32_bf16(aF[f], bF[g], acc[4 + f][g], 0, 0, 0); \
        __builtin_amdgcn_s_setprio(0); BARR(); \
    } \
} while (0)

template<int ACT, bool PART>
__global__ __launch_bounds__(512, 1)
void gemm256(const unsigned short* __restrict__ A0,
             const unsigned short* __restrict__ A1,
             const unsigned short* __restrict__ W0,
             const unsigned short* __restrict__ W1,
             const float* __restrict__ bias0,
             const float* __restrict__ bias1,
             float* __restrict__ C0, float* __restrict__ C1,
             float* __restrict__ part,
             int ldc, int N, int K, int nks, int KTS)
{
    __shared__ unsigned short AS[2][2][256][32];
    __shared__ unsigned short BS[2][2][256][32];

    const int tid = threadIdx.x;
    const int lane = tid & 63;
    const int wid = tid >> 6;

    const int z = blockIdx.z;
    const int dir = z / nks;
    const int ks = z - dir * nks;
    const unsigned short* A = dir ? A1 : A0;
    const unsigned short* W = dir ? W1 : W0;

    const int nbx = gridDim.x;
    const int nwg = nbx * gridDim.y;
    int bid = blockIdx.y * nbx + blockIdx.x;
    int q8 = nwg >> 3;
    int swz = (bid & 7) * q8 + (bid >> 3);
    const int bm = (swz / nbx) * 256;
    const int bn = (swz % nbx) * 256;

    const int ldg = 2 * K;
    const int Kc = KTS * 64;
    const int kbase = ks * Kc;
    const int NT = 3 * KTS;

    const int wm = (wid >> 2) * 128;
    const int wn = (wid & 3) * 64;
    const int fr = lane & 15;
    const int fs = lane >> 4;

    f32x4 acc[8][4];
    #pragma unroll
    for (int i = 0; i < 8; ++i)
        #pragma unroll
        for (int j = 0; j < 4; ++j) {
            f32x4 zv = {0.f, 0.f, 0.f, 0.f};
            acc[i][j] = zv;
        }

    auto koffA = [&](int t) { int sg = t / KTS; int w = t - sg * KTS;
                              return ((sg == 1) ? K : 0) + kbase + w * 64; };
    auto koffB = [&](int t) { int sg = t / KTS; int w = t - sg * KTS;
                              return ((sg == 2) ? K : 0) + kbase + w * 64; };

    auto stageA = [&](int t, int kk) {
        int ko = koffA(t) + kk * 32;
        unsigned short* dst = &AS[t & 1][kk][0][0];
        #pragma unroll
        for (int i = 0; i < 2; ++i) {
            int s = i * 512 + tid;
            int row = s >> 2, sl = s & 3, lsl = sl ^ (row & 3);
            const unsigned short* src = A + (size_t)(bm + row) * ldg + ko + lsl * 8;
            __builtin_amdgcn_global_load_lds(
                (const __attribute__((address_space(1))) void*)src,
                (__attribute__((address_space(3))) void*)(dst + s * 8), 16, 0, 0);
        }
    };
    auto stageB = [&](int t, int kk) {
        int ko = koffB(t) + kk * 32;
        unsigned short* dst = &BS[t & 1][kk][0][0];
        #pragma unroll
        for (int i = 0; i < 2; ++i) {
            int s = i * 512 + tid;
            int row = s >> 2, sl = s & 3, lsl = sl ^ (row & 3);
            const unsigned short* src = W + (size_t)(bn + row) * ldg + ko + lsl * 8;
            __builtin_amdgcn_global_load_lds(
                (const __attribute__((address_space(1))) void*)src,
                (__attribute__((address_space(3))) void*)(dst + s * 8), 16, 0, 0);
        }
    };

    // prologue: 7 half-tiles (K-tile 0 complete + 3/4 of K-tile 1)
    stageB(0, 0); stageA(0, 0); stageB(0, 1); stageA(0, 1);
    stageB(1, 0); stageA(1, 0); stageB(1, 1);
    VMW(6);
    BARR();

    for (int kt = 0; kt < NT - 2; ++kt) KTILE(0, kt);
    KTILE(1, NT - 2);
    KTILE(2, NT - 1);

    if (PART) {
        float* P = part + (size_t)z * ((size_t)MROWS * N);
        #pragma unroll
        for (int i = 0; i < 8; ++i)
            #pragma unroll
            for (int j = 0; j < 4; ++j) {
                int coln = bn + wn + j * 16 + fr;
                #pragma unroll
                for (int r = 0; r < 4; ++r) {
                    int rowm = bm + wm + i * 16 + fs * 4 + r;
                    P[(size_t)rowm * N + coln] = acc[i][j][r];
                }
            }
    } else {
        const float* bias = dir ? bias1 : bias0;
        float* C = dir ? C1 : C0;
        #pragma unroll
        for (int i = 0; i < 8; ++i)
            #pragma unroll
            for (int j = 0; j < 4; ++j) {
                int coln = bn + wn + j * 16 + fr;
                float bv = bias ? bias[coln] : 0.f;
                #pragma unroll
                for (int r = 0; r < 4; ++r) {
                    int rowm = bm + wm + i * 16 + fs * 4 + r;
                    float v = acc[i][j][r] + bv;
                    if (ACT == 1) v = (v > 20.f) ? v : log1pf(__expf(v));
                    C[(size_t)rowm * ldc + coln] = v;
                }
            }
    }
}

// ---------------------------------------------------------------------------
// 128x128 bf16x3 MFMA GEMM (2-barrier structure) for small shapes.
// ---------------------------------------------------------------------------
template<int ACT, bool PART>
__global__ __launch_bounds__(256)
void gemm_mfma(const unsigned short* __restrict__ A0,
               const unsigned short* __restrict__ A1,
               const unsigned short* __restrict__ W0,
               const unsigned short* __restrict__ W1,
               const float* __restrict__ bias0,
               const float* __restrict__ bias1,
               float* __restrict__ C0, float* __restrict__ C1,
               float* __restrict__ part,
               int ldc, int N, int K, int nks)
{
    __shared__ __align__(16) unsigned short As[128 * 32];
    __shared__ __align__(16) unsigned short Bs[128 * 32];

    const int tid = threadIdx.x;
    const int lane = tid & 63;
    const int wid = tid >> 6;

    const int z = blockIdx.z;
    const int dir = z / nks;
    const int ks = z - dir * nks;
    const unsigned short* A = dir ? A1 : A0;
    const unsigned short* W = dir ? W1 : W0;

    const int nbx = gridDim.x;
    const int nwg = nbx * gridDim.y;
    int bid = blockIdx.y * nbx + blockIdx.x;
    int q8 = nwg >> 3;
    int swz = (nwg >= 8) ? (bid & 7) * q8 + (bid >> 3) : bid;
    const int bm = (swz / nbx) * 128;
    const int bn = (swz % nbx) * 128;

    const int ldg = 2 * K;
    const int Kc = K / nks;
    const int kbase = ks * Kc;

    f32x4 acc[4][4];
    #pragma unroll
    for (int i = 0; i < 4; ++i)
        #pragma unroll
        for (int j = 0; j < 4; ++j) {
            f32x4 zv = {0.f, 0.f, 0.f, 0.f};
            acc[i][j] = zv;
        }

    const int r0 = tid >> 2;
    const int k0s = (tid & 3) ^ ((r0 >> 1) & 3);
    const int r1 = (256 + tid) >> 2;
    const int k1s = (tid & 3) ^ ((r1 >> 1) & 3);

    unsigned short* As_w0 = &As[(wid << 6) * 8];
    unsigned short* As_w1 = &As[(256 + (wid << 6)) * 8];
    unsigned short* Bs_w0 = &Bs[(wid << 6) * 8];
    unsigned short* Bs_w1 = &Bs[(256 + (wid << 6)) * 8];

    const int wm = (wid >> 1) * 64;
    const int wn = (wid & 1) * 64;
    const int fr = lane & 15;
    const int fs = lane >> 4;

    const int KS = Kc >> 5;
    #pragma unroll 1
    for (int seg = 0; seg < 3; ++seg) {
        const int aoff = ((seg == 1) ? K : 0) + kbase;
        const int boff = ((seg == 2) ? K : 0) + kbase;
        #pragma unroll 1
        for (int kt = 0; kt < KS; ++kt) {
            const int kk = kt << 5;
            const unsigned short* ga0 = A + (size_t)(bm + r0) * ldg + aoff + kk + k0s * 8;
            const unsigned short* ga1 = A + (size_t)(bm + r1) * ldg + aoff + kk + k1s * 8;
            const unsigned short* gw0 = W + (size_t)(bn + r0) * ldg + boff + kk + k0s * 8;
            const unsigned short* gw1 = W + (size_t)(bn + r1) * ldg + boff + kk + k1s * 8;
            __builtin_amdgcn_global_load_lds(
                (const __attribute__((address_space(1))) void*)ga0,
                (__attribute__((address_space(3))) void*)As_w0, 16, 0, 0);
            __builtin_amdgcn_global_load_lds(
                (const __attribute__((address_space(1))) void*)ga1,
                (__attribute__((address_space(3))) void*)As_w1, 16, 0, 0);
            __builtin_amdgcn_global_load_lds(
                (const __attribute__((address_space(1))) void*)gw0,
                (__attribute__((address_space(3))) void*)Bs_w0, 16, 0, 0);
            __builtin_amdgcn_global_load_lds(
                (const __attribute__((address_space(1))) void*)gw1,
                (__attribute__((address_space(3))) void*)Bs_w1, 16, 0, 0);
            __syncthreads();

            bf16x8 aF[4], bF[4];
            #pragma unroll
            for (int f = 0; f < 4; ++f) {
                int ra = wm + f * 16 + fr;
                int sa = fs ^ ((ra >> 1) & 3);
                aF[f] = *(const bf16x8*)&As[ra * 32 + sa * 8];
                int rb = wn + f * 16 + fr;
                int sb = fs ^ ((rb >> 1) & 3);
                bF[f] = *(const bf16x8*)&Bs[rb * 32 + sb * 8];
            }
            #pragma unroll
            for (int i = 0; i < 4; ++i)
                #pragma unroll
                for (int j = 0; j < 4; ++j)
                    acc[i][j] = __builtin_amdgcn_mfma_f32_16x16x32_bf16(
                        aF[i], bF[j], acc[i][j], 0, 0, 0);
            __syncthreads();
        }
    }

    if (PART) {
        float* P = part + (size_t)z * ((size_t)MROWS * N);
        #pragma unroll
        for (int i = 0; i < 4; ++i)
            #pragma unroll
            for (int j = 0; j < 4; ++j) {
                int coln = bn + wn + j * 16 + fr;
                #pragma unroll
                for (int r = 0; r < 4; ++r) {
                    int rowm = bm + wm + i * 16 + fs * 4 + r;
                    P[(size_t)rowm * N + coln] = acc[i][j][r];
                }
            }
    } else {
        const float* bias = dir ? bias1 : bias0;
        float* C = dir ? C1 : C0;
        #pragma unroll
        for (int i = 0; i < 4; ++i)
            #pragma unroll
            for (int j = 0; j < 4; ++j) {
                int coln = bn + wn + j * 16 + fr;
                float bv = bias ? bias[coln] : 0.f;
                #pragma unroll
                for (int r = 0; r < 4; ++r) {
                    int rowm = bm + wm + i * 16 + fs * 4 + r;
                    float v = acc[i][j][r] + bv;
                    if (ACT == 1) v = (v > 20.f) ? v : log1pf(__expf(v));
                    C[(size_t)rowm * ldc + coln] = v;
                }
            }
    }
}

// ---------------------------------------------------------------------------
// Split-K reduces with fused epilogues.
// ---------------------------------------------------------------------------
__global__ __launch_bounds__(256)
void reduce_xdbl_k(const float* __restrict__ part,
                   float* __restrict__ xdbl, unsigned short* __restrict__ dtb)
{
    int i = blockIdx.x * 256 + threadIdx.x;
    int row = i >> 5;
    int c4 = (i & 31) << 2;
    float4 s = make_float4(0.f, 0.f, 0.f, 0.f);
    #pragma unroll
    for (int k = 0; k < 16; ++k) {
        float4 v = *(const float4*)(part + (size_t)k * MROWS * XDBL_LD + (size_t)row * XDBL_LD + c4);
        s.x += v.x; s.y += v.y; s.z += v.z; s.w += v.w;
    }
    *(float4*)(xdbl + (size_t)row * XDBL_LD + c4) = s;
    if (c4 < DT_RANK) {
        float f[4] = {s.x, s.y, s.z, s.w};
        unsigned short h[4], l[4];
        #pragma unroll
        for (int j = 0; j < 4; ++j) hl_split(f[j], h[j], l[j]);
        *(ushort4*)(dtb + (size_t)row * (2 * DT_RANK) + c4) = make_ushort4(h[0], h[1], h[2], h[3]);
        *(ushort4*)(dtb + (size_t)row * (2 * DT_RANK) + DT_RANK + c4) = make_ushort4(l[0], l[1], l[2], l[3]);
    }
}

template<bool FLIP>
__global__ __launch_bounds__(256)
void reduce_tmpb_k(const float* __restrict__ part, const float* __restrict__ bias,
                   unsigned short* __restrict__ tmpb, int colofs)
{
    int i = blockIdx.x * 256 + threadIdx.x;
    int row = i >> 8;
    int c4 = (i & 255) << 2;
    float4 s = make_float4(bias[c4], bias[c4 + 1], bias[c4 + 2], bias[c4 + 3]);
    #pragma unroll
    for (int k = 0; k < 4; ++k) {
        float4 v = *(const float4*)(part + (size_t)k * MROWS * D_MODEL + (size_t)row * D_MODEL + c4);
        s.x += v.x; s.y += v.y; s.z += v.z; s.w += v.w;
    }
    int orow = row;
    if (FLIP) { int bb = row >> 10, t = row & 1023; orow = (bb << 10) + 1023 - t; }
    float f[4] = {s.x, s.y, s.z, s.w};
    unsigned short h[4], l[4];
    #pragma unroll
    for (int j = 0; j < 4; ++j) hl_split(f[j], h[j], l[j]);
    *(ushort4*)(tmpb + (size_t)orow * 4096 + colofs + c4) = make_ushort4(h[0], h[1], h[2], h[3]);
    *(ushort4*)(tmpb + (size_t)orow * 4096 + 2048 + colofs + c4) = make_ushort4(l[0], l[1], l[2], l[3]);
}

__global__ __launch_bounds__(256)
void reduce_out_k(const float* __restrict__ part, const float* __restrict__ bias,
                  float* __restrict__ out)
{
    int i = blockIdx.x * 256 + threadIdx.x;
    int row = i >> 8;
    int c4 = (i & 255) << 2;
    float4 s = make_float4(bias[c4], bias[c4 + 1], bias[c4 + 2], bias[c4 + 3]);
    #pragma unroll
    for (int k = 0; k < 8; ++k) {
        float4 v = *(const float4*)(part + (size_t)k * MROWS * D_MODEL + (size_t)row * D_MODEL + c4);
        s.x += v.x; s.y += v.y; s.z += v.z; s.w += v.w;
    }
    *(float4*)(out + (size_t)row * D_MODEL + c4) = s;
}

// ---------------------------------------------------------------------------
// Causal depthwise conv + SiLU -> ub (hi|lo bf16).
// ---------------------------------------------------------------------------
__global__ __launch_bounds__(256)
void conv_silu_kernel(const float* __restrict__ xz,
                      const float* __restrict__ convw,
                      const float* __restrict__ convb,
                      unsigned short* __restrict__ ub)
{
    int idx = blockIdx.x * 256 + threadIdx.x;
    int d = idx % D_INNER;
    int r = idx / D_INNER;
    int t = r % SEQLEN;
    float acc = convb[d];
    #pragma unroll
    for (int k = 0; k < D_CONV; ++k) {
        int back = D_CONV - 1 - k;
        if (t - back >= 0)
            acc += xz[(size_t)(r - back) * (2 * D_INNER) + d] * convw[d * D_CONV + k];
    }
    float v = acc * sigmoidf_(acc);
    unsigned short h, l;
    hl_split(v, h, l);
    ub[(size_t)r * (2 * D_INNER) + d] = h;
    ub[(size_t)r * (2 * D_INNER) + D_INNER + d] = l;
}

// ---------------------------------------------------------------------------
// Chunked selective scan (3 phases); u reconstructed from ub hi+lo.
// ---------------------------------------------------------------------------
__global__ __launch_bounds__(256)
void scan_phase1(const float* __restrict__ delta,
                 const unsigned short* __restrict__ ub,
                 const float* __restrict__ xdbl,
                 const float* __restrict__ Alog,
                 float* __restrict__ aprod,
                 float* __restrict__ hfin)
{
    const int tid = threadIdx.x;
    const int ch = blockIdx.x * 16 + (tid >> 4);
    const int n = tid & 15;
    const int chunk = blockIdx.y;
    const int b = ch / D_INNER;
    const int d = ch % D_INNER;

    const float Av = -__expf(Alog[d * D_STATE + n]);
    float h = 0.f, ap = 1.f;
    const int t0 = chunk * CLEN;
    for (int t = t0; t < t0 + CLEN; ++t) {
        const size_t r = (size_t)b * SEQLEN + t;
        float dlt = delta[r * D_INNER + d];
        float uu = us2f(ub[r * (2 * D_INNER) + d]) + us2f(ub[r * (2 * D_INNER) + D_INNER + d]);
        float Bv = xdbl[r * XDBL_LD + DT_RANK + n];
        float dA = __expf(dlt * Av);
        h = h * dA + (dlt * uu) * Bv;
        ap *= dA;
    }
    const size_t idx = ((size_t)ch * D_STATE + n) * NCHUNK + chunk;
    aprod[idx] = ap;
    hfin[idx] = h;
}

__global__ __launch_bounds__(256)
void scan_phase2(const float* __restrict__ aprod,
                 const float* __restrict__ hfin,
                 float* __restrict__ hin)
{
    const int gid = blockIdx.x * 256 + threadIdx.x;
    const size_t base = (size_t)gid * NCHUNK;
    float h = 0.f;
    #pragma unroll
    for (int c = 0; c < NCHUNK; ++c) {
        hin[base + c] = h;
        h = aprod[base + c] * h + hfin[base + c];
    }
}

__global__ __launch_bounds__(256)
void scan_phase3(const float* __restrict__ delta,
                 unsigned short* __restrict__ ub,
                 const float* __restrict__ xdbl,
                 const float* __restrict__ Alog,
                 const float* __restrict__ Dsk,
                 const float* __restrict__ xz,
                 const float* __restrict__ hin)
{
    const int tid = threadIdx.x;
    const int ch = blockIdx.x * 16 + (tid >> 4);
    const int n = tid & 15;
    const int chunk = blockIdx.y;
    const int b = ch / D_INNER;
    const int d = ch % D_INNER;

    const float Av = -__expf(Alog[d * D_STATE + n]);
    const float Dv = Dsk[d];
    float h = hin[((size_t)ch * D_STATE + n) * NCHUNK + chunk];
    const int t0 = chunk * CLEN;
    for (int t = t0; t < t0 + CLEN; ++t) {
        const size_t r = (size_t)b * SEQLEN + t;
        float dlt = delta[r * D_INNER + d];
        float uu = us2f(ub[r * (2 * D_INNER) + d]) + us2f(ub[r * (2 * D_INNER) + D_INNER + d]);
        float Bv = xdbl[r * XDBL_LD + DT_RANK + n];
        float Cv = xdbl[r * XDBL_LD + DT_RANK + D_STATE + n];
        float dA = __expf(dlt * Av);
        h = h * dA + (dlt * uu) * Bv;
        float p = h * Cv;
        p += __shfl_xor(p, 1, 16);
        p += __shfl_xor(p, 2, 16);
        p += __shfl_xor(p, 4, 16);
        p += __shfl_xor(p, 8, 16);
        if (n == 0) {
            float zv = xz[r * (2 * D_INNER) + D_INNER + d];
            float v = (p + uu * Dv) * (zv * sigmoidf_(zv));
            unsigned short hh, ll;
            hl_split(v, hh, ll);
            ub[r * (2 * D_INNER) + d] = hh;
            ub[r * (2 * D_INNER) + D_INNER + d] = ll;
        }
    }
}

// ---------------------------------------------------------------------------
extern "C" void kernel_launch(void* const* d_in, const int* in_sizes, int n_in,
                              void* d_out, int out_size, void* d_ws, size_t ws_size,
                              hipStream_t stream)
{
    const float* x = (const float*)d_in[0];
    const float* proj_W = (const float*)d_in[23];
    const float* proj_b = (const float*)d_in[24];
    float* out = (float*)d_out;

    const float *Win[2], *bin_[2], *convw[2], *convb[2], *Wx[2], *Wdt[2], *bdt[2],
                *Alog[2], *Dsk[2], *Wout[2], *bout[2];
    for (int dir = 0; dir < 2; ++dir) {
        const int base = 1 + dir * 11;
        Win[dir]   = (const float*)d_in[base + 0];
        bin_[dir]  = (const float*)d_in[base + 1];
        convw[dir] = (const float*)d_in[base + 2];
        convb[dir] = (const float*)d_in[base + 3];
        Wx[dir]    = (const float*)d_in[base + 4];
        Wdt[dir]   = (const float*)d_in[base + 5];
        bdt[dir]   = (const float*)d_in[base + 6];
        Alog[dir]  = (const float*)d_in[base + 7];
        Dsk[dir]   = (const float*)d_in[base + 8];
        Wout[dir]  = (const float*)d_in[base + 9];
        bout[dir]  = (const float*)d_in[base + 10];
    }

    // ---- explicit arena (lifetime-checked overlays) ----
    char* ws = (char*)d_ws;
    const size_t MB = 1ull << 20;
    float* xz[2]            = {(float*)(ws + 0 * MB),   (float*)(ws + 32 * MB)};   // [0,64)
    unsigned short* ub[2]   = {(unsigned short*)(ws + 64 * MB),
                               (unsigned short*)(ws + 80 * MB)};                   // [64,96)
    unsigned short* Winb[2] = {(unsigned short*)(ws + 96 * MB),
                               (unsigned short*)(ws + 112 * MB)};                  // [96,128)
    unsigned short* xc[2]   = {(unsigned short*)(ws + 128 * MB),
                               (unsigned short*)(ws + 136 * MB)};                  // [128,144)
    // overlays:
    float* part             = (float*)(ws + 112 * MB);          // [112,144) after gemm1 (xproj)
    float* part2            = (float*)(ws + 0 * MB);            // [0,64) after scan3 (xz dead)
    float* delta[2]         = {(float*)(ws + 112 * MB), (float*)(ws + 128 * MB)};
    unsigned short* Woutb[2]= {(unsigned short*)(ws + 96 * MB),
                               (unsigned short*)(ws + 104 * MB)};                  // in Winb0
    unsigned short* yzb[2]  = {ub[0], ub[1]};                   // in-place scan3
    unsigned short* tmpb    = ub[0];                            // after gemm6
    unsigned short* pWb     = ub[1];
    // smalls [144,162):
    unsigned short* Wxb[2]  = {(unsigned short*)(ws + 144 * MB), (unsigned short*)(ws + 145 * MB)};
    unsigned short* Wdtb[2] = {(unsigned short*)(ws + 146 * MB), (unsigned short*)(ws + 146 * MB + 512 * 1024)};
    unsigned short* dtb[2]  = {(unsigned short*)(ws + 147 * MB), (unsigned short*)(ws + 147 * MB + 512 * 1024)};
    float* xdbl[2]          = {(float*)(ws + 148 * MB), (float*)(ws + 149 * MB)};
    float* aprod[2]         = {(float*)(ws + 150 * MB), (float*)(ws + 156 * MB)};
    float* hfin[2]          = {(float*)(ws + 152 * MB), (float*)(ws + 158 * MB)};
    float* hin[2]           = {(float*)(ws + 154 * MB), (float*)(ws + 160 * MB)};

    dim3 blk(256);
    const dim3 scan_grid(BATCH * D_INNER / 16, NCHUNK);

    // --- conversions needed before gemm1 ---
    split_hl_kernel<false><<<2048, blk, 0, stream>>>(x, MROWS, D_MODEL, D_MODEL, xc[0], MROWS);
    split_hl_kernel<true ><<<2048, blk, 0, stream>>>(x, MROWS, D_MODEL, D_MODEL, xc[1], MROWS);
    for (int d = 0; d < 2; ++d) {
        split_hl_kernel<false><<<4096, blk, 0, stream>>>(Win[d], 4096, D_MODEL, D_MODEL, Winb[d], 4096);
        split_hl_kernel<false><<<256,  blk, 0, stream>>>(Wx[d], DT_RANK + 2 * D_STATE, D_INNER, D_INNER, Wxb[d], XDBL_LD);
        split_hl_kernel<false><<<128,  blk, 0, stream>>>(Wdt[d], D_INNER, DT_RANK, DT_RANK, Wdtb[d], D_INNER);
    }

    // --- 1. input proj (8-phase 256²), both dirs: xz = x' @ Win'^T + bin ---
    gemm256<0, false><<<dim3(16, 8, 2), dim3(512), 0, stream>>>(
        xc[0], xc[1], Winb[0], Winb[1], bin_[0], bin_[1], xz[0], xz[1],
        nullptr, 4096, 4096, D_MODEL, 1, 16);

    // Wout conversions (into Winb0 region — after gemm1 in stream order)
    for (int d = 0; d < 2; ++d)
        split_hl_kernel<false><<<2048, blk, 0, stream>>>(Wout[d], D_MODEL, D_INNER, D_INNER, Woutb[d], D_MODEL);

    // --- 2. conv + silu -> ub hi/lo ---
    for (int d = 0; d < 2; ++d)
        conv_silu_kernel<<<(MROWS * D_INNER) / 256, blk, 0, stream>>>(
            xz[d], convw[d], convb[d], ub[d]);

    // --- 3. xproj split-K (128², nks=16, both dirs): part -> xdbl + dtb ---
    gemm_mfma<0, true><<<dim3(1, 16, 32), blk, 0, stream>>>(
        ub[0], ub[1], Wxb[0], Wxb[1], nullptr, nullptr, nullptr, nullptr,
        part, XDBL_LD, XDBL_LD, D_INNER, 16);
    for (int d = 0; d < 2; ++d)
        reduce_xdbl_k<<<256, blk, 0, stream>>>(
            part + (size_t)d * 16 * MROWS * XDBL_LD, xdbl[d], dtb[d]);

    // --- 4. dt proj (128²), both dirs: delta = softplus(dt @ Wdt^T + bdt) ---
    gemm_mfma<1, false><<<dim3(16, 16, 2), blk, 0, stream>>>(
        dtb[0], dtb[1], Wdtb[0], Wdtb[1], bdt[0], bdt[1], delta[0], delta[1],
        nullptr, D_INNER, D_INNER, DT_RANK, 1);

    // --- 5. chunked scan + gate (in-place ub -> yzb) ---
    for (int d = 0; d < 2; ++d) {
        scan_phase1<<<scan_grid, blk, 0, stream>>>(delta[d], ub[d], xdbl[d], Alog[d], aprod[d], hfin[d]);
        scan_phase2<<<BATCH * D_INNER * D_STATE / 256, blk, 0, stream>>>(aprod[d], hfin[d], hin[d]);
        scan_phase3<<<scan_grid, blk, 0, stream>>>(delta[d], ub[d], xdbl[d], Alog[d], Dsk[d], xz[d], hin[d]);
    }

    // --- 6. out proj (8-phase 256², nks=4, both dirs) -> part2 [xz dead] ---
    gemm256<0, true><<<dim3(4, 8, 8), dim3(512), 0, stream>>>(
        yzb[0], yzb[1], Woutb[0], Woutb[1], nullptr, nullptr, nullptr, nullptr,
        part2, D_MODEL, D_MODEL, D_INNER, 4, 8);
    reduce_tmpb_k<false><<<2048, blk, 0, stream>>>(part2, bout[0], tmpb, 0);
    reduce_tmpb_k<true ><<<2048, blk, 0, stream>>>(
        part2 + (size_t)4 * MROWS * D_MODEL, bout[1], tmpb, D_MODEL);

    // pW conversion (into ub1 region — yzb1 dead after gemm6)
    split_hl_kernel<false><<<2048, blk, 0, stream>>>(proj_W, D_MODEL, 2 * D_MODEL, 2 * D_MODEL, pWb, D_MODEL);

    // --- 7. final proj (8-phase 256², nks=8): out = tmp @ proj_W^T + proj_b ---
    gemm256<0, true><<<dim3(4, 8, 8), dim3(512), 0, stream>>>(
        tmpb, nullptr, pWb, nullptr, nullptr, nullptr, nullptr, nullptr,
        part2, D_MODEL, D_MODEL, 2 * D_MODEL, 8, 4);
    reduce_out_k<<<2048, blk, 0, stream>>>(part2, proj_b, out);
}

// Round 7
// 731.794 us; speedup vs baseline: 3.9614x; 1.0096x over previous
//
#include <hip/hip_runtime.h>
#include <math.h>

#define D_MODEL 1024
#define D_STATE 16
#define D_CONV  4
#define D_INNER 2048
#define DT_RANK 64
#define BATCH   2
#define SEQLEN  1024
#define MROWS   2048
#define XDBL_LD 128
#define NCHUNK  8
#define CLEN    (SEQLEN / NCHUNK)

typedef __attribute__((ext_vector_type(8))) short bf16x8;
typedef __attribute__((ext_vector_type(4))) float f32x4;

#define BARR() asm volatile("s_barrier" ::: "memory")
#define VMW(n) asm volatile("s_waitcnt vmcnt(" #n ")" ::: "memory")

static __device__ __forceinline__ float sigmoidf_(float x) {
    return 1.f / (1.f + __expf(-x));
}
static __device__ __forceinline__ unsigned short bf16rn(float f) {
    unsigned u = __float_as_uint(f);
    return (unsigned short)((u + 0x7FFFu + ((u >> 16) & 1u)) >> 16);
}
static __device__ __forceinline__ void hl_split(float f, unsigned short& h, unsigned short& l) {
    h = bf16rn(f);
    l = bf16rn(f - __uint_as_float((unsigned)h << 16));
}
static __device__ __forceinline__ float us2f(unsigned short u) {
    return __uint_as_float((unsigned)u << 16);
}

// ---------------------------------------------------------------------------
// fp32 -> bf16 hi|lo split (cols [0,C)=hi, [C,2C)=lo). FLIP = time-reverse.
// ---------------------------------------------------------------------------
template<bool FLIP>
__global__ __launch_bounds__(256)
void split_hl_kernel(const float* __restrict__ in, int R, int C, int ldin,
                     unsigned short* __restrict__ out, int Rout)
{
    int q = blockIdx.x * 256 + threadIdx.x;
    int qpr = C >> 2;
    int row = q / qpr;
    int c4 = (q - row * qpr) << 2;
    if (row >= Rout) return;
    unsigned short h[4] = {0, 0, 0, 0}, l[4] = {0, 0, 0, 0};
    if (row < R) {
        int sr = row;
        if (FLIP) { int b = row >> 10, t = row & 1023; sr = (b << 10) + (1023 - t); }
        float4 v = *(const float4*)(in + (size_t)sr * ldin + c4);
        float f[4] = {v.x, v.y, v.z, v.w};
        #pragma unroll
        for (int i = 0; i < 4; ++i) hl_split(f[i], h[i], l[i]);
    }
    size_t ob = (size_t)row * (2 * C);
    *(ushort4*)(out + ob + c4)     = make_ushort4(h[0], h[1], h[2], h[3]);
    *(ushort4*)(out + ob + C + c4) = make_ushort4(l[0], l[1], l[2], l[3]);
}

// ---------------------------------------------------------------------------
// 256x256 8-phase bf16x3 MFMA GEMM (T2+T3+T4+T5), dual-dir + split-K.
// 512 threads = 8 waves (2M x 4N), BK=64 in 2 kk-halves of 32.
// LDS: AS/BS [2 dbuf][2 kk][256 rows][32] = 64KB each (128KB total).
// Counted vmcnt keeps 4 half-tiles in flight; never drains to 0 mid-loop.
// Swizzle: 16B slot ^= ((row>>1)&3) — row stride is 64B = half the banks,
// so rows alias every 2; period-8 XOR leaves only free 2-way aliasing
// (round-6 bug: (row&3) had period 4 -> 4-way conflict, 9.4M/dispatch).
// Same involution applied to pre-swizzled global source and ds_read.
// ---------------------------------------------------------------------------
#define SWZ(row) (((row) >> 1) & 3)
#define RDA(p, kk, row) (*(const bf16x8*)&AS[p][kk][row][(fs ^ SWZ(row)) << 3])
#define RDB(p, kk, row) (*(const bf16x8*)&BS[p][kk][row][(fs ^ SWZ(row)) << 3])

#define KTILE(MODE, kt) do { \
    const int p_ = (kt) & 1; \
    bf16x8 bF[4]; \
    { /* P1 */ \
        bf16x8 aF[4]; \
        _Pragma("unroll") for (int f = 0; f < 4; ++f) { int rw = wm + f * 16 + fr; aF[f] = RDA(p_, 0, rw); } \
        _Pragma("unroll") for (int g = 0; g < 4; ++g) { int rw = wn + g * 16 + fr; bF[g] = RDB(p_, 0, rw); } \
        if (MODE < 2) stageA((kt) + 1, 1); \
        BARR(); __builtin_amdgcn_s_setprio(1); \
        _Pragma("unroll") for (int f = 0; f < 4; ++f) \
        _Pragma("unroll") for (int g = 0; g < 4; ++g) \
            acc[f][g] = __builtin_amdgcn_mfma_f32_16x16x32_bf16(aF[f], bF[g], acc[f][g], 0, 0, 0); \
        __builtin_amdgcn_s_setprio(0); BARR(); \
    } \
    { /* P2 */ \
        if (MODE == 2) { VMW(0); } else { VMW(8); } \
        bf16x8 aF[4]; \
        _Pragma("unroll") for (int f = 0; f < 4; ++f) { int rw = wm + 64 + f * 16 + fr; aF[f] = RDA(p_, 0, rw); } \
        if (MODE == 0) stageB((kt) + 2, 0); \
        BARR(); __builtin_amdgcn_s_setprio(1); \
        _Pragma("unroll") for (int f = 0; f < 4; ++f) \
        _Pragma("unroll") for (int g = 0; g < 4; ++g) \
            acc[4 + f][g] = __builtin_amdgcn_mfma_f32_16x16x32_bf16(aF[f], bF[g], acc[4 + f][g], 0, 0, 0); \
        __builtin_amdgcn_s_setprio(0); BARR(); \
    } \
    { /* P3 */ \
        bf16x8 aF[4]; \
        _Pragma("unroll") for (int f = 0; f < 4; ++f) { int rw = wm + f * 16 + fr; aF[f] = RDA(p_, 1, rw); } \
        _Pragma("unroll") for (int g = 0; g < 4; ++g) { int rw = wn + g * 16 + fr; bF[g] = RDB(p_, 1, rw); } \
        if (MODE == 0) stageA((kt) + 2, 0); \
        BARR(); __builtin_amdgcn_s_setprio(1); \
        _Pragma("unroll") for (int f = 0; f < 4; ++f) \
        _Pragma("unroll") for (int g = 0; g < 4; ++g) \
            acc[f][g] = __builtin_amdgcn_mfma_f32_16x16x32_bf16(aF[f], bF[g], acc[f][g], 0, 0, 0); \
        __builtin_amdgcn_s_setprio(0); BARR(); \
    } \
    { /* P4 */ \
        if (MODE == 0) { VMW(8); } else if (MODE == 1) { VMW(4); } \
        bf16x8 aF[4]; \
        _Pragma("unroll") for (int f = 0; f < 4; ++f) { int rw = wm + 64 + f * 16 + fr; aF[f] = RDA(p_, 1, rw); } \
        if (MODE == 0) stageB((kt) + 2, 1); \
        BARR(); __builtin_amdgcn_s_setprio(1); \
        _Pragma("unroll") for (int f = 0; f < 4; ++f) \
        _Pragma("unroll") for (int g = 0; g < 4; ++g) \
            acc[4 + f][g] = __builtin_amdgcn_mfma_f32_16x16x32_bf16(aF[f], bF[g], acc[4 + f][g], 0, 0, 0); \
        __builtin_amdgcn_s_setprio(0); BARR(); \
    } \
} while (0)

template<int ACT, bool PART>
__global__ __launch_bounds__(512, 1)
void gemm256(const unsigned short* __restrict__ A0,
             const unsigned short* __restrict__ A1,
             const unsigned short* __restrict__ W0,
             const unsigned short* __restrict__ W1,
             const float* __restrict__ bias0,
             const float* __restrict__ bias1,
             float* __restrict__ C0, float* __restrict__ C1,
             float* __restrict__ part,
             int ldc, int N, int K, int nks, int KTS)
{
    __shared__ unsigned short AS[2][2][256][32];
    __shared__ unsigned short BS[2][2][256][32];

    const int tid = threadIdx.x;
    const int lane = tid & 63;
    const int wid = tid >> 6;

    const int z = blockIdx.z;
    const int dir = z / nks;
    const int ks = z - dir * nks;
    const unsigned short* A = dir ? A1 : A0;
    const unsigned short* W = dir ? W1 : W0;

    const int nbx = gridDim.x;
    const int nwg = nbx * gridDim.y;
    int bid = blockIdx.y * nbx + blockIdx.x;
    int q8 = nwg >> 3;
    int swz = (bid & 7) * q8 + (bid >> 3);
    const int bm = (swz / nbx) * 256;
    const int bn = (swz % nbx) * 256;

    const int ldg = 2 * K;
    const int Kc = KTS * 64;
    const int kbase = ks * Kc;
    const int NT = 3 * KTS;

    const int wm = (wid >> 2) * 128;
    const int wn = (wid & 3) * 64;
    const int fr = lane & 15;
    const int fs = lane >> 4;

    f32x4 acc[8][4];
    #pragma unroll
    for (int i = 0; i < 8; ++i)
        #pragma unroll
        for (int j = 0; j < 4; ++j) {
            f32x4 zv = {0.f, 0.f, 0.f, 0.f};
            acc[i][j] = zv;
        }

    auto koffA = [&](int t) { int sg = t / KTS; int w = t - sg * KTS;
                              return ((sg == 1) ? K : 0) + kbase + w * 64; };
    auto koffB = [&](int t) { int sg = t / KTS; int w = t - sg * KTS;
                              return ((sg == 2) ? K : 0) + kbase + w * 64; };

    auto stageA = [&](int t, int kk) {
        int ko = koffA(t) + kk * 32;
        unsigned short* dst = &AS[t & 1][kk][0][0];
        #pragma unroll
        for (int i = 0; i < 2; ++i) {
            int s = i * 512 + tid;
            int row = s >> 2, sl = s & 3, lsl = sl ^ SWZ(row);
            const unsigned short* src = A + (size_t)(bm + row) * ldg + ko + lsl * 8;
            __builtin_amdgcn_global_load_lds(
                (const __attribute__((address_space(1))) void*)src,
                (__attribute__((address_space(3))) void*)(dst + s * 8), 16, 0, 0);
        }
    };
    auto stageB = [&](int t, int kk) {
        int ko = koffB(t) + kk * 32;
        unsigned short* dst = &BS[t & 1][kk][0][0];
        #pragma unroll
        for (int i = 0; i < 2; ++i) {
            int s = i * 512 + tid;
            int row = s >> 2, sl = s & 3, lsl = sl ^ SWZ(row);
            const unsigned short* src = W + (size_t)(bn + row) * ldg + ko + lsl * 8;
            __builtin_amdgcn_global_load_lds(
                (const __attribute__((address_space(1))) void*)src,
                (__attribute__((address_space(3))) void*)(dst + s * 8), 16, 0, 0);
        }
    };

    // prologue: 7 half-tiles (K-tile 0 complete + 3/4 of K-tile 1)
    stageB(0, 0); stageA(0, 0); stageB(0, 1); stageA(0, 1);
    stageB(1, 0); stageA(1, 0); stageB(1, 1);
    VMW(6);
    BARR();

    for (int kt = 0; kt < NT - 2; ++kt) KTILE(0, kt);
    KTILE(1, NT - 2);
    KTILE(2, NT - 1);

    if (PART) {
        float* P = part + (size_t)z * ((size_t)MROWS * N);
        #pragma unroll
        for (int i = 0; i < 8; ++i)
            #pragma unroll
            for (int j = 0; j < 4; ++j) {
                int coln = bn + wn + j * 16 + fr;
                #pragma unroll
                for (int r = 0; r < 4; ++r) {
                    int rowm = bm + wm + i * 16 + fs * 4 + r;
                    P[(size_t)rowm * N + coln] = acc[i][j][r];
                }
            }
    } else {
        const float* bias = dir ? bias1 : bias0;
        float* C = dir ? C1 : C0;
        #pragma unroll
        for (int i = 0; i < 8; ++i)
            #pragma unroll
            for (int j = 0; j < 4; ++j) {
                int coln = bn + wn + j * 16 + fr;
                float bv = bias ? bias[coln] : 0.f;
                #pragma unroll
                for (int r = 0; r < 4; ++r) {
                    int rowm = bm + wm + i * 16 + fs * 4 + r;
                    float v = acc[i][j][r] + bv;
                    if (ACT == 1) v = (v > 20.f) ? v : log1pf(__expf(v));
                    C[(size_t)rowm * ldc + coln] = v;
                }
            }
    }
}

// ---------------------------------------------------------------------------
// 128x128 bf16x3 MFMA GEMM (2-barrier structure) for small shapes.
// ---------------------------------------------------------------------------
template<int ACT, bool PART>
__global__ __launch_bounds__(256)
void gemm_mfma(const unsigned short* __restrict__ A0,
               const unsigned short* __restrict__ A1,
               const unsigned short* __restrict__ W0,
               const unsigned short* __restrict__ W1,
               const float* __restrict__ bias0,
               const float* __restrict__ bias1,
               float* __restrict__ C0, float* __restrict__ C1,
               float* __restrict__ part,
               int ldc, int N, int K, int nks)
{
    __shared__ __align__(16) unsigned short As[128 * 32];
    __shared__ __align__(16) unsigned short Bs[128 * 32];

    const int tid = threadIdx.x;
    const int lane = tid & 63;
    const int wid = tid >> 6;

    const int z = blockIdx.z;
    const int dir = z / nks;
    const int ks = z - dir * nks;
    const unsigned short* A = dir ? A1 : A0;
    const unsigned short* W = dir ? W1 : W0;

    const int nbx = gridDim.x;
    const int nwg = nbx * gridDim.y;
    int bid = blockIdx.y * nbx + blockIdx.x;
    int q8 = nwg >> 3;
    int swz = (nwg >= 8) ? (bid & 7) * q8 + (bid >> 3) : bid;
    const int bm = (swz / nbx) * 128;
    const int bn = (swz % nbx) * 128;

    const int ldg = 2 * K;
    const int Kc = K / nks;
    const int kbase = ks * Kc;

    f32x4 acc[4][4];
    #pragma unroll
    for (int i = 0; i < 4; ++i)
        #pragma unroll
        for (int j = 0; j < 4; ++j) {
            f32x4 zv = {0.f, 0.f, 0.f, 0.f};
            acc[i][j] = zv;
        }

    const int r0 = tid >> 2;
    const int k0s = (tid & 3) ^ ((r0 >> 1) & 3);
    const int r1 = (256 + tid) >> 2;
    const int k1s = (tid & 3) ^ ((r1 >> 1) & 3);

    unsigned short* As_w0 = &As[(wid << 6) * 8];
    unsigned short* As_w1 = &As[(256 + (wid << 6)) * 8];
    unsigned short* Bs_w0 = &Bs[(wid << 6) * 8];
    unsigned short* Bs_w1 = &Bs[(256 + (wid << 6)) * 8];

    const int wm = (wid >> 1) * 64;
    const int wn = (wid & 1) * 64;
    const int fr = lane & 15;
    const int fs = lane >> 4;

    const int KS = Kc >> 5;
    #pragma unroll 1
    for (int seg = 0; seg < 3; ++seg) {
        const int aoff = ((seg == 1) ? K : 0) + kbase;
        const int boff = ((seg == 2) ? K : 0) + kbase;
        #pragma unroll 1
        for (int kt = 0; kt < KS; ++kt) {
            const int kk = kt << 5;
            const unsigned short* ga0 = A + (size_t)(bm + r0) * ldg + aoff + kk + k0s * 8;
            const unsigned short* ga1 = A + (size_t)(bm + r1) * ldg + aoff + kk + k1s * 8;
            const unsigned short* gw0 = W + (size_t)(bn + r0) * ldg + boff + kk + k0s * 8;
            const unsigned short* gw1 = W + (size_t)(bn + r1) * ldg + boff + kk + k1s * 8;
            __builtin_amdgcn_global_load_lds(
                (const __attribute__((address_space(1))) void*)ga0,
                (__attribute__((address_space(3))) void*)As_w0, 16, 0, 0);
            __builtin_amdgcn_global_load_lds(
                (const __attribute__((address_space(1))) void*)ga1,
                (__attribute__((address_space(3))) void*)As_w1, 16, 0, 0);
            __builtin_amdgcn_global_load_lds(
                (const __attribute__((address_space(1))) void*)gw0,
                (__attribute__((address_space(3))) void*)Bs_w0, 16, 0, 0);
            __builtin_amdgcn_global_load_lds(
                (const __attribute__((address_space(1))) void*)gw1,
                (__attribute__((address_space(3))) void*)Bs_w1, 16, 0, 0);
            __syncthreads();

            bf16x8 aF[4], bF[4];
            #pragma unroll
            for (int f = 0; f < 4; ++f) {
                int ra = wm + f * 16 + fr;
                int sa = fs ^ ((ra >> 1) & 3);
                aF[f] = *(const bf16x8*)&As[ra * 32 + sa * 8];
                int rb = wn + f * 16 + fr;
                int sb = fs ^ ((rb >> 1) & 3);
                bF[f] = *(const bf16x8*)&Bs[rb * 32 + sb * 8];
            }
            #pragma unroll
            for (int i = 0; i < 4; ++i)
                #pragma unroll
                for (int j = 0; j < 4; ++j)
                    acc[i][j] = __builtin_amdgcn_mfma_f32_16x16x32_bf16(
                        aF[i], bF[j], acc[i][j], 0, 0, 0);
            __syncthreads();
        }
    }

    if (PART) {
        float* P = part + (size_t)z * ((size_t)MROWS * N);
        #pragma unroll
        for (int i = 0; i < 4; ++i)
            #pragma unroll
            for (int j = 0; j < 4; ++j) {
                int coln = bn + wn + j * 16 + fr;
                #pragma unroll
                for (int r = 0; r < 4; ++r) {
                    int rowm = bm + wm + i * 16 + fs * 4 + r;
                    P[(size_t)rowm * N + coln] = acc[i][j][r];
                }
            }
    } else {
        const float* bias = dir ? bias1 : bias0;
        float* C = dir ? C1 : C0;
        #pragma unroll
        for (int i = 0; i < 4; ++i)
            #pragma unroll
            for (int j = 0; j < 4; ++j) {
                int coln = bn + wn + j * 16 + fr;
                float bv = bias ? bias[coln] : 0.f;
                #pragma unroll
                for (int r = 0; r < 4; ++r) {
                    int rowm = bm + wm + i * 16 + fs * 4 + r;
                    float v = acc[i][j][r] + bv;
                    if (ACT == 1) v = (v > 20.f) ? v : log1pf(__expf(v));
                    C[(size_t)rowm * ldc + coln] = v;
                }
            }
    }
}

// ---------------------------------------------------------------------------
// Split-K reduces with fused epilogues.
// ---------------------------------------------------------------------------
__global__ __launch_bounds__(256)
void reduce_xdbl_k(const float* __restrict__ part,
                   float* __restrict__ xdbl, unsigned short* __restrict__ dtb)
{
    int i = blockIdx.x * 256 + threadIdx.x;
    int row = i >> 5;
    int c4 = (i & 31) << 2;
    float4 s = make_float4(0.f, 0.f, 0.f, 0.f);
    #pragma unroll
    for (int k = 0; k < 16; ++k) {
        float4 v = *(const float4*)(part + (size_t)k * MROWS * XDBL_LD + (size_t)row * XDBL_LD + c4);
        s.x += v.x; s.y += v.y; s.z += v.z; s.w += v.w;
    }
    *(float4*)(xdbl + (size_t)row * XDBL_LD + c4) = s;
    if (c4 < DT_RANK) {
        float f[4] = {s.x, s.y, s.z, s.w};
        unsigned short h[4], l[4];
        #pragma unroll
        for (int j = 0; j < 4; ++j) hl_split(f[j], h[j], l[j]);
        *(ushort4*)(dtb + (size_t)row * (2 * DT_RANK) + c4) = make_ushort4(h[0], h[1], h[2], h[3]);
        *(ushort4*)(dtb + (size_t)row * (2 * DT_RANK) + DT_RANK + c4) = make_ushort4(l[0], l[1], l[2], l[3]);
    }
}

template<bool FLIP>
__global__ __launch_bounds__(256)
void reduce_tmpb_k(const float* __restrict__ part, const float* __restrict__ bias,
                   unsigned short* __restrict__ tmpb, int colofs)
{
    int i = blockIdx.x * 256 + threadIdx.x;
    int row = i >> 8;
    int c4 = (i & 255) << 2;
    float4 s = make_float4(bias[c4], bias[c4 + 1], bias[c4 + 2], bias[c4 + 3]);
    #pragma unroll
    for (int k = 0; k < 4; ++k) {
        float4 v = *(const float4*)(part + (size_t)k * MROWS * D_MODEL + (size_t)row * D_MODEL + c4);
        s.x += v.x; s.y += v.y; s.z += v.z; s.w += v.w;
    }
    int orow = row;
    if (FLIP) { int bb = row >> 10, t = row & 1023; orow = (bb << 10) + 1023 - t; }
    float f[4] = {s.x, s.y, s.z, s.w};
    unsigned short h[4], l[4];
    #pragma unroll
    for (int j = 0; j < 4; ++j) hl_split(f[j], h[j], l[j]);
    *(ushort4*)(tmpb + (size_t)orow * 4096 + colofs + c4) = make_ushort4(h[0], h[1], h[2], h[3]);
    *(ushort4*)(tmpb + (size_t)orow * 4096 + 2048 + colofs + c4) = make_ushort4(l[0], l[1], l[2], l[3]);
}

__global__ __launch_bounds__(256)
void reduce_out_k(const float* __restrict__ part, const float* __restrict__ bias,
                  float* __restrict__ out)
{
    int i = blockIdx.x * 256 + threadIdx.x;
    int row = i >> 8;
    int c4 = (i & 255) << 2;
    float4 s = make_float4(bias[c4], bias[c4 + 1], bias[c4 + 2], bias[c4 + 3]);
    #pragma unroll
    for (int k = 0; k < 8; ++k) {
        float4 v = *(const float4*)(part + (size_t)k * MROWS * D_MODEL + (size_t)row * D_MODEL + c4);
        s.x += v.x; s.y += v.y; s.z += v.z; s.w += v.w;
    }
    *(float4*)(out + (size_t)row * D_MODEL + c4) = s;
}

// ---------------------------------------------------------------------------
// Causal depthwise conv + SiLU -> ub (hi|lo bf16).
// ---------------------------------------------------------------------------
__global__ __launch_bounds__(256)
void conv_silu_kernel(const float* __restrict__ xz,
                      const float* __restrict__ convw,
                      const float* __restrict__ convb,
                      unsigned short* __restrict__ ub)
{
    int idx = blockIdx.x * 256 + threadIdx.x;
    int d = idx % D_INNER;
    int r = idx / D_INNER;
    int t = r % SEQLEN;
    float acc = convb[d];
    #pragma unroll
    for (int k = 0; k < D_CONV; ++k) {
        int back = D_CONV - 1 - k;
        if (t - back >= 0)
            acc += xz[(size_t)(r - back) * (2 * D_INNER) + d] * convw[d * D_CONV + k];
    }
    float v = acc * sigmoidf_(acc);
    unsigned short h, l;
    hl_split(v, h, l);
    ub[(size_t)r * (2 * D_INNER) + d] = h;
    ub[(size_t)r * (2 * D_INNER) + D_INNER + d] = l;
}

// ---------------------------------------------------------------------------
// Chunked selective scan (3 phases); u reconstructed from ub hi+lo.
// ---------------------------------------------------------------------------
__global__ __launch_bounds__(256)
void scan_phase1(const float* __restrict__ delta,
                 const unsigned short* __restrict__ ub,
                 const float* __restrict__ xdbl,
                 const float* __restrict__ Alog,
                 float* __restrict__ aprod,
                 float* __restrict__ hfin)
{
    const int tid = threadIdx.x;
    const int ch = blockIdx.x * 16 + (tid >> 4);
    const int n = tid & 15;
    const int chunk = blockIdx.y;
    const int b = ch / D_INNER;
    const int d = ch % D_INNER;

    const float Av = -__expf(Alog[d * D_STATE + n]);
    float h = 0.f, ap = 1.f;
    const int t0 = chunk * CLEN;
    for (int t = t0; t < t0 + CLEN; ++t) {
        const size_t r = (size_t)b * SEQLEN + t;
        float dlt = delta[r * D_INNER + d];
        float uu = us2f(ub[r * (2 * D_INNER) + d]) + us2f(ub[r * (2 * D_INNER) + D_INNER + d]);
        float Bv = xdbl[r * XDBL_LD + DT_RANK + n];
        float dA = __expf(dlt * Av);
        h = h * dA + (dlt * uu) * Bv;
        ap *= dA;
    }
    const size_t idx = ((size_t)ch * D_STATE + n) * NCHUNK + chunk;
    aprod[idx] = ap;
    hfin[idx] = h;
}

__global__ __launch_bounds__(256)
void scan_phase2(const float* __restrict__ aprod,
                 const float* __restrict__ hfin,
                 float* __restrict__ hin)
{
    const int gid = blockIdx.x * 256 + threadIdx.x;
    const size_t base = (size_t)gid * NCHUNK;
    float h = 0.f;
    #pragma unroll
    for (int c = 0; c < NCHUNK; ++c) {
        hin[base + c] = h;
        h = aprod[base + c] * h + hfin[base + c];
    }
}

__global__ __launch_bounds__(256)
void scan_phase3(const float* __restrict__ delta,
                 unsigned short* __restrict__ ub,
                 const float* __restrict__ xdbl,
                 const float* __restrict__ Alog,
                 const float* __restrict__ Dsk,
                 const float* __restrict__ xz,
                 const float* __restrict__ hin)
{
    const int tid = threadIdx.x;
    const int ch = blockIdx.x * 16 + (tid >> 4);
    const int n = tid & 15;
    const int chunk = blockIdx.y;
    const int b = ch / D_INNER;
    const int d = ch % D_INNER;

    const float Av = -__expf(Alog[d * D_STATE + n]);
    const float Dv = Dsk[d];
    float h = hin[((size_t)ch * D_STATE + n) * NCHUNK + chunk];
    const int t0 = chunk * CLEN;
    for (int t = t0; t < t0 + CLEN; ++t) {
        const size_t r = (size_t)b * SEQLEN + t;
        float dlt = delta[r * D_INNER + d];
        float uu = us2f(ub[r * (2 * D_INNER) + d]) + us2f(ub[r * (2 * D_INNER) + D_INNER + d]);
        float Bv = xdbl[r * XDBL_LD + DT_RANK + n];
        float Cv = xdbl[r * XDBL_LD + DT_RANK + D_STATE + n];
        float dA = __expf(dlt * Av);
        h = h * dA + (dlt * uu) * Bv;
        float p = h * Cv;
        p += __shfl_xor(p, 1, 16);
        p += __shfl_xor(p, 2, 16);
        p += __shfl_xor(p, 4, 16);
        p += __shfl_xor(p, 8, 16);
        if (n == 0) {
            float zv = xz[r * (2 * D_INNER) + D_INNER + d];
            float v = (p + uu * Dv) * (zv * sigmoidf_(zv));
            unsigned short hh, ll;
            hl_split(v, hh, ll);
            ub[r * (2 * D_INNER) + d] = hh;
            ub[r * (2 * D_INNER) + D_INNER + d] = ll;
        }
    }
}

// ---------------------------------------------------------------------------
extern "C" void kernel_launch(void* const* d_in, const int* in_sizes, int n_in,
                              void* d_out, int out_size, void* d_ws, size_t ws_size,
                              hipStream_t stream)
{
    const float* x = (const float*)d_in[0];
    const float* proj_W = (const float*)d_in[23];
    const float* proj_b = (const float*)d_in[24];
    float* out = (float*)d_out;

    const float *Win[2], *bin_[2], *convw[2], *convb[2], *Wx[2], *Wdt[2], *bdt[2],
                *Alog[2], *Dsk[2], *Wout[2], *bout[2];
    for (int dir = 0; dir < 2; ++dir) {
        const int base = 1 + dir * 11;
        Win[dir]   = (const float*)d_in[base + 0];
        bin_[dir]  = (const float*)d_in[base + 1];
        convw[dir] = (const float*)d_in[base + 2];
        convb[dir] = (const float*)d_in[base + 3];
        Wx[dir]    = (const float*)d_in[base + 4];
        Wdt[dir]   = (const float*)d_in[base + 5];
        bdt[dir]   = (const float*)d_in[base + 6];
        Alog[dir]  = (const float*)d_in[base + 7];
        Dsk[dir]   = (const float*)d_in[base + 8];
        Wout[dir]  = (const float*)d_in[base + 9];
        bout[dir]  = (const float*)d_in[base + 10];
    }

    // ---- explicit arena (lifetime-checked overlays) ----
    char* ws = (char*)d_ws;
    const size_t MB = 1ull << 20;
    float* xz[2]            = {(float*)(ws + 0 * MB),   (float*)(ws + 32 * MB)};   // [0,64)
    unsigned short* ub[2]   = {(unsigned short*)(ws + 64 * MB),
                               (unsigned short*)(ws + 80 * MB)};                   // [64,96)
    unsigned short* Winb[2] = {(unsigned short*)(ws + 96 * MB),
                               (unsigned short*)(ws + 112 * MB)};                  // [96,128)
    unsigned short* xc[2]   = {(unsigned short*)(ws + 128 * MB),
                               (unsigned short*)(ws + 136 * MB)};                  // [128,144)
    // overlays:
    float* part             = (float*)(ws + 112 * MB);          // [112,144) after gemm1 (xproj)
    float* part2            = (float*)(ws + 0 * MB);            // [0,64) after scan3 (xz dead)
    float* delta[2]         = {(float*)(ws + 112 * MB), (float*)(ws + 128 * MB)};
    unsigned short* Woutb[2]= {(unsigned short*)(ws + 96 * MB),
                               (unsigned short*)(ws + 104 * MB)};                  // in Winb0
    unsigned short* yzb[2]  = {ub[0], ub[1]};                   // in-place scan3
    unsigned short* tmpb    = ub[0];                            // after gemm6
    unsigned short* pWb     = ub[1];
    // smalls [144,162):
    unsigned short* Wxb[2]  = {(unsigned short*)(ws + 144 * MB), (unsigned short*)(ws + 145 * MB)};
    unsigned short* Wdtb[2] = {(unsigned short*)(ws + 146 * MB), (unsigned short*)(ws + 146 * MB + 512 * 1024)};
    unsigned short* dtb[2]  = {(unsigned short*)(ws + 147 * MB), (unsigned short*)(ws + 147 * MB + 512 * 1024)};
    float* xdbl[2]          = {(float*)(ws + 148 * MB), (float*)(ws + 149 * MB)};
    float* aprod[2]         = {(float*)(ws + 150 * MB), (float*)(ws + 156 * MB)};
    float* hfin[2]          = {(float*)(ws + 152 * MB), (float*)(ws + 158 * MB)};
    float* hin[2]           = {(float*)(ws + 154 * MB), (float*)(ws + 160 * MB)};

    dim3 blk(256);
    const dim3 scan_grid(BATCH * D_INNER / 16, NCHUNK);

    // --- conversions needed before gemm1 ---
    split_hl_kernel<false><<<2048, blk, 0, stream>>>(x, MROWS, D_MODEL, D_MODEL, xc[0], MROWS);
    split_hl_kernel<true ><<<2048, blk, 0, stream>>>(x, MROWS, D_MODEL, D_MODEL, xc[1], MROWS);
    for (int d = 0; d < 2; ++d) {
        split_hl_kernel<false><<<4096, blk, 0, stream>>>(Win[d], 4096, D_MODEL, D_MODEL, Winb[d], 4096);
        split_hl_kernel<false><<<256,  blk, 0, stream>>>(Wx[d], DT_RANK + 2 * D_STATE, D_INNER, D_INNER, Wxb[d], XDBL_LD);
        split_hl_kernel<false><<<128,  blk, 0, stream>>>(Wdt[d], D_INNER, DT_RANK, DT_RANK, Wdtb[d], D_INNER);
    }

    // --- 1. input proj (8-phase 256²), both dirs: xz = x' @ Win'^T + bin ---
    gemm256<0, false><<<dim3(16, 8, 2), dim3(512), 0, stream>>>(
        xc[0], xc[1], Winb[0], Winb[1], bin_[0], bin_[1], xz[0], xz[1],
        nullptr, 4096, 4096, D_MODEL, 1, 16);

    // Wout conversions (into Winb0 region — after gemm1 in stream order)
    for (int d = 0; d < 2; ++d)
        split_hl_kernel<false><<<2048, blk, 0, stream>>>(Wout[d], D_MODEL, D_INNER, D_INNER, Woutb[d], D_MODEL);

    // --- 2. conv + silu -> ub hi/lo ---
    for (int d = 0; d < 2; ++d)
        conv_silu_kernel<<<(MROWS * D_INNER) / 256, blk, 0, stream>>>(
            xz[d], convw[d], convb[d], ub[d]);

    // --- 3. xproj split-K (128², nks=16, both dirs): part -> xdbl + dtb ---
    gemm_mfma<0, true><<<dim3(1, 16, 32), blk, 0, stream>>>(
        ub[0], ub[1], Wxb[0], Wxb[1], nullptr, nullptr, nullptr, nullptr,
        part, XDBL_LD, XDBL_LD, D_INNER, 16);
    for (int d = 0; d < 2; ++d)
        reduce_xdbl_k<<<256, blk, 0, stream>>>(
            part + (size_t)d * 16 * MROWS * XDBL_LD, xdbl[d], dtb[d]);

    // --- 4. dt proj (128²), both dirs: delta = softplus(dt @ Wdt^T + bdt) ---
    gemm_mfma<1, false><<<dim3(16, 16, 2), blk, 0, stream>>>(
        dtb[0], dtb[1], Wdtb[0], Wdtb[1], bdt[0], bdt[1], delta[0], delta[1],
        nullptr, D_INNER, D_INNER, DT_RANK, 1);

    // --- 5. chunked scan + gate (in-place ub -> yzb) ---
    for (int d = 0; d < 2; ++d) {
        scan_phase1<<<scan_grid, blk, 0, stream>>>(delta[d], ub[d], xdbl[d], Alog[d], aprod[d], hfin[d]);
        scan_phase2<<<BATCH * D_INNER * D_STATE / 256, blk, 0, stream>>>(aprod[d], hfin[d], hin[d]);
        scan_phase3<<<scan_grid, blk, 0, stream>>>(delta[d], ub[d], xdbl[d], Alog[d], Dsk[d], xz[d], hin[d]);
    }

    // --- 6. out proj (8-phase 256², nks=4, both dirs) -> part2 [xz dead] ---
    gemm256<0, true><<<dim3(4, 8, 8), dim3(512), 0, stream>>>(
        yzb[0], yzb[1], Woutb[0], Woutb[1], nullptr, nullptr, nullptr, nullptr,
        part2, D_MODEL, D_MODEL, D_INNER, 4, 8);
    reduce_tmpb_k<false><<<2048, blk, 0, stream>>>(part2, bout[0], tmpb, 0);
    reduce_tmpb_k<true ><<<2048, blk, 0, stream>>>(
        part2 + (size_t)4 * MROWS * D_MODEL, bout[1], tmpb, D_MODEL);

    // pW conversion (into ub1 region — yzb1 dead after gemm6)
    split_hl_kernel<false><<<2048, blk, 0, stream>>>(proj_W, D_MODEL, 2 * D_MODEL, 2 * D_MODEL, pWb, D_MODEL);

    // --- 7. final proj (8-phase 256², nks=8): out = tmp @ proj_W^T + proj_b ---
    gemm256<0, true><<<dim3(4, 8, 8), dim3(512), 0, stream>>>(
        tmpb, nullptr, pWb, nullptr, nullptr, nullptr, nullptr, nullptr,
        part2, D_MODEL, D_MODEL, 2 * D_MODEL, 8, 4);
    reduce_out_k<<<2048, blk, 0, stream>>>(part2, proj_b, out);
}

// Round 8
// 697.426 us; speedup vs baseline: 4.1566x; 1.0493x over previous
//
#include <hip/hip_runtime.h>
#include <math.h>

#define D_MODEL 1024
#define D_STATE 16
#define D_CONV  4
#define D_INNER 2048
#define DT_RANK 64
#define BATCH   2
#define SEQLEN  1024
#define MROWS   2048
#define XDBL_LD 128
#define NCHUNK  8
#define CLEN    (SEQLEN / NCHUNK)

typedef __attribute__((ext_vector_type(8))) short bf16x8;
typedef __attribute__((ext_vector_type(4))) float f32x4;

#define BARR() asm volatile("s_barrier" ::: "memory")
#define VMW(n) asm volatile("s_waitcnt vmcnt(" #n ")" ::: "memory")

static __device__ __forceinline__ float sigmoidf_(float x) {
    return 1.f / (1.f + __expf(-x));
}
static __device__ __forceinline__ unsigned short bf16rn(float f) {
    unsigned u = __float_as_uint(f);
    return (unsigned short)((u + 0x7FFFu + ((u >> 16) & 1u)) >> 16);
}
static __device__ __forceinline__ void hl_split(float f, unsigned short& h, unsigned short& l) {
    h = bf16rn(f);
    l = bf16rn(f - __uint_as_float((unsigned)h << 16));
}
static __device__ __forceinline__ float us2f(unsigned short u) {
    return __uint_as_float((unsigned)u << 16);
}

// ---------------------------------------------------------------------------
// Shared split worker: fp32 (R x C) -> bf16 (Rout x 2C) hi|lo. blk-local idx.
// ---------------------------------------------------------------------------
static __device__ __forceinline__
void split_block(const float* __restrict__ in, int R, int C, int ldin,
                 unsigned short* __restrict__ out, int Rout, bool flip,
                 int blk, int tid)
{
    int q = blk * 256 + tid;
    int qpr = C >> 2;
    int row = q / qpr;
    int c4 = (q - row * qpr) << 2;
    if (row >= Rout) return;
    unsigned short h[4] = {0, 0, 0, 0}, l[4] = {0, 0, 0, 0};
    if (row < R) {
        int sr = row;
        if (flip) { int b = row >> 10, t = row & 1023; sr = (b << 10) + (1023 - t); }
        float4 v = *(const float4*)(in + (size_t)sr * ldin + c4);
        float f[4] = {v.x, v.y, v.z, v.w};
        #pragma unroll
        for (int i = 0; i < 4; ++i) hl_split(f[i], h[i], l[i]);
    }
    size_t ob = (size_t)row * (2 * C);
    *(ushort4*)(out + ob + c4)     = make_ushort4(h[0], h[1], h[2], h[3]);
    *(ushort4*)(out + ob + C + c4) = make_ushort4(l[0], l[1], l[2], l[3]);
}

// prep1: all pre-GEMM conversions in one launch (block-range dispatch).
// ranges: x->xc0 [0,2048), x->xc1 flip [2048,4096), Win0 [4096,8192),
// Win1 [8192,12288), Wx0 [12288,12544), Wx1 [12544,12800),
// Wdt0 [12800,12928), Wdt1 [12928,13056)
__global__ __launch_bounds__(256)
void prep1_kernel(const float* __restrict__ x,
                  const float* __restrict__ Win0, const float* __restrict__ Win1,
                  const float* __restrict__ Wx0,  const float* __restrict__ Wx1,
                  const float* __restrict__ Wdt0, const float* __restrict__ Wdt1,
                  unsigned short* xc0, unsigned short* xc1,
                  unsigned short* Winb0, unsigned short* Winb1,
                  unsigned short* Wxb0, unsigned short* Wxb1,
                  unsigned short* Wdtb0, unsigned short* Wdtb1)
{
    int b = blockIdx.x, tid = threadIdx.x;
    if      (b < 2048)  split_block(x,    MROWS, D_MODEL, D_MODEL, xc0,  MROWS, false, b,        tid);
    else if (b < 4096)  split_block(x,    MROWS, D_MODEL, D_MODEL, xc1,  MROWS, true,  b - 2048, tid);
    else if (b < 8192)  split_block(Win0, 4096,  D_MODEL, D_MODEL, Winb0, 4096, false, b - 4096, tid);
    else if (b < 12288) split_block(Win1, 4096,  D_MODEL, D_MODEL, Winb1, 4096, false, b - 8192, tid);
    else if (b < 12544) split_block(Wx0,  96,    D_INNER, D_INNER, Wxb0,  128,  false, b - 12288, tid);
    else if (b < 12800) split_block(Wx1,  96,    D_INNER, D_INNER, Wxb1,  128,  false, b - 12544, tid);
    else if (b < 12928) split_block(Wdt0, D_INNER, DT_RANK, DT_RANK, Wdtb0, D_INNER, false, b - 12800, tid);
    else                split_block(Wdt1, D_INNER, DT_RANK, DT_RANK, Wdtb1, D_INNER, false, b - 12928, tid);
}

// prep2: Wout conversions (after input-proj gemm; overlays Winb region).
__global__ __launch_bounds__(256)
void prep2_kernel(const float* __restrict__ Wout0, const float* __restrict__ Wout1,
                  unsigned short* Woutb0, unsigned short* Woutb1)
{
    int b = blockIdx.x, tid = threadIdx.x;
    if (b < 2048) split_block(Wout0, D_MODEL, D_INNER, D_INNER, Woutb0, D_MODEL, false, b, tid);
    else          split_block(Wout1, D_MODEL, D_INNER, D_INNER, Woutb1, D_MODEL, false, b - 2048, tid);
}

// ---------------------------------------------------------------------------
// 256x256 8-phase bf16x3 MFMA GEMM (T2+T3+T4+T5), dual-dir + split-K.
// Swizzle: 16B slot ^= ((row>>1)&3) both sides (conflict-free, r7 verified).
// Counted vmcnt keeps 4-6 half-tiles in flight; never drains to 0 mid-loop.
// ---------------------------------------------------------------------------
#define SWZ(row) (((row) >> 1) & 3)
#define RDA(p, kk, row) (*(const bf16x8*)&AS[p][kk][row][(fs ^ SWZ(row)) << 3])
#define RDB(p, kk, row) (*(const bf16x8*)&BS[p][kk][row][(fs ^ SWZ(row)) << 3])

#define KTILE(MODE, kt) do { \
    const int p_ = (kt) & 1; \
    bf16x8 bF[4]; \
    { /* P1 */ \
        bf16x8 aF[4]; \
        _Pragma("unroll") for (int f = 0; f < 4; ++f) { int rw = wm + f * 16 + fr; aF[f] = RDA(p_, 0, rw); } \
        _Pragma("unroll") for (int g = 0; g < 4; ++g) { int rw = wn + g * 16 + fr; bF[g] = RDB(p_, 0, rw); } \
        if (MODE < 2) stageA((kt) + 1, 1); \
        BARR(); __builtin_amdgcn_s_setprio(1); \
        _Pragma("unroll") for (int f = 0; f < 4; ++f) \
        _Pragma("unroll") for (int g = 0; g < 4; ++g) \
            acc[f][g] = __builtin_amdgcn_mfma_f32_16x16x32_bf16(aF[f], bF[g], acc[f][g], 0, 0, 0); \
        __builtin_amdgcn_s_setprio(0); BARR(); \
    } \
    { /* P2 */ \
        if (MODE == 2) { VMW(0); } else { VMW(8); } \
        bf16x8 aF[4]; \
        _Pragma("unroll") for (int f = 0; f < 4; ++f) { int rw = wm + 64 + f * 16 + fr; aF[f] = RDA(p_, 0, rw); } \
        if (MODE == 0) stageB((kt) + 2, 0); \
        BARR(); __builtin_amdgcn_s_setprio(1); \
        _Pragma("unroll") for (int f = 0; f < 4; ++f) \
        _Pragma("unroll") for (int g = 0; g < 4; ++g) \
            acc[4 + f][g] = __builtin_amdgcn_mfma_f32_16x16x32_bf16(aF[f], bF[g], acc[4 + f][g], 0, 0, 0); \
        __builtin_amdgcn_s_setprio(0); BARR(); \
    } \
    { /* P3 */ \
        bf16x8 aF[4]; \
        _Pragma("unroll") for (int f = 0; f < 4; ++f) { int rw = wm + f * 16 + fr; aF[f] = RDA(p_, 1, rw); } \
        _Pragma("unroll") for (int g = 0; g < 4; ++g) { int rw = wn + g * 16 + fr; bF[g] = RDB(p_, 1, rw); } \
        if (MODE == 0) stageA((kt) + 2, 0); \
        BARR(); __builtin_amdgcn_s_setprio(1); \
        _Pragma("unroll") for (int f = 0; f < 4; ++f) \
        _Pragma("unroll") for (int g = 0; g < 4; ++g) \
            acc[f][g] = __builtin_amdgcn_mfma_f32_16x16x32_bf16(aF[f], bF[g], acc[f][g], 0, 0, 0); \
        __builtin_amdgcn_s_setprio(0); BARR(); \
    } \
    { /* P4 */ \
        if (MODE == 0) { VMW(8); } else if (MODE == 1) { VMW(4); } \
        bf16x8 aF[4]; \
        _Pragma("unroll") for (int f = 0; f < 4; ++f) { int rw = wm + 64 + f * 16 + fr; aF[f] = RDA(p_, 1, rw); } \
        if (MODE == 0) stageB((kt) + 2, 1); \
        BARR(); __builtin_amdgcn_s_setprio(1); \
        _Pragma("unroll") for (int f = 0; f < 4; ++f) \
        _Pragma("unroll") for (int g = 0; g < 4; ++g) \
            acc[4 + f][g] = __builtin_amdgcn_mfma_f32_16x16x32_bf16(aF[f], bF[g], acc[4 + f][g], 0, 0, 0); \
        __builtin_amdgcn_s_setprio(0); BARR(); \
    } \
} while (0)

template<int ACT, bool PART>
__global__ __launch_bounds__(512, 1)
void gemm256(const unsigned short* __restrict__ A0,
             const unsigned short* __restrict__ A1,
             const unsigned short* __restrict__ W0,
             const unsigned short* __restrict__ W1,
             const float* __restrict__ bias0,
             const float* __restrict__ bias1,
             float* __restrict__ C0, float* __restrict__ C1,
             float* __restrict__ part,
             int ldc, int N, int K, int nks, int KTS)
{
    __shared__ unsigned short AS[2][2][256][32];
    __shared__ unsigned short BS[2][2][256][32];

    const int tid = threadIdx.x;
    const int lane = tid & 63;
    const int wid = tid >> 6;

    const int z = blockIdx.z;
    const int dir = z / nks;
    const int ks = z - dir * nks;
    const unsigned short* A = dir ? A1 : A0;
    const unsigned short* W = dir ? W1 : W0;

    const int nbx = gridDim.x;
    const int nwg = nbx * gridDim.y;
    int bid = blockIdx.y * nbx + blockIdx.x;
    int q8 = nwg >> 3;
    int swz = (bid & 7) * q8 + (bid >> 3);
    const int bm = (swz / nbx) * 256;
    const int bn = (swz % nbx) * 256;

    const int ldg = 2 * K;
    const int Kc = KTS * 64;
    const int kbase = ks * Kc;
    const int NT = 3 * KTS;

    const int wm = (wid >> 2) * 128;
    const int wn = (wid & 3) * 64;
    const int fr = lane & 15;
    const int fs = lane >> 4;

    f32x4 acc[8][4];
    #pragma unroll
    for (int i = 0; i < 8; ++i)
        #pragma unroll
        for (int j = 0; j < 4; ++j) {
            f32x4 zv = {0.f, 0.f, 0.f, 0.f};
            acc[i][j] = zv;
        }

    auto koffA = [&](int t) { int sg = t / KTS; int w = t - sg * KTS;
                              return ((sg == 1) ? K : 0) + kbase + w * 64; };
    auto koffB = [&](int t) { int sg = t / KTS; int w = t - sg * KTS;
                              return ((sg == 2) ? K : 0) + kbase + w * 64; };

    auto stageA = [&](int t, int kk) {
        int ko = koffA(t) + kk * 32;
        unsigned short* dst = &AS[t & 1][kk][0][0];
        #pragma unroll
        for (int i = 0; i < 2; ++i) {
            int s = i * 512 + tid;
            int row = s >> 2, sl = s & 3, lsl = sl ^ SWZ(row);
            const unsigned short* src = A + (size_t)(bm + row) * ldg + ko + lsl * 8;
            __builtin_amdgcn_global_load_lds(
                (const __attribute__((address_space(1))) void*)src,
                (__attribute__((address_space(3))) void*)(dst + s * 8), 16, 0, 0);
        }
    };
    auto stageB = [&](int t, int kk) {
        int ko = koffB(t) + kk * 32;
        unsigned short* dst = &BS[t & 1][kk][0][0];
        #pragma unroll
        for (int i = 0; i < 2; ++i) {
            int s = i * 512 + tid;
            int row = s >> 2, sl = s & 3, lsl = sl ^ SWZ(row);
            const unsigned short* src = W + (size_t)(bn + row) * ldg + ko + lsl * 8;
            __builtin_amdgcn_global_load_lds(
                (const __attribute__((address_space(1))) void*)src,
                (__attribute__((address_space(3))) void*)(dst + s * 8), 16, 0, 0);
        }
    };

    // prologue: 7 half-tiles (K-tile 0 complete + 3/4 of K-tile 1)
    stageB(0, 0); stageA(0, 0); stageB(0, 1); stageA(0, 1);
    stageB(1, 0); stageA(1, 0); stageB(1, 1);
    VMW(6);
    BARR();

    for (int kt = 0; kt < NT - 2; ++kt) KTILE(0, kt);
    KTILE(1, NT - 2);
    KTILE(2, NT - 1);

    if (PART) {
        float* P = part + (size_t)z * ((size_t)MROWS * N);
        #pragma unroll
        for (int i = 0; i < 8; ++i)
            #pragma unroll
            for (int j = 0; j < 4; ++j) {
                int coln = bn + wn + j * 16 + fr;
                #pragma unroll
                for (int r = 0; r < 4; ++r) {
                    int rowm = bm + wm + i * 16 + fs * 4 + r;
                    P[(size_t)rowm * N + coln] = acc[i][j][r];
                }
            }
    } else {
        const float* bias = dir ? bias1 : bias0;
        float* C = dir ? C1 : C0;
        #pragma unroll
        for (int i = 0; i < 8; ++i)
            #pragma unroll
            for (int j = 0; j < 4; ++j) {
                int coln = bn + wn + j * 16 + fr;
                float bv = bias ? bias[coln] : 0.f;
                #pragma unroll
                for (int r = 0; r < 4; ++r) {
                    int rowm = bm + wm + i * 16 + fs * 4 + r;
                    float v = acc[i][j][r] + bv;
                    if (ACT == 1) v = (v > 20.f) ? v : log1pf(__expf(v));
                    C[(size_t)rowm * ldc + coln] = v;
                }
            }
    }
}

// ---------------------------------------------------------------------------
// 128x128 bf16x3 MFMA GEMM (2-barrier structure) for small shapes.
// ---------------------------------------------------------------------------
template<int ACT, bool PART>
__global__ __launch_bounds__(256)
void gemm_mfma(const unsigned short* __restrict__ A0,
               const unsigned short* __restrict__ A1,
               const unsigned short* __restrict__ W0,
               const unsigned short* __restrict__ W1,
               const float* __restrict__ bias0,
               const float* __restrict__ bias1,
               float* __restrict__ C0, float* __restrict__ C1,
               float* __restrict__ part,
               int ldc, int N, int K, int nks)
{
    __shared__ __align__(16) unsigned short As[128 * 32];
    __shared__ __align__(16) unsigned short Bs[128 * 32];

    const int tid = threadIdx.x;
    const int lane = tid & 63;
    const int wid = tid >> 6;

    const int z = blockIdx.z;
    const int dir = z / nks;
    const int ks = z - dir * nks;
    const unsigned short* A = dir ? A1 : A0;
    const unsigned short* W = dir ? W1 : W0;

    const int nbx = gridDim.x;
    const int nwg = nbx * gridDim.y;
    int bid = blockIdx.y * nbx + blockIdx.x;
    int q8 = nwg >> 3;
    int swz = (nwg >= 8) ? (bid & 7) * q8 + (bid >> 3) : bid;
    const int bm = (swz / nbx) * 128;
    const int bn = (swz % nbx) * 128;

    const int ldg = 2 * K;
    const int Kc = K / nks;
    const int kbase = ks * Kc;

    f32x4 acc[4][4];
    #pragma unroll
    for (int i = 0; i < 4; ++i)
        #pragma unroll
        for (int j = 0; j < 4; ++j) {
            f32x4 zv = {0.f, 0.f, 0.f, 0.f};
            acc[i][j] = zv;
        }

    const int r0 = tid >> 2;
    const int k0s = (tid & 3) ^ ((r0 >> 1) & 3);
    const int r1 = (256 + tid) >> 2;
    const int k1s = (tid & 3) ^ ((r1 >> 1) & 3);

    unsigned short* As_w0 = &As[(wid << 6) * 8];
    unsigned short* As_w1 = &As[(256 + (wid << 6)) * 8];
    unsigned short* Bs_w0 = &Bs[(wid << 6) * 8];
    unsigned short* Bs_w1 = &Bs[(256 + (wid << 6)) * 8];

    const int wm = (wid >> 1) * 64;
    const int wn = (wid & 1) * 64;
    const int fr = lane & 15;
    const int fs = lane >> 4;

    const int KS = Kc >> 5;
    #pragma unroll 1
    for (int seg = 0; seg < 3; ++seg) {
        const int aoff = ((seg == 1) ? K : 0) + kbase;
        const int boff = ((seg == 2) ? K : 0) + kbase;
        #pragma unroll 1
        for (int kt = 0; kt < KS; ++kt) {
            const int kk = kt << 5;
            const unsigned short* ga0 = A + (size_t)(bm + r0) * ldg + aoff + kk + k0s * 8;
            const unsigned short* ga1 = A + (size_t)(bm + r1) * ldg + aoff + kk + k1s * 8;
            const unsigned short* gw0 = W + (size_t)(bn + r0) * ldg + boff + kk + k0s * 8;
            const unsigned short* gw1 = W + (size_t)(bn + r1) * ldg + boff + kk + k1s * 8;
            __builtin_amdgcn_global_load_lds(
                (const __attribute__((address_space(1))) void*)ga0,
                (__attribute__((address_space(3))) void*)As_w0, 16, 0, 0);
            __builtin_amdgcn_global_load_lds(
                (const __attribute__((address_space(1))) void*)ga1,
                (__attribute__((address_space(3))) void*)As_w1, 16, 0, 0);
            __builtin_amdgcn_global_load_lds(
                (const __attribute__((address_space(1))) void*)gw0,
                (__attribute__((address_space(3))) void*)Bs_w0, 16, 0, 0);
            __builtin_amdgcn_global_load_lds(
                (const __attribute__((address_space(1))) void*)gw1,
                (__attribute__((address_space(3))) void*)Bs_w1, 16, 0, 0);
            __syncthreads();

            bf16x8 aF[4], bF[4];
            #pragma unroll
            for (int f = 0; f < 4; ++f) {
                int ra = wm + f * 16 + fr;
                int sa = fs ^ ((ra >> 1) & 3);
                aF[f] = *(const bf16x8*)&As[ra * 32 + sa * 8];
                int rb = wn + f * 16 + fr;
                int sb = fs ^ ((rb >> 1) & 3);
                bF[f] = *(const bf16x8*)&Bs[rb * 32 + sb * 8];
            }
            #pragma unroll
            for (int i = 0; i < 4; ++i)
                #pragma unroll
                for (int j = 0; j < 4; ++j)
                    acc[i][j] = __builtin_amdgcn_mfma_f32_16x16x32_bf16(
                        aF[i], bF[j], acc[i][j], 0, 0, 0);
            __syncthreads();
        }
    }

    if (PART) {
        float* P = part + (size_t)z * ((size_t)MROWS * N);
        #pragma unroll
        for (int i = 0; i < 4; ++i)
            #pragma unroll
            for (int j = 0; j < 4; ++j) {
                int coln = bn + wn + j * 16 + fr;
                #pragma unroll
                for (int r = 0; r < 4; ++r) {
                    int rowm = bm + wm + i * 16 + fs * 4 + r;
                    P[(size_t)rowm * N + coln] = acc[i][j][r];
                }
            }
    } else {
        const float* bias = dir ? bias1 : bias0;
        float* C = dir ? C1 : C0;
        #pragma unroll
        for (int i = 0; i < 4; ++i)
            #pragma unroll
            for (int j = 0; j < 4; ++j) {
                int coln = bn + wn + j * 16 + fr;
                float bv = bias ? bias[coln] : 0.f;
                #pragma unroll
                for (int r = 0; r < 4; ++r) {
                    int rowm = bm + wm + i * 16 + fs * 4 + r;
                    float v = acc[i][j][r] + bv;
                    if (ACT == 1) v = (v > 20.f) ? v : log1pf(__expf(v));
                    C[(size_t)rowm * ldc + coln] = v;
                }
            }
    }
}

// ---------------------------------------------------------------------------
// Split-K reduces with fused epilogues (z-batched over dir).
// ---------------------------------------------------------------------------
__global__ __launch_bounds__(256)
void reduce_xdbl_k(const float* __restrict__ part,
                   float* __restrict__ xdbl0, float* __restrict__ xdbl1,
                   unsigned short* __restrict__ dtb0, unsigned short* __restrict__ dtb1)
{
    const int dz = blockIdx.z;
    const float* P = part + (size_t)dz * 16 * MROWS * XDBL_LD;
    float* xdbl = dz ? xdbl1 : xdbl0;
    unsigned short* dtb = dz ? dtb1 : dtb0;
    int i = blockIdx.x * 256 + threadIdx.x;
    int row = i >> 5;
    int c4 = (i & 31) << 2;
    float4 s = make_float4(0.f, 0.f, 0.f, 0.f);
    #pragma unroll
    for (int k = 0; k < 16; ++k) {
        float4 v = *(const float4*)(P + (size_t)k * MROWS * XDBL_LD + (size_t)row * XDBL_LD + c4);
        s.x += v.x; s.y += v.y; s.z += v.z; s.w += v.w;
    }
    *(float4*)(xdbl + (size_t)row * XDBL_LD + c4) = s;
    if (c4 < DT_RANK) {
        float f[4] = {s.x, s.y, s.z, s.w};
        unsigned short h[4], l[4];
        #pragma unroll
        for (int j = 0; j < 4; ++j) hl_split(f[j], h[j], l[j]);
        *(ushort4*)(dtb + (size_t)row * (2 * DT_RANK) + c4) = make_ushort4(h[0], h[1], h[2], h[3]);
        *(ushort4*)(dtb + (size_t)row * (2 * DT_RANK) + DT_RANK + c4) = make_ushort4(l[0], l[1], l[2], l[3]);
    }
}

// mid: z=0/1 -> reduce out-proj partials (4 slices per dir) + bias + flip ->
// tmpb hi/lo; z=2 -> split proj_W -> pWb.
__global__ __launch_bounds__(256)
void mid_kernel(const float* __restrict__ part2,
                const float* __restrict__ bout0, const float* __restrict__ bout1,
                unsigned short* __restrict__ tmpb,
                const float* __restrict__ projW, unsigned short* __restrict__ pWb)
{
    const int dz = blockIdx.z;
    const int tid = threadIdx.x;
    if (dz == 2) {
        split_block(projW, D_MODEL, 2 * D_MODEL, 2 * D_MODEL, pWb, D_MODEL, false, blockIdx.x, tid);
        return;
    }
    const float* P = part2 + (size_t)dz * 4 * MROWS * D_MODEL;
    const float* bias = dz ? bout1 : bout0;
    const int colofs = dz ? D_MODEL : 0;
    int i = blockIdx.x * 256 + tid;
    int row = i >> 8;
    int c4 = (i & 255) << 2;
    float4 s = make_float4(bias[c4], bias[c4 + 1], bias[c4 + 2], bias[c4 + 3]);
    #pragma unroll
    for (int k = 0; k < 4; ++k) {
        float4 v = *(const float4*)(P + (size_t)k * MROWS * D_MODEL + (size_t)row * D_MODEL + c4);
        s.x += v.x; s.y += v.y; s.z += v.z; s.w += v.w;
    }
    int orow = row;
    if (dz) { int bb = row >> 10, t = row & 1023; orow = (bb << 10) + 1023 - t; }
    float f[4] = {s.x, s.y, s.z, s.w};
    unsigned short h[4], l[4];
    #pragma unroll
    for (int j = 0; j < 4; ++j) hl_split(f[j], h[j], l[j]);
    *(ushort4*)(tmpb + (size_t)orow * 4096 + colofs + c4) = make_ushort4(h[0], h[1], h[2], h[3]);
    *(ushort4*)(tmpb + (size_t)orow * 4096 + 2048 + colofs + c4) = make_ushort4(l[0], l[1], l[2], l[3]);
}

__global__ __launch_bounds__(256)
void reduce_out_k(const float* __restrict__ part, const float* __restrict__ bias,
                  float* __restrict__ out)
{
    int i = blockIdx.x * 256 + threadIdx.x;
    int row = i >> 8;
    int c4 = (i & 255) << 2;
    float4 s = make_float4(bias[c4], bias[c4 + 1], bias[c4 + 2], bias[c4 + 3]);
    #pragma unroll
    for (int k = 0; k < 8; ++k) {
        float4 v = *(const float4*)(part + (size_t)k * MROWS * D_MODEL + (size_t)row * D_MODEL + c4);
        s.x += v.x; s.y += v.y; s.z += v.z; s.w += v.w;
    }
    *(float4*)(out + (size_t)row * D_MODEL + c4) = s;
}

// ---------------------------------------------------------------------------
// Causal depthwise conv + SiLU -> ub (hi|lo bf16). z = dir.
// ---------------------------------------------------------------------------
__global__ __launch_bounds__(256)
void conv_silu_kernel(const float* __restrict__ xz0, const float* __restrict__ xz1,
                      const float* __restrict__ cw0, const float* __restrict__ cw1,
                      const float* __restrict__ cb0, const float* __restrict__ cb1,
                      unsigned short* __restrict__ ub0, unsigned short* __restrict__ ub1)
{
    const int dz = blockIdx.z;
    const float* xz = dz ? xz1 : xz0;
    const float* convw = dz ? cw1 : cw0;
    const float* convb = dz ? cb1 : cb0;
    unsigned short* ub = dz ? ub1 : ub0;
    int idx = blockIdx.x * 256 + threadIdx.x;
    int d = idx % D_INNER;
    int r = idx / D_INNER;
    int t = r % SEQLEN;
    float acc = convb[d];
    #pragma unroll
    for (int k = 0; k < D_CONV; ++k) {
        int back = D_CONV - 1 - k;
        if (t - back >= 0)
            acc += xz[(size_t)(r - back) * (2 * D_INNER) + d] * convw[d * D_CONV + k];
    }
    float v = acc * sigmoidf_(acc);
    unsigned short h, l;
    hl_split(v, h, l);
    ub[(size_t)r * (2 * D_INNER) + d] = h;
    ub[(size_t)r * (2 * D_INNER) + D_INNER + d] = l;
}

// ---------------------------------------------------------------------------
// Chunked selective scan. phase1 emits (prod dA, h_local_end); phase3 folds
// the cross-chunk combine inline (identical fold order to the old phase2),
// then re-runs the chunk recurrence, reduces y, gates, writes yz hi/lo
// in-place over ub. z = dir.
// ---------------------------------------------------------------------------
__global__ __launch_bounds__(256)
void scan_phase1(const float* __restrict__ delta0, const float* __restrict__ delta1,
                 const unsigned short* __restrict__ ub0, const unsigned short* __restrict__ ub1,
                 const float* __restrict__ xdbl0, const float* __restrict__ xdbl1,
                 const float* __restrict__ Alog0, const float* __restrict__ Alog1,
                 float* __restrict__ aprod0, float* __restrict__ aprod1,
                 float* __restrict__ hfin0, float* __restrict__ hfin1)
{
    const int dz = blockIdx.z;
    const float* delta = dz ? delta1 : delta0;
    const unsigned short* ub = dz ? ub1 : ub0;
    const float* xdbl = dz ? xdbl1 : xdbl0;
    const float* Alog = dz ? Alog1 : Alog0;
    float* aprod = dz ? aprod1 : aprod0;
    float* hfin = dz ? hfin1 : hfin0;

    const int tid = threadIdx.x;
    const int ch = blockIdx.x * 16 + (tid >> 4);
    const int n = tid & 15;
    const int chunk = blockIdx.y;
    const int b = ch / D_INNER;
    const int d = ch % D_INNER;

    const float Av = -__expf(Alog[d * D_STATE + n]);
    float h = 0.f, ap = 1.f;
    const int t0 = chunk * CLEN;
    for (int t = t0; t < t0 + CLEN; ++t) {
        const size_t r = (size_t)b * SEQLEN + t;
        float dlt = delta[r * D_INNER + d];
        float uu = us2f(ub[r * (2 * D_INNER) + d]) + us2f(ub[r * (2 * D_INNER) + D_INNER + d]);
        float Bv = xdbl[r * XDBL_LD + DT_RANK + n];
        float dA = __expf(dlt * Av);
        h = h * dA + (dlt * uu) * Bv;
        ap *= dA;
    }
    const size_t idx = ((size_t)ch * D_STATE + n) * NCHUNK + chunk;
    aprod[idx] = ap;
    hfin[idx] = h;
}

__global__ __launch_bounds__(256)
void scan_phase3(const float* __restrict__ delta0, const float* __restrict__ delta1,
                 unsigned short* __restrict__ ub0, unsigned short* __restrict__ ub1,
                 const float* __restrict__ xdbl0, const float* __restrict__ xdbl1,
                 const float* __restrict__ Alog0, const float* __restrict__ Alog1,
                 const float* __restrict__ Dsk0, const float* __restrict__ Dsk1,
                 const float* __restrict__ xz0, const float* __restrict__ xz1,
                 const float* __restrict__ aprod0, const float* __restrict__ aprod1,
                 const float* __restrict__ hfin0, const float* __restrict__ hfin1)
{
    const int dz = blockIdx.z;
    const float* delta = dz ? delta1 : delta0;
    unsigned short* ub = dz ? ub1 : ub0;
    const float* xdbl = dz ? xdbl1 : xdbl0;
    const float* Alog = dz ? Alog1 : Alog0;
    const float* Dsk = dz ? Dsk1 : Dsk0;
    const float* xz = dz ? xz1 : xz0;
    const float* aprod = dz ? aprod1 : aprod0;
    const float* hfin = dz ? hfin1 : hfin0;

    const int tid = threadIdx.x;
    const int ch = blockIdx.x * 16 + (tid >> 4);
    const int n = tid & 15;
    const int chunk = blockIdx.y;
    const int b = ch / D_INNER;
    const int d = ch % D_INNER;

    const float Av = -__expf(Alog[d * D_STATE + n]);
    const float Dv = Dsk[d];

    // inline cross-chunk combine (same fold order as the old phase2)
    const size_t cbase = (size_t)(ch * D_STATE + n) * NCHUNK;
    float h = 0.f;
    for (int c = 0; c < chunk; ++c)
        h = aprod[cbase + c] * h + hfin[cbase + c];

    const int t0 = chunk * CLEN;
    for (int t = t0; t < t0 + CLEN; ++t) {
        const size_t r = (size_t)b * SEQLEN + t;
        float dlt = delta[r * D_INNER + d];
        float uu = us2f(ub[r * (2 * D_INNER) + d]) + us2f(ub[r * (2 * D_INNER) + D_INNER + d]);
        float Bv = xdbl[r * XDBL_LD + DT_RANK + n];
        float Cv = xdbl[r * XDBL_LD + DT_RANK + D_STATE + n];
        float dA = __expf(dlt * Av);
        h = h * dA + (dlt * uu) * Bv;
        float p = h * Cv;
        p += __shfl_xor(p, 1, 16);
        p += __shfl_xor(p, 2, 16);
        p += __shfl_xor(p, 4, 16);
        p += __shfl_xor(p, 8, 16);
        if (n == 0) {
            float zv = xz[r * (2 * D_INNER) + D_INNER + d];
            float v = (p + uu * Dv) * (zv * sigmoidf_(zv));
            unsigned short hh, ll;
            hl_split(v, hh, ll);
            ub[r * (2 * D_INNER) + d] = hh;
            ub[r * (2 * D_INNER) + D_INNER + d] = ll;
        }
    }
}

// ---------------------------------------------------------------------------
extern "C" void kernel_launch(void* const* d_in, const int* in_sizes, int n_in,
                              void* d_out, int out_size, void* d_ws, size_t ws_size,
                              hipStream_t stream)
{
    const float* x = (const float*)d_in[0];
    const float* proj_W = (const float*)d_in[23];
    const float* proj_b = (const float*)d_in[24];
    float* out = (float*)d_out;

    const float *Win[2], *bin_[2], *convw[2], *convb[2], *Wx[2], *Wdt[2], *bdt[2],
                *Alog[2], *Dsk[2], *Wout[2], *bout[2];
    for (int dir = 0; dir < 2; ++dir) {
        const int base = 1 + dir * 11;
        Win[dir]   = (const float*)d_in[base + 0];
        bin_[dir]  = (const float*)d_in[base + 1];
        convw[dir] = (const float*)d_in[base + 2];
        convb[dir] = (const float*)d_in[base + 3];
        Wx[dir]    = (const float*)d_in[base + 4];
        Wdt[dir]   = (const float*)d_in[base + 5];
        bdt[dir]   = (const float*)d_in[base + 6];
        Alog[dir]  = (const float*)d_in[base + 7];
        Dsk[dir]   = (const float*)d_in[base + 8];
        Wout[dir]  = (const float*)d_in[base + 9];
        bout[dir]  = (const float*)d_in[base + 10];
    }

    // ---- explicit arena (lifetime-checked overlays; ~162 MiB) ----
    char* ws = (char*)d_ws;
    const size_t MB = 1ull << 20;
    float* xz[2]            = {(float*)(ws + 0 * MB),   (float*)(ws + 32 * MB)};   // [0,64)
    unsigned short* ub[2]   = {(unsigned short*)(ws + 64 * MB),
                               (unsigned short*)(ws + 80 * MB)};                   // [64,96)
    unsigned short* Winb[2] = {(unsigned short*)(ws + 96 * MB),
                               (unsigned short*)(ws + 112 * MB)};                  // [96,128)
    unsigned short* xc[2]   = {(unsigned short*)(ws + 128 * MB),
                               (unsigned short*)(ws + 136 * MB)};                  // [128,144)
    // overlays:
    float* part             = (float*)(ws + 112 * MB);          // xproj partials [112,144) after gemm1
    float* part2            = (float*)(ws + 0 * MB);            // [0,64) after scan3 (xz dead)
    float* delta[2]         = {(float*)(ws + 112 * MB), (float*)(ws + 128 * MB)};
    unsigned short* Woutb[2]= {(unsigned short*)(ws + 96 * MB),
                               (unsigned short*)(ws + 104 * MB)};                  // in Winb0 (dead after gemm1)
    unsigned short* yzb[2]  = {ub[0], ub[1]};                   // in-place scan3
    unsigned short* tmpb    = ub[0];                            // after out-proj
    unsigned short* pWb     = ub[1];                            // after out-proj
    // smalls [144,162):
    unsigned short* Wxb[2]  = {(unsigned short*)(ws + 144 * MB), (unsigned short*)(ws + 145 * MB)};
    unsigned short* Wdtb[2] = {(unsigned short*)(ws + 146 * MB), (unsigned short*)(ws + 146 * MB + 512 * 1024)};
    unsigned short* dtb[2]  = {(unsigned short*)(ws + 147 * MB), (unsigned short*)(ws + 147 * MB + 512 * 1024)};
    float* xdbl[2]          = {(float*)(ws + 148 * MB), (float*)(ws + 149 * MB)};
    float* aprod[2]         = {(float*)(ws + 150 * MB), (float*)(ws + 156 * MB)};
    float* hfin[2]          = {(float*)(ws + 152 * MB), (float*)(ws + 158 * MB)};

    dim3 blk(256);

    // 1. prep1: all pre-GEMM splits (x both dirs, Win, Wx, Wdt)
    prep1_kernel<<<13056, blk, 0, stream>>>(
        x, Win[0], Win[1], Wx[0], Wx[1], Wdt[0], Wdt[1],
        xc[0], xc[1], Winb[0], Winb[1], Wxb[0], Wxb[1], Wdtb[0], Wdtb[1]);

    // 2. input proj (8-phase 256²), both dirs
    gemm256<0, false><<<dim3(16, 8, 2), dim3(512), 0, stream>>>(
        xc[0], xc[1], Winb[0], Winb[1], bin_[0], bin_[1], xz[0], xz[1],
        nullptr, 4096, 4096, D_MODEL, 1, 16);

    // 3. prep2: Wout splits (overlay Winb, dead after step 2)
    prep2_kernel<<<4096, blk, 0, stream>>>(Wout[0], Wout[1], Woutb[0], Woutb[1]);

    // 4. conv + silu -> ub hi/lo (both dirs)
    conv_silu_kernel<<<dim3((MROWS * D_INNER) / 256, 1, 2), blk, 0, stream>>>(
        xz[0], xz[1], convw[0], convw[1], convb[0], convb[1], ub[0], ub[1]);

    // 5. xproj split-K (128², nks=16, both dirs) -> part
    gemm_mfma<0, true><<<dim3(1, 16, 32), blk, 0, stream>>>(
        ub[0], ub[1], Wxb[0], Wxb[1], nullptr, nullptr, nullptr, nullptr,
        part, XDBL_LD, XDBL_LD, D_INNER, 16);

    // 6. reduce -> xdbl fp32 + dtb hi/lo (both dirs)
    reduce_xdbl_k<<<dim3(256, 1, 2), blk, 0, stream>>>(
        part, xdbl[0], xdbl[1], dtb[0], dtb[1]);

    // 7. dt proj (128², both dirs): delta = softplus(dt @ Wdt^T + bdt)
    gemm_mfma<1, false><<<dim3(16, 16, 2), blk, 0, stream>>>(
        dtb[0], dtb[1], Wdtb[0], Wdtb[1], bdt[0], bdt[1], delta[0], delta[1],
        nullptr, D_INNER, D_INNER, DT_RANK, 1);

    // 8-9. chunked scan (phase2 folded into phase3), both dirs
    const dim3 scan_grid(BATCH * D_INNER / 16, NCHUNK, 2);
    scan_phase1<<<scan_grid, blk, 0, stream>>>(
        delta[0], delta[1], ub[0], ub[1], xdbl[0], xdbl[1], Alog[0], Alog[1],
        aprod[0], aprod[1], hfin[0], hfin[1]);
    scan_phase3<<<scan_grid, blk, 0, stream>>>(
        delta[0], delta[1], ub[0], ub[1], xdbl[0], xdbl[1], Alog[0], Alog[1],
        Dsk[0], Dsk[1], xz[0], xz[1], aprod[0], aprod[1], hfin[0], hfin[1]);

    // 10. out proj (8-phase 256², nks=4, both dirs) -> part2 [xz dead]
    gemm256<0, true><<<dim3(4, 8, 8), dim3(512), 0, stream>>>(
        yzb[0], yzb[1], Woutb[0], Woutb[1], nullptr, nullptr, nullptr, nullptr,
        part2, D_MODEL, D_MODEL, D_INNER, 4, 8);

    // 11. mid: reduce out-proj partials -> tmpb (both dirs) + split proj_W -> pWb
    mid_kernel<<<dim3(2048, 1, 3), blk, 0, stream>>>(
        part2, bout[0], bout[1], tmpb, proj_W, pWb);

    // 12. final proj (8-phase 256², nks=8) -> part2
    gemm256<0, true><<<dim3(4, 8, 8), dim3(512), 0, stream>>>(
        tmpb, nullptr, pWb, nullptr, nullptr, nullptr, nullptr, nullptr,
        part2, D_MODEL, D_MODEL, 2 * D_MODEL, 8, 4);

    // 13. reduce -> out
    reduce_out_k<<<2048, blk, 0, stream>>>(part2, proj_b, out);
}

// Round 9
// 491.396 us; speedup vs baseline: 5.8993x; 1.4193x over previous
//
#include <hip/hip_runtime.h>
#include <math.h>

#define D_MODEL 1024
#define D_STATE 16
#define D_CONV  4
#define D_INNER 2048
#define DT_RANK 64
#define BATCH   2
#define SEQLEN  1024
#define MROWS   2048
#define XDBL_LD 128
#define NCHUNK  32
#define CLEN    (SEQLEN / NCHUNK)   // 32
#define NCHG    8192                // 2 dirs * BATCH * D_INNER

typedef __attribute__((ext_vector_type(8))) short bf16x8;
typedef __attribute__((ext_vector_type(4))) float f32x4;

#define BARR() asm volatile("s_barrier" ::: "memory")
#define VMW(n) asm volatile("s_waitcnt vmcnt(" #n ")" ::: "memory")

static __device__ __forceinline__ float sigmoidf_(float x) {
    return 1.f / (1.f + __expf(-x));
}
static __device__ __forceinline__ unsigned short bf16rn(float f) {
    unsigned u = __float_as_uint(f);
    return (unsigned short)((u + 0x7FFFu + ((u >> 16) & 1u)) >> 16);
}
static __device__ __forceinline__ void hl_split(float f, unsigned short& h, unsigned short& l) {
    h = bf16rn(f);
    l = bf16rn(f - __uint_as_float((unsigned)h << 16));
}
static __device__ __forceinline__ float us2f(unsigned short u) {
    return __uint_as_float((unsigned)u << 16);
}

// ---------------------------------------------------------------------------
// Shared split worker: fp32 (R x C) -> bf16 (Rout x 2C) hi|lo. blk-local idx.
// ---------------------------------------------------------------------------
static __device__ __forceinline__
void split_block(const float* __restrict__ in, int R, int C, int ldin,
                 unsigned short* __restrict__ out, int Rout, bool flip,
                 int blk, int tid)
{
    int q = blk * 256 + tid;
    int qpr = C >> 2;
    int row = q / qpr;
    int c4 = (q - row * qpr) << 2;
    if (row >= Rout) return;
    unsigned short h[4] = {0, 0, 0, 0}, l[4] = {0, 0, 0, 0};
    if (row < R) {
        int sr = row;
        if (flip) { int b = row >> 10, t = row & 1023; sr = (b << 10) + (1023 - t); }
        float4 v = *(const float4*)(in + (size_t)sr * ldin + c4);
        float f[4] = {v.x, v.y, v.z, v.w};
        #pragma unroll
        for (int i = 0; i < 4; ++i) hl_split(f[i], h[i], l[i]);
    }
    size_t ob = (size_t)row * (2 * C);
    *(ushort4*)(out + ob + c4)     = make_ushort4(h[0], h[1], h[2], h[3]);
    *(ushort4*)(out + ob + C + c4) = make_ushort4(l[0], l[1], l[2], l[3]);
}

// prep1: all pre-GEMM conversions in one launch (block-range dispatch).
__global__ __launch_bounds__(256)
void prep1_kernel(const float* __restrict__ x,
                  const float* __restrict__ Win0, const float* __restrict__ Win1,
                  const float* __restrict__ Wx0,  const float* __restrict__ Wx1,
                  const float* __restrict__ Wdt0, const float* __restrict__ Wdt1,
                  unsigned short* xc0, unsigned short* xc1,
                  unsigned short* Winb0, unsigned short* Winb1,
                  unsigned short* Wxb0, unsigned short* Wxb1,
                  unsigned short* Wdtb0, unsigned short* Wdtb1)
{
    int b = blockIdx.x, tid = threadIdx.x;
    if      (b < 2048)  split_block(x,    MROWS, D_MODEL, D_MODEL, xc0,  MROWS, false, b,        tid);
    else if (b < 4096)  split_block(x,    MROWS, D_MODEL, D_MODEL, xc1,  MROWS, true,  b - 2048, tid);
    else if (b < 8192)  split_block(Win0, 4096,  D_MODEL, D_MODEL, Winb0, 4096, false, b - 4096, tid);
    else if (b < 12288) split_block(Win1, 4096,  D_MODEL, D_MODEL, Winb1, 4096, false, b - 8192, tid);
    else if (b < 12544) split_block(Wx0,  96,    D_INNER, D_INNER, Wxb0,  128,  false, b - 12288, tid);
    else if (b < 12800) split_block(Wx1,  96,    D_INNER, D_INNER, Wxb1,  128,  false, b - 12544, tid);
    else if (b < 12928) split_block(Wdt0, D_INNER, DT_RANK, DT_RANK, Wdtb0, D_INNER, false, b - 12800, tid);
    else                split_block(Wdt1, D_INNER, DT_RANK, DT_RANK, Wdtb1, D_INNER, false, b - 12928, tid);
}

// prep2: Wout conversions (after input-proj gemm; overlays Winb region).
__global__ __launch_bounds__(256)
void prep2_kernel(const float* __restrict__ Wout0, const float* __restrict__ Wout1,
                  unsigned short* Woutb0, unsigned short* Woutb1)
{
    int b = blockIdx.x, tid = threadIdx.x;
    if (b < 2048) split_block(Wout0, D_MODEL, D_INNER, D_INNER, Woutb0, D_MODEL, false, b, tid);
    else          split_block(Wout1, D_MODEL, D_INNER, D_INNER, Woutb1, D_MODEL, false, b - 2048, tid);
}

// ---------------------------------------------------------------------------
// 256x256 8-phase bf16x3 MFMA GEMM (T2+T3+T4+T5), dual-dir + split-K.
// ---------------------------------------------------------------------------
#define SWZ(row) (((row) >> 1) & 3)
#define RDA(p, kk, row) (*(const bf16x8*)&AS[p][kk][row][(fs ^ SWZ(row)) << 3])
#define RDB(p, kk, row) (*(const bf16x8*)&BS[p][kk][row][(fs ^ SWZ(row)) << 3])

#define KTILE(MODE, kt) do { \
    const int p_ = (kt) & 1; \
    bf16x8 bF[4]; \
    { /* P1 */ \
        bf16x8 aF[4]; \
        _Pragma("unroll") for (int f = 0; f < 4; ++f) { int rw = wm + f * 16 + fr; aF[f] = RDA(p_, 0, rw); } \
        _Pragma("unroll") for (int g = 0; g < 4; ++g) { int rw = wn + g * 16 + fr; bF[g] = RDB(p_, 0, rw); } \
        if (MODE < 2) stageA((kt) + 1, 1); \
        BARR(); __builtin_amdgcn_s_setprio(1); \
        _Pragma("unroll") for (int f = 0; f < 4; ++f) \
        _Pragma("unroll") for (int g = 0; g < 4; ++g) \
            acc[f][g] = __builtin_amdgcn_mfma_f32_16x16x32_bf16(aF[f], bF[g], acc[f][g], 0, 0, 0); \
        __builtin_amdgcn_s_setprio(0); BARR(); \
    } \
    { /* P2 */ \
        if (MODE == 2) { VMW(0); } else { VMW(8); } \
        bf16x8 aF[4]; \
        _Pragma("unroll") for (int f = 0; f < 4; ++f) { int rw = wm + 64 + f * 16 + fr; aF[f] = RDA(p_, 0, rw); } \
        if (MODE == 0) stageB((kt) + 2, 0); \
        BARR(); __builtin_amdgcn_s_setprio(1); \
        _Pragma("unroll") for (int f = 0; f < 4; ++f) \
        _Pragma("unroll") for (int g = 0; g < 4; ++g) \
            acc[4 + f][g] = __builtin_amdgcn_mfma_f32_16x16x32_bf16(aF[f], bF[g], acc[4 + f][g], 0, 0, 0); \
        __builtin_amdgcn_s_setprio(0); BARR(); \
    } \
    { /* P3 */ \
        bf16x8 aF[4]; \
        _Pragma("unroll") for (int f = 0; f < 4; ++f) { int rw = wm + f * 16 + fr; aF[f] = RDA(p_, 1, rw); } \
        _Pragma("unroll") for (int g = 0; g < 4; ++g) { int rw = wn + g * 16 + fr; bF[g] = RDB(p_, 1, rw); } \
        if (MODE == 0) stageA((kt) + 2, 0); \
        BARR(); __builtin_amdgcn_s_setprio(1); \
        _Pragma("unroll") for (int f = 0; f < 4; ++f) \
        _Pragma("unroll") for (int g = 0; g < 4; ++g) \
            acc[f][g] = __builtin_amdgcn_mfma_f32_16x16x32_bf16(aF[f], bF[g], acc[f][g], 0, 0, 0); \
        __builtin_amdgcn_s_setprio(0); BARR(); \
    } \
    { /* P4 */ \
        if (MODE == 0) { VMW(8); } else if (MODE == 1) { VMW(4); } \
        bf16x8 aF[4]; \
        _Pragma("unroll") for (int f = 0; f < 4; ++f) { int rw = wm + 64 + f * 16 + fr; aF[f] = RDA(p_, 1, rw); } \
        if (MODE == 0) stageB((kt) + 2, 1); \
        BARR(); __builtin_amdgcn_s_setprio(1); \
        _Pragma("unroll") for (int f = 0; f < 4; ++f) \
        _Pragma("unroll") for (int g = 0; g < 4; ++g) \
            acc[4 + f][g] = __builtin_amdgcn_mfma_f32_16x16x32_bf16(aF[f], bF[g], acc[4 + f][g], 0, 0, 0); \
        __builtin_amdgcn_s_setprio(0); BARR(); \
    } \
} while (0)

template<int ACT, bool PART>
__global__ __launch_bounds__(512, 1)
void gemm256(const unsigned short* __restrict__ A0,
             const unsigned short* __restrict__ A1,
             const unsigned short* __restrict__ W0,
             const unsigned short* __restrict__ W1,
             const float* __restrict__ bias0,
             const float* __restrict__ bias1,
             float* __restrict__ C0, float* __restrict__ C1,
             float* __restrict__ part,
             int ldc, int N, int K, int nks, int KTS)
{
    __shared__ unsigned short AS[2][2][256][32];
    __shared__ unsigned short BS[2][2][256][32];

    const int tid = threadIdx.x;
    const int lane = tid & 63;
    const int wid = tid >> 6;

    const int z = blockIdx.z;
    const int dir = z / nks;
    const int ks = z - dir * nks;
    const unsigned short* A = dir ? A1 : A0;
    const unsigned short* W = dir ? W1 : W0;

    const int nbx = gridDim.x;
    const int nwg = nbx * gridDim.y;
    int bid = blockIdx.y * nbx + blockIdx.x;
    int q8 = nwg >> 3;
    int swz = (bid & 7) * q8 + (bid >> 3);
    const int bm = (swz / nbx) * 256;
    const int bn = (swz % nbx) * 256;

    const int ldg = 2 * K;
    const int Kc = KTS * 64;
    const int kbase = ks * Kc;
    const int NT = 3 * KTS;

    const int wm = (wid >> 2) * 128;
    const int wn = (wid & 3) * 64;
    const int fr = lane & 15;
    const int fs = lane >> 4;

    f32x4 acc[8][4];
    #pragma unroll
    for (int i = 0; i < 8; ++i)
        #pragma unroll
        for (int j = 0; j < 4; ++j) {
            f32x4 zv = {0.f, 0.f, 0.f, 0.f};
            acc[i][j] = zv;
        }

    auto koffA = [&](int t) { int sg = t / KTS; int w = t - sg * KTS;
                              return ((sg == 1) ? K : 0) + kbase + w * 64; };
    auto koffB = [&](int t) { int sg = t / KTS; int w = t - sg * KTS;
                              return ((sg == 2) ? K : 0) + kbase + w * 64; };

    auto stageA = [&](int t, int kk) {
        int ko = koffA(t) + kk * 32;
        unsigned short* dst = &AS[t & 1][kk][0][0];
        #pragma unroll
        for (int i = 0; i < 2; ++i) {
            int s = i * 512 + tid;
            int row = s >> 2, sl = s & 3, lsl = sl ^ SWZ(row);
            const unsigned short* src = A + (size_t)(bm + row) * ldg + ko + lsl * 8;
            __builtin_amdgcn_global_load_lds(
                (const __attribute__((address_space(1))) void*)src,
                (__attribute__((address_space(3))) void*)(dst + s * 8), 16, 0, 0);
        }
    };
    auto stageB = [&](int t, int kk) {
        int ko = koffB(t) + kk * 32;
        unsigned short* dst = &BS[t & 1][kk][0][0];
        #pragma unroll
        for (int i = 0; i < 2; ++i) {
            int s = i * 512 + tid;
            int row = s >> 2, sl = s & 3, lsl = sl ^ SWZ(row);
            const unsigned short* src = W + (size_t)(bn + row) * ldg + ko + lsl * 8;
            __builtin_amdgcn_global_load_lds(
                (const __attribute__((address_space(1))) void*)src,
                (__attribute__((address_space(3))) void*)(dst + s * 8), 16, 0, 0);
        }
    };

    // prologue: 7 half-tiles (K-tile 0 complete + 3/4 of K-tile 1)
    stageB(0, 0); stageA(0, 0); stageB(0, 1); stageA(0, 1);
    stageB(1, 0); stageA(1, 0); stageB(1, 1);
    VMW(6);
    BARR();

    for (int kt = 0; kt < NT - 2; ++kt) KTILE(0, kt);
    KTILE(1, NT - 2);
    KTILE(2, NT - 1);

    if (PART) {
        float* P = part + (size_t)z * ((size_t)MROWS * N);
        #pragma unroll
        for (int i = 0; i < 8; ++i)
            #pragma unroll
            for (int j = 0; j < 4; ++j) {
                int coln = bn + wn + j * 16 + fr;
                #pragma unroll
                for (int r = 0; r < 4; ++r) {
                    int rowm = bm + wm + i * 16 + fs * 4 + r;
                    P[(size_t)rowm * N + coln] = acc[i][j][r];
                }
            }
    } else {
        const float* bias = dir ? bias1 : bias0;
        float* C = dir ? C1 : C0;
        #pragma unroll
        for (int i = 0; i < 8; ++i)
            #pragma unroll
            for (int j = 0; j < 4; ++j) {
                int coln = bn + wn + j * 16 + fr;
                float bv = bias ? bias[coln] : 0.f;
                #pragma unroll
                for (int r = 0; r < 4; ++r) {
                    int rowm = bm + wm + i * 16 + fs * 4 + r;
                    float v = acc[i][j][r] + bv;
                    if (ACT == 1) v = (v > 20.f) ? v : log1pf(__expf(v));
                    C[(size_t)rowm * ldc + coln] = v;
                }
            }
    }
}

// ---------------------------------------------------------------------------
// 128x128 bf16x3 MFMA GEMM (2-barrier structure) for small shapes.
// ---------------------------------------------------------------------------
template<int ACT, bool PART>
__global__ __launch_bounds__(256)
void gemm_mfma(const unsigned short* __restrict__ A0,
               const unsigned short* __restrict__ A1,
               const unsigned short* __restrict__ W0,
               const unsigned short* __restrict__ W1,
               const float* __restrict__ bias0,
               const float* __restrict__ bias1,
               float* __restrict__ C0, float* __restrict__ C1,
               float* __restrict__ part,
               int ldc, int N, int K, int nks)
{
    __shared__ __align__(16) unsigned short As[128 * 32];
    __shared__ __align__(16) unsigned short Bs[128 * 32];

    const int tid = threadIdx.x;
    const int lane = tid & 63;
    const int wid = tid >> 6;

    const int z = blockIdx.z;
    const int dir = z / nks;
    const int ks = z - dir * nks;
    const unsigned short* A = dir ? A1 : A0;
    const unsigned short* W = dir ? W1 : W0;

    const int nbx = gridDim.x;
    const int nwg = nbx * gridDim.y;
    int bid = blockIdx.y * nbx + blockIdx.x;
    int q8 = nwg >> 3;
    int swz = (nwg >= 8) ? (bid & 7) * q8 + (bid >> 3) : bid;
    const int bm = (swz / nbx) * 128;
    const int bn = (swz % nbx) * 128;

    const int ldg = 2 * K;
    const int Kc = K / nks;
    const int kbase = ks * Kc;

    f32x4 acc[4][4];
    #pragma unroll
    for (int i = 0; i < 4; ++i)
        #pragma unroll
        for (int j = 0; j < 4; ++j) {
            f32x4 zv = {0.f, 0.f, 0.f, 0.f};
            acc[i][j] = zv;
        }

    const int r0 = tid >> 2;
    const int k0s = (tid & 3) ^ ((r0 >> 1) & 3);
    const int r1 = (256 + tid) >> 2;
    const int k1s = (tid & 3) ^ ((r1 >> 1) & 3);

    unsigned short* As_w0 = &As[(wid << 6) * 8];
    unsigned short* As_w1 = &As[(256 + (wid << 6)) * 8];
    unsigned short* Bs_w0 = &Bs[(wid << 6) * 8];
    unsigned short* Bs_w1 = &Bs[(256 + (wid << 6)) * 8];

    const int wm = (wid >> 1) * 64;
    const int wn = (wid & 1) * 64;
    const int fr = lane & 15;
    const int fs = lane >> 4;

    const int KS = Kc >> 5;
    #pragma unroll 1
    for (int seg = 0; seg < 3; ++seg) {
        const int aoff = ((seg == 1) ? K : 0) + kbase;
        const int boff = ((seg == 2) ? K : 0) + kbase;
        #pragma unroll 1
        for (int kt = 0; kt < KS; ++kt) {
            const int kk = kt << 5;
            const unsigned short* ga0 = A + (size_t)(bm + r0) * ldg + aoff + kk + k0s * 8;
            const unsigned short* ga1 = A + (size_t)(bm + r1) * ldg + aoff + kk + k1s * 8;
            const unsigned short* gw0 = W + (size_t)(bn + r0) * ldg + boff + kk + k0s * 8;
            const unsigned short* gw1 = W + (size_t)(bn + r1) * ldg + boff + kk + k1s * 8;
            __builtin_amdgcn_global_load_lds(
                (const __attribute__((address_space(1))) void*)ga0,
                (__attribute__((address_space(3))) void*)As_w0, 16, 0, 0);
            __builtin_amdgcn_global_load_lds(
                (const __attribute__((address_space(1))) void*)ga1,
                (__attribute__((address_space(3))) void*)As_w1, 16, 0, 0);
            __builtin_amdgcn_global_load_lds(
                (const __attribute__((address_space(1))) void*)gw0,
                (__attribute__((address_space(3))) void*)Bs_w0, 16, 0, 0);
            __builtin_amdgcn_global_load_lds(
                (const __attribute__((address_space(1))) void*)gw1,
                (__attribute__((address_space(3))) void*)Bs_w1, 16, 0, 0);
            __syncthreads();

            bf16x8 aF[4], bF[4];
            #pragma unroll
            for (int f = 0; f < 4; ++f) {
                int ra = wm + f * 16 + fr;
                int sa = fs ^ ((ra >> 1) & 3);
                aF[f] = *(const bf16x8*)&As[ra * 32 + sa * 8];
                int rb = wn + f * 16 + fr;
                int sb = fs ^ ((rb >> 1) & 3);
                bF[f] = *(const bf16x8*)&Bs[rb * 32 + sb * 8];
            }
            #pragma unroll
            for (int i = 0; i < 4; ++i)
                #pragma unroll
                for (int j = 0; j < 4; ++j)
                    acc[i][j] = __builtin_amdgcn_mfma_f32_16x16x32_bf16(
                        aF[i], bF[j], acc[i][j], 0, 0, 0);
            __syncthreads();
        }
    }

    if (PART) {
        float* P = part + (size_t)z * ((size_t)MROWS * N);
        #pragma unroll
        for (int i = 0; i < 4; ++i)
            #pragma unroll
            for (int j = 0; j < 4; ++j) {
                int coln = bn + wn + j * 16 + fr;
                #pragma unroll
                for (int r = 0; r < 4; ++r) {
                    int rowm = bm + wm + i * 16 + fs * 4 + r;
                    P[(size_t)rowm * N + coln] = acc[i][j][r];
                }
            }
    } else {
        const float* bias = dir ? bias1 : bias0;
        float* C = dir ? C1 : C0;
        #pragma unroll
        for (int i = 0; i < 4; ++i)
            #pragma unroll
            for (int j = 0; j < 4; ++j) {
                int coln = bn + wn + j * 16 + fr;
                float bv = bias ? bias[coln] : 0.f;
                #pragma unroll
                for (int r = 0; r < 4; ++r) {
                    int rowm = bm + wm + i * 16 + fs * 4 + r;
                    float v = acc[i][j][r] + bv;
                    if (ACT == 1) v = (v > 20.f) ? v : log1pf(__expf(v));
                    C[(size_t)rowm * ldc + coln] = v;
                }
            }
    }
}

// ---------------------------------------------------------------------------
// Split-K reduces with fused epilogues (z-batched over dir).
// ---------------------------------------------------------------------------
__global__ __launch_bounds__(256)
void reduce_xdbl_k(const float* __restrict__ part,
                   float* __restrict__ xdbl0, float* __restrict__ xdbl1,
                   unsigned short* __restrict__ dtb0, unsigned short* __restrict__ dtb1)
{
    const int dz = blockIdx.z;
    const float* P = part + (size_t)dz * 16 * MROWS * XDBL_LD;
    float* xdbl = dz ? xdbl1 : xdbl0;
    unsigned short* dtb = dz ? dtb1 : dtb0;
    int i = blockIdx.x * 256 + threadIdx.x;
    int row = i >> 5;
    int c4 = (i & 31) << 2;
    float4 s = make_float4(0.f, 0.f, 0.f, 0.f);
    #pragma unroll
    for (int k = 0; k < 16; ++k) {
        float4 v = *(const float4*)(P + (size_t)k * MROWS * XDBL_LD + (size_t)row * XDBL_LD + c4);
        s.x += v.x; s.y += v.y; s.z += v.z; s.w += v.w;
    }
    *(float4*)(xdbl + (size_t)row * XDBL_LD + c4) = s;
    if (c4 < DT_RANK) {
        float f[4] = {s.x, s.y, s.z, s.w};
        unsigned short h[4], l[4];
        #pragma unroll
        for (int j = 0; j < 4; ++j) hl_split(f[j], h[j], l[j]);
        *(ushort4*)(dtb + (size_t)row * (2 * DT_RANK) + c4) = make_ushort4(h[0], h[1], h[2], h[3]);
        *(ushort4*)(dtb + (size_t)row * (2 * DT_RANK) + DT_RANK + c4) = make_ushort4(l[0], l[1], l[2], l[3]);
    }
}

// mid: z=0/1 -> reduce out-proj partials + bias + flip -> tmpb; z=2 -> proj_W split.
__global__ __launch_bounds__(256)
void mid_kernel(const float* __restrict__ part2,
                const float* __restrict__ bout0, const float* __restrict__ bout1,
                unsigned short* __restrict__ tmpb,
                const float* __restrict__ projW, unsigned short* __restrict__ pWb)
{
    const int dz = blockIdx.z;
    const int tid = threadIdx.x;
    if (dz == 2) {
        split_block(projW, D_MODEL, 2 * D_MODEL, 2 * D_MODEL, pWb, D_MODEL, false, blockIdx.x, tid);
        return;
    }
    const float* P = part2 + (size_t)dz * 4 * MROWS * D_MODEL;
    const float* bias = dz ? bout1 : bout0;
    const int colofs = dz ? D_MODEL : 0;
    int i = blockIdx.x * 256 + tid;
    int row = i >> 8;
    int c4 = (i & 255) << 2;
    float4 s = make_float4(bias[c4], bias[c4 + 1], bias[c4 + 2], bias[c4 + 3]);
    #pragma unroll
    for (int k = 0; k < 4; ++k) {
        float4 v = *(const float4*)(P + (size_t)k * MROWS * D_MODEL + (size_t)row * D_MODEL + c4);
        s.x += v.x; s.y += v.y; s.z += v.z; s.w += v.w;
    }
    int orow = row;
    if (dz) { int bb = row >> 10, t = row & 1023; orow = (bb << 10) + 1023 - t; }
    float f[4] = {s.x, s.y, s.z, s.w};
    unsigned short h[4], l[4];
    #pragma unroll
    for (int j = 0; j < 4; ++j) hl_split(f[j], h[j], l[j]);
    *(ushort4*)(tmpb + (size_t)orow * 4096 + colofs + c4) = make_ushort4(h[0], h[1], h[2], h[3]);
    *(ushort4*)(tmpb + (size_t)orow * 4096 + 2048 + colofs + c4) = make_ushort4(l[0], l[1], l[2], l[3]);
}

__global__ __launch_bounds__(256)
void reduce_out_k(const float* __restrict__ part, const float* __restrict__ bias,
                  float* __restrict__ out)
{
    int i = blockIdx.x * 256 + threadIdx.x;
    int row = i >> 8;
    int c4 = (i & 255) << 2;
    float4 s = make_float4(bias[c4], bias[c4 + 1], bias[c4 + 2], bias[c4 + 3]);
    #pragma unroll
    for (int k = 0; k < 8; ++k) {
        float4 v = *(const float4*)(part + (size_t)k * MROWS * D_MODEL + (size_t)row * D_MODEL + c4);
        s.x += v.x; s.y += v.y; s.z += v.z; s.w += v.w;
    }
    *(float4*)(out + (size_t)row * D_MODEL + c4) = s;
}

// ---------------------------------------------------------------------------
// Causal depthwise conv + SiLU -> ub (hi|lo bf16). z = dir.
// ---------------------------------------------------------------------------
__global__ __launch_bounds__(256)
void conv_silu_kernel(const float* __restrict__ xz0, const float* __restrict__ xz1,
                      const float* __restrict__ cw0, const float* __restrict__ cw1,
                      const float* __restrict__ cb0, const float* __restrict__ cb1,
                      unsigned short* __restrict__ ub0, unsigned short* __restrict__ ub1)
{
    const int dz = blockIdx.z;
    const float* xz = dz ? xz1 : xz0;
    const float* convw = dz ? cw1 : cw0;
    const float* convb = dz ? cb1 : cb0;
    unsigned short* ub = dz ? ub1 : ub0;
    int idx = blockIdx.x * 256 + threadIdx.x;
    int d = idx % D_INNER;
    int r = idx / D_INNER;
    int t = r % SEQLEN;
    float acc = convb[d];
    #pragma unroll
    for (int k = 0; k < D_CONV; ++k) {
        int back = D_CONV - 1 - k;
        if (t - back >= 0)
            acc += xz[(size_t)(r - back) * (2 * D_INNER) + d] * convw[d * D_CONV + k];
    }
    float v = acc * sigmoidf_(acc);
    unsigned short h, l;
    hl_split(v, h, l);
    ub[(size_t)r * (2 * D_INNER) + d] = h;
    ub[(size_t)r * (2 * D_INNER) + D_INNER + d] = l;
}

// ---------------------------------------------------------------------------
// Chunked selective scan, thread-per-channel: each thread owns (dir,b,d,chunk)
// with all 16 states in registers. No shuffles, no divergence, no broadcast-
// redundant loads. NCHUNK=32 (CLEN=32) for occupancy.
// aprod/hfin layout: [chunk][chg=dir*4096+b*2048+d][16n] (coalesced all phases)
// phase2 in-place: aprod becomes hin (per-thread read-before-write).
// ---------------------------------------------------------------------------
__global__ __launch_bounds__(256)
void scan_phase1(const float* __restrict__ delta0, const float* __restrict__ delta1,
                 const unsigned short* __restrict__ ub0, const unsigned short* __restrict__ ub1,
                 const float* __restrict__ xdbl0, const float* __restrict__ xdbl1,
                 const float* __restrict__ Alog0, const float* __restrict__ Alog1,
                 float* __restrict__ aprod, float* __restrict__ hfin)
{
    const int gid = blockIdx.x * 256 + threadIdx.x;   // [0, NCHUNK*NCHG)
    const int chg = gid & (NCHG - 1);
    const int chunk = gid >> 13;
    const int dir = chg >> 12;
    const int bd = chg & 4095;
    const int b = bd >> 11, d = bd & 2047;
    const float* delta = dir ? delta1 : delta0;
    const unsigned short* ub = dir ? ub1 : ub0;
    const float* xdbl = dir ? xdbl1 : xdbl0;
    const float* Alog = dir ? Alog1 : Alog0;

    float Av[16], h[16], ap[16];
    #pragma unroll
    for (int n = 0; n < 16; ++n) {
        Av[n] = -__expf(Alog[d * D_STATE + n]);
        h[n] = 0.f; ap[n] = 1.f;
    }
    const int t0 = chunk * CLEN;
    for (int t = t0; t < t0 + CLEN; ++t) {
        const size_t r = (size_t)b * SEQLEN + t;
        float dlt = delta[r * D_INNER + d];
        float uu = us2f(ub[r * 4096 + d]) + us2f(ub[r * 4096 + 2048 + d]);
        float du = dlt * uu;
        float4 bq[4];
        #pragma unroll
        for (int q = 0; q < 4; ++q)
            bq[q] = *(const float4*)(xdbl + r * XDBL_LD + DT_RANK + q * 4);
        #pragma unroll
        for (int n = 0; n < 16; ++n) {
            float Bv = ((const float*)&bq[n >> 2])[n & 3];
            float dA = __expf(dlt * Av[n]);
            h[n] = h[n] * dA + du * Bv;
            ap[n] *= dA;
        }
    }
    float* pa = aprod + (size_t)chunk * (NCHG * 16) + (size_t)chg * 16;
    float* pf = hfin  + (size_t)chunk * (NCHG * 16) + (size_t)chg * 16;
    #pragma unroll
    for (int q = 0; q < 4; ++q) {
        *(float4*)(pa + q * 4) = make_float4(ap[q*4], ap[q*4+1], ap[q*4+2], ap[q*4+3]);
        *(float4*)(pf + q * 4) = make_float4(h[q*4], h[q*4+1], h[q*4+2], h[q*4+3]);
    }
}

__global__ __launch_bounds__(256)
void scan_phase2(float* __restrict__ aprod /* in: A, out: hin */,
                 const float* __restrict__ hfin)
{
    const int gid = blockIdx.x * 256 + threadIdx.x;   // [0, NCHG*16)
    float h = 0.f;
    for (int c = 0; c < NCHUNK; ++c) {
        const size_t idx = (size_t)c * (NCHG * 16) + gid;
        float a = aprod[idx];
        float f = hfin[idx];
        aprod[idx] = h;         // hin for this chunk
        h = a * h + f;
    }
}

__global__ __launch_bounds__(256)
void scan_phase3(const float* __restrict__ delta0, const float* __restrict__ delta1,
                 unsigned short* __restrict__ ub0, unsigned short* __restrict__ ub1,
                 const float* __restrict__ xdbl0, const float* __restrict__ xdbl1,
                 const float* __restrict__ Alog0, const float* __restrict__ Alog1,
                 const float* __restrict__ Dsk0, const float* __restrict__ Dsk1,
                 const float* __restrict__ xz0, const float* __restrict__ xz1,
                 const float* __restrict__ hin)
{
    const int gid = blockIdx.x * 256 + threadIdx.x;
    const int chg = gid & (NCHG - 1);
    const int chunk = gid >> 13;
    const int dir = chg >> 12;
    const int bd = chg & 4095;
    const int b = bd >> 11, d = bd & 2047;
    const float* delta = dir ? delta1 : delta0;
    unsigned short* ub = dir ? ub1 : ub0;
    const float* xdbl = dir ? xdbl1 : xdbl0;
    const float* Alog = dir ? Alog1 : Alog0;
    const float* Dsk = dir ? Dsk1 : Dsk0;
    const float* xz = dir ? xz1 : xz0;

    float Av[16], h[16];
    const float* ph = hin + (size_t)chunk * (NCHG * 16) + (size_t)chg * 16;
    #pragma unroll
    for (int n = 0; n < 16; ++n) {
        Av[n] = -__expf(Alog[d * D_STATE + n]);
        h[n] = ph[n];
    }
    const float Dv = Dsk[d];
    const int t0 = chunk * CLEN;
    for (int t = t0; t < t0 + CLEN; ++t) {
        const size_t r = (size_t)b * SEQLEN + t;
        float dlt = delta[r * D_INNER + d];
        float uu = us2f(ub[r * 4096 + d]) + us2f(ub[r * 4096 + 2048 + d]);
        float du = dlt * uu;
        float4 bq[4], cq[4];
        #pragma unroll
        for (int q = 0; q < 4; ++q) {
            bq[q] = *(const float4*)(xdbl + r * XDBL_LD + DT_RANK + q * 4);
            cq[q] = *(const float4*)(xdbl + r * XDBL_LD + DT_RANK + D_STATE + q * 4);
        }
        float p0 = 0.f, p1 = 0.f, p2 = 0.f, p3 = 0.f;
        #pragma unroll
        for (int n = 0; n < 16; ++n) {
            float Bv = ((const float*)&bq[n >> 2])[n & 3];
            float Cv = ((const float*)&cq[n >> 2])[n & 3];
            float dA = __expf(dlt * Av[n]);
            h[n] = h[n] * dA + du * Bv;
            if ((n & 3) == 0) p0 += h[n] * Cv;
            else if ((n & 3) == 1) p1 += h[n] * Cv;
            else if ((n & 3) == 2) p2 += h[n] * Cv;
            else p3 += h[n] * Cv;
        }
        float y = ((p0 + p1) + (p2 + p3)) + uu * Dv;
        float zv = xz[r * (2 * D_INNER) + D_INNER + d];
        float v = y * (zv * sigmoidf_(zv));
        unsigned short hh, ll;
        hl_split(v, hh, ll);
        ub[r * 4096 + d] = hh;
        ub[r * 4096 + 2048 + d] = ll;
    }
}

// ---------------------------------------------------------------------------
extern "C" void kernel_launch(void* const* d_in, const int* in_sizes, int n_in,
                              void* d_out, int out_size, void* d_ws, size_t ws_size,
                              hipStream_t stream)
{
    const float* x = (const float*)d_in[0];
    const float* proj_W = (const float*)d_in[23];
    const float* proj_b = (const float*)d_in[24];
    float* out = (float*)d_out;

    const float *Win[2], *bin_[2], *convw[2], *convb[2], *Wx[2], *Wdt[2], *bdt[2],
                *Alog[2], *Dsk[2], *Wout[2], *bout[2];
    for (int dir = 0; dir < 2; ++dir) {
        const int base = 1 + dir * 11;
        Win[dir]   = (const float*)d_in[base + 0];
        bin_[dir]  = (const float*)d_in[base + 1];
        convw[dir] = (const float*)d_in[base + 2];
        convb[dir] = (const float*)d_in[base + 3];
        Wx[dir]    = (const float*)d_in[base + 4];
        Wdt[dir]   = (const float*)d_in[base + 5];
        bdt[dir]   = (const float*)d_in[base + 6];
        Alog[dir]  = (const float*)d_in[base + 7];
        Dsk[dir]   = (const float*)d_in[base + 8];
        Wout[dir]  = (const float*)d_in[base + 9];
        bout[dir]  = (const float*)d_in[base + 10];
    }

    // ---- explicit arena (lifetime-checked overlays; high-water ~184 MiB) ----
    char* ws = (char*)d_ws;
    const size_t MB = 1ull << 20;
    float* xz[2]            = {(float*)(ws + 0 * MB),   (float*)(ws + 32 * MB)};   // [0,64)
    unsigned short* ub[2]   = {(unsigned short*)(ws + 64 * MB),
                               (unsigned short*)(ws + 80 * MB)};                   // [64,96)
    unsigned short* Winb[2] = {(unsigned short*)(ws + 96 * MB),
                               (unsigned short*)(ws + 112 * MB)};                  // [96,128)
    unsigned short* xc[2]   = {(unsigned short*)(ws + 128 * MB),
                               (unsigned short*)(ws + 136 * MB)};                  // [128,144)
    // overlays:
    float* part             = (float*)(ws + 112 * MB);          // xproj partials after gemm1
    float* part2            = (float*)(ws + 0 * MB);            // after scan3 (xz dead)
    float* delta[2]         = {(float*)(ws + 112 * MB), (float*)(ws + 128 * MB)};
    unsigned short* Woutb[2]= {(unsigned short*)(ws + 96 * MB),
                               (unsigned short*)(ws + 104 * MB)};                  // in Winb0
    unsigned short* yzb[2]  = {ub[0], ub[1]};                   // in-place scan3
    unsigned short* tmpb    = ub[0];                            // after out-proj
    unsigned short* pWb     = ub[1];                            // after out-proj
    // smalls [144,150):
    unsigned short* Wxb[2]  = {(unsigned short*)(ws + 144 * MB), (unsigned short*)(ws + 145 * MB)};
    unsigned short* Wdtb[2] = {(unsigned short*)(ws + 146 * MB), (unsigned short*)(ws + 146 * MB + 512 * 1024)};
    unsigned short* dtb[2]  = {(unsigned short*)(ws + 147 * MB), (unsigned short*)(ws + 147 * MB + 512 * 1024)};
    float* xdbl[2]          = {(float*)(ws + 148 * MB), (float*)(ws + 149 * MB)};
    // scan buffers [150,184): [NCHUNK][NCHG][16] floats = 16.78 MB each
    float* aprod            = (float*)(ws + 150 * MB);          // becomes hin in phase2
    float* hfin             = (float*)(ws + 167 * MB);

    dim3 blk(256);

    // 1. prep1: all pre-GEMM splits
    prep1_kernel<<<13056, blk, 0, stream>>>(
        x, Win[0], Win[1], Wx[0], Wx[1], Wdt[0], Wdt[1],
        xc[0], xc[1], Winb[0], Winb[1], Wxb[0], Wxb[1], Wdtb[0], Wdtb[1]);

    // 2. input proj (8-phase 256²), both dirs
    gemm256<0, false><<<dim3(16, 8, 2), dim3(512), 0, stream>>>(
        xc[0], xc[1], Winb[0], Winb[1], bin_[0], bin_[1], xz[0], xz[1],
        nullptr, 4096, 4096, D_MODEL, 1, 16);

    // 3. prep2: Wout splits (overlay Winb)
    prep2_kernel<<<4096, blk, 0, stream>>>(Wout[0], Wout[1], Woutb[0], Woutb[1]);

    // 4. conv + silu -> ub hi/lo (both dirs)
    conv_silu_kernel<<<dim3((MROWS * D_INNER) / 256, 1, 2), blk, 0, stream>>>(
        xz[0], xz[1], convw[0], convw[1], convb[0], convb[1], ub[0], ub[1]);

    // 5. xproj split-K (128², nks=16, both dirs) -> part
    gemm_mfma<0, true><<<dim3(1, 16, 32), blk, 0, stream>>>(
        ub[0], ub[1], Wxb[0], Wxb[1], nullptr, nullptr, nullptr, nullptr,
        part, XDBL_LD, XDBL_LD, D_INNER, 16);

    // 6. reduce -> xdbl fp32 + dtb hi/lo (both dirs)
    reduce_xdbl_k<<<dim3(256, 1, 2), blk, 0, stream>>>(
        part, xdbl[0], xdbl[1], dtb[0], dtb[1]);

    // 7. dt proj (128², both dirs)
    gemm_mfma<1, false><<<dim3(16, 16, 2), blk, 0, stream>>>(
        dtb[0], dtb[1], Wdtb[0], Wdtb[1], bdt[0], bdt[1], delta[0], delta[1],
        nullptr, D_INNER, D_INNER, DT_RANK, 1);

    // 8-10. thread-per-channel chunked scan
    scan_phase1<<<NCHUNK * NCHG / 256, blk, 0, stream>>>(
        delta[0], delta[1], ub[0], ub[1], xdbl[0], xdbl[1], Alog[0], Alog[1],
        aprod, hfin);
    scan_phase2<<<NCHG * 16 / 256, blk, 0, stream>>>(aprod, hfin);
    scan_phase3<<<NCHUNK * NCHG / 256, blk, 0, stream>>>(
        delta[0], delta[1], ub[0], ub[1], xdbl[0], xdbl[1], Alog[0], Alog[1],
        Dsk[0], Dsk[1], xz[0], xz[1], aprod);

    // 11. out proj (8-phase 256², nks=4, both dirs) -> part2 [xz dead]
    gemm256<0, true><<<dim3(4, 8, 8), dim3(512), 0, stream>>>(
        yzb[0], yzb[1], Woutb[0], Woutb[1], nullptr, nullptr, nullptr, nullptr,
        part2, D_MODEL, D_MODEL, D_INNER, 4, 8);

    // 12. mid: reduce out-proj partials -> tmpb + split proj_W -> pWb
    mid_kernel<<<dim3(2048, 1, 3), blk, 0, stream>>>(
        part2, bout[0], bout[1], tmpb, proj_W, pWb);

    // 13. final proj (8-phase 256², nks=8) -> part2
    gemm256<0, true><<<dim3(4, 8, 8), dim3(512), 0, stream>>>(
        tmpb, nullptr, pWb, nullptr, nullptr, nullptr, nullptr, nullptr,
        part2, D_MODEL, D_MODEL, 2 * D_MODEL, 8, 4);

    // 14. reduce -> out
    reduce_out_k<<<2048, blk, 0, stream>>>(part2, proj_b, out);
}

// Round 10
// 482.279 us; speedup vs baseline: 6.0108x; 1.0189x over previous
//
#include <hip/hip_runtime.h>
#include <math.h>

#define D_MODEL 1024
#define D_STATE 16
#define D_CONV  4
#define D_INNER 2048
#define DT_RANK 64
#define BATCH   2
#define SEQLEN  1024
#define MROWS   2048
#define XDBL_LD 128
#define NCHUNK  32
#define CLEN    (SEQLEN / NCHUNK)   // 32
#define NCHG    8192                // 2 dirs * BATCH * D_INNER

typedef __attribute__((ext_vector_type(8))) short bf16x8;
typedef __attribute__((ext_vector_type(4))) float f32x4;

#define BARR() asm volatile("s_barrier" ::: "memory")
#define VMW(n) asm volatile("s_waitcnt vmcnt(" #n ")" ::: "memory")

static __device__ __forceinline__ float sigmoidf_(float x) {
    return 1.f / (1.f + __expf(-x));
}
static __device__ __forceinline__ unsigned short bf16rn(float f) {
    unsigned u = __float_as_uint(f);
    return (unsigned short)((u + 0x7FFFu + ((u >> 16) & 1u)) >> 16);
}
static __device__ __forceinline__ void hl_split(float f, unsigned short& h, unsigned short& l) {
    h = bf16rn(f);
    l = bf16rn(f - __uint_as_float((unsigned)h << 16));
}
static __device__ __forceinline__ float us2f(unsigned short u) {
    return __uint_as_float((unsigned)u << 16);
}

// ---------------------------------------------------------------------------
// Shared split worker: fp32 (R x C) -> bf16 (Rout x 2C) hi|lo. blk-local idx.
// ---------------------------------------------------------------------------
static __device__ __forceinline__
void split_block(const float* __restrict__ in, int R, int C, int ldin,
                 unsigned short* __restrict__ out, int Rout, bool flip,
                 int blk, int tid)
{
    int q = blk * 256 + tid;
    int qpr = C >> 2;
    int row = q / qpr;
    int c4 = (q - row * qpr) << 2;
    if (row >= Rout) return;
    unsigned short h[4] = {0, 0, 0, 0}, l[4] = {0, 0, 0, 0};
    if (row < R) {
        int sr = row;
        if (flip) { int b = row >> 10, t = row & 1023; sr = (b << 10) + (1023 - t); }
        float4 v = *(const float4*)(in + (size_t)sr * ldin + c4);
        float f[4] = {v.x, v.y, v.z, v.w};
        #pragma unroll
        for (int i = 0; i < 4; ++i) hl_split(f[i], h[i], l[i]);
    }
    size_t ob = (size_t)row * (2 * C);
    *(ushort4*)(out + ob + c4)     = make_ushort4(h[0], h[1], h[2], h[3]);
    *(ushort4*)(out + ob + C + c4) = make_ushort4(l[0], l[1], l[2], l[3]);
}

// prep1: all pre-GEMM conversions (no flipped x needed anymore — the
// input-proj epilogue writes dir-1 rows flipped).
// ranges: x->xc0 [0,2048), Win0 [2048,6144), Win1 [6144,10240),
// Wx0 [10240,10496), Wx1 [10496,10752), Wdt0 [10752,10880), Wdt1 [10880,11008)
__global__ __launch_bounds__(256)
void prep1_kernel(const float* __restrict__ x,
                  const float* __restrict__ Win0, const float* __restrict__ Win1,
                  const float* __restrict__ Wx0,  const float* __restrict__ Wx1,
                  const float* __restrict__ Wdt0, const float* __restrict__ Wdt1,
                  unsigned short* xc0,
                  unsigned short* Winb0, unsigned short* Winb1,
                  unsigned short* Wxb0, unsigned short* Wxb1,
                  unsigned short* Wdtb0, unsigned short* Wdtb1)
{
    int b = blockIdx.x, tid = threadIdx.x;
    if      (b < 2048)  split_block(x,    MROWS, D_MODEL, D_MODEL, xc0,  MROWS, false, b,        tid);
    else if (b < 6144)  split_block(Win0, 4096,  D_MODEL, D_MODEL, Winb0, 4096, false, b - 2048, tid);
    else if (b < 10240) split_block(Win1, 4096,  D_MODEL, D_MODEL, Winb1, 4096, false, b - 6144, tid);
    else if (b < 10496) split_block(Wx0,  96,    D_INNER, D_INNER, Wxb0,  128,  false, b - 10240, tid);
    else if (b < 10752) split_block(Wx1,  96,    D_INNER, D_INNER, Wxb1,  128,  false, b - 10496, tid);
    else if (b < 10880) split_block(Wdt0, D_INNER, DT_RANK, DT_RANK, Wdtb0, D_INNER, false, b - 10752, tid);
    else                split_block(Wdt1, D_INNER, DT_RANK, DT_RANK, Wdtb1, D_INNER, false, b - 10880, tid);
}

// ---------------------------------------------------------------------------
// 256x256 8-phase bf16x3 MFMA GEMM (T2+T3+T4+T5).
// KTS now COMPILE-TIME (16/8/4, powers of 2): koff divisions become shifts —
// they sat in the staging critical path before each phase barrier (r9 fix).
// DUALN: A shared across both dirs; column-tile selects W/bias/C per dir and
// dir-1 C rows are written time-flipped (flip(x)@W == row-flip of x@W).
// ---------------------------------------------------------------------------
#define SWZ(row) (((row) >> 1) & 3)
#define RDA(p, kk, row) (*(const bf16x8*)&AS[p][kk][row][(fs ^ SWZ(row)) << 3])
#define RDB(p, kk, row) (*(const bf16x8*)&BS[p][kk][row][(fs ^ SWZ(row)) << 3])

#define KTILE(MODE, kt) do { \
    const int p_ = (kt) & 1; \
    bf16x8 bF[4]; \
    { /* P1 */ \
        bf16x8 aF[4]; \
        _Pragma("unroll") for (int f = 0; f < 4; ++f) { int rw = wm + f * 16 + fr; aF[f] = RDA(p_, 0, rw); } \
        _Pragma("unroll") for (int g = 0; g < 4; ++g) { int rw = wn + g * 16 + fr; bF[g] = RDB(p_, 0, rw); } \
        if (MODE < 2) stageA((kt) + 1, 1); \
        BARR(); __builtin_amdgcn_s_setprio(1); \
        _Pragma("unroll") for (int f = 0; f < 4; ++f) \
        _Pragma("unroll") for (int g = 0; g < 4; ++g) \
            acc[f][g] = __builtin_amdgcn_mfma_f32_16x16x32_bf16(aF[f], bF[g], acc[f][g], 0, 0, 0); \
        __builtin_amdgcn_s_setprio(0); BARR(); \
    } \
    { /* P2 */ \
        if (MODE == 2) { VMW(0); } else { VMW(8); } \
        bf16x8 aF[4]; \
        _Pragma("unroll") for (int f = 0; f < 4; ++f) { int rw = wm + 64 + f * 16 + fr; aF[f] = RDA(p_, 0, rw); } \
        if (MODE == 0) stageB((kt) + 2, 0); \
        BARR(); __builtin_amdgcn_s_setprio(1); \
        _Pragma("unroll") for (int f = 0; f < 4; ++f) \
        _Pragma("unroll") for (int g = 0; g < 4; ++g) \
            acc[4 + f][g] = __builtin_amdgcn_mfma_f32_16x16x32_bf16(aF[f], bF[g], acc[4 + f][g], 0, 0, 0); \
        __builtin_amdgcn_s_setprio(0); BARR(); \
    } \
    { /* P3 */ \
        bf16x8 aF[4]; \
        _Pragma("unroll") for (int f = 0; f < 4; ++f) { int rw = wm + f * 16 + fr; aF[f] = RDA(p_, 1, rw); } \
        _Pragma("unroll") for (int g = 0; g < 4; ++g) { int rw = wn + g * 16 + fr; bF[g] = RDB(p_, 1, rw); } \
        if (MODE == 0) stageA((kt) + 2, 0); \
        BARR(); __builtin_amdgcn_s_setprio(1); \
        _Pragma("unroll") for (int f = 0; f < 4; ++f) \
        _Pragma("unroll") for (int g = 0; g < 4; ++g) \
            acc[f][g] = __builtin_amdgcn_mfma_f32_16x16x32_bf16(aF[f], bF[g], acc[f][g], 0, 0, 0); \
        __builtin_amdgcn_s_setprio(0); BARR(); \
    } \
    { /* P4 */ \
        if (MODE == 0) { VMW(8); } else if (MODE == 1) { VMW(4); } \
        bf16x8 aF[4]; \
        _Pragma("unroll") for (int f = 0; f < 4; ++f) { int rw = wm + 64 + f * 16 + fr; aF[f] = RDA(p_, 1, rw); } \
        if (MODE == 0) stageB((kt) + 2, 1); \
        BARR(); __builtin_amdgcn_s_setprio(1); \
        _Pragma("unroll") for (int f = 0; f < 4; ++f) \
        _Pragma("unroll") for (int g = 0; g < 4; ++g) \
            acc[4 + f][g] = __builtin_amdgcn_mfma_f32_16x16x32_bf16(aF[f], bF[g], acc[4 + f][g], 0, 0, 0); \
        __builtin_amdgcn_s_setprio(0); BARR(); \
    } \
} while (0)

template<int ACT, bool PART, int KTS, bool DUALN>
__global__ __launch_bounds__(512, 1)
void gemm256(const unsigned short* __restrict__ A0,
             const unsigned short* __restrict__ A1,
             const unsigned short* __restrict__ W0,
             const unsigned short* __restrict__ W1,
             const float* __restrict__ bias0,
             const float* __restrict__ bias1,
             float* __restrict__ C0, float* __restrict__ C1,
             float* __restrict__ part,
             int ldc, int N, int K, int nks)
{
    __shared__ unsigned short AS[2][2][256][32];
    __shared__ unsigned short BS[2][2][256][32];

    const int tid = threadIdx.x;
    const int lane = tid & 63;
    const int wid = tid >> 6;

    const int z = blockIdx.z;
    const int zdir = z / nks;
    const int ks = z - zdir * nks;

    const int nbx = gridDim.x;
    const int nwg = nbx * gridDim.y;
    int bid = blockIdx.y * nbx + blockIdx.x;
    int q8 = nwg >> 3;
    int swz = (bid & 7) * q8 + (bid >> 3);
    const int bm = (swz / nbx) * 256;
    const int bn = (swz % nbx) * 256;

    // direction & effective column base
    int dn, bnn;
    if (DUALN) { dn = (bn >= (N >> 1)) ? 1 : 0; bnn = bn - dn * (N >> 1); }
    else       { dn = zdir; bnn = bn; }
    const unsigned short* A = (DUALN || dn == 0) ? A0 : A1;
    const unsigned short* W = dn ? W1 : W0;

    const int ldg = 2 * K;
    constexpr int NT = 3 * KTS;
    const int Kc = KTS * 64;
    const int kbase = ks * Kc;

    const int wm = (wid >> 2) * 128;
    const int wn = (wid & 3) * 64;
    const int fr = lane & 15;
    const int fs = lane >> 4;

    f32x4 acc[8][4];
    #pragma unroll
    for (int i = 0; i < 8; ++i)
        #pragma unroll
        for (int j = 0; j < 4; ++j) {
            f32x4 zv = {0.f, 0.f, 0.f, 0.f};
            acc[i][j] = zv;
        }

    auto koffA = [&](int t) { unsigned tu = (unsigned)t; unsigned sg = tu / KTS;
                              unsigned w = tu - sg * KTS;
                              return (int)((sg == 1 ? (unsigned)K : 0u) + kbase + w * 64); };
    auto koffB = [&](int t) { unsigned tu = (unsigned)t; unsigned sg = tu / KTS;
                              unsigned w = tu - sg * KTS;
                              return (int)((sg == 2 ? (unsigned)K : 0u) + kbase + w * 64); };

    auto stageA = [&](int t, int kk) {
        int ko = koffA(t) + kk * 32;
        unsigned short* dst = &AS[t & 1][kk][0][0];
        #pragma unroll
        for (int i = 0; i < 2; ++i) {
            int s = i * 512 + tid;
            int row = s >> 2, sl = s & 3, lsl = sl ^ SWZ(row);
            const unsigned short* src = A + (size_t)(bm + row) * ldg + ko + lsl * 8;
            __builtin_amdgcn_global_load_lds(
                (const __attribute__((address_space(1))) void*)src,
                (__attribute__((address_space(3))) void*)(dst + s * 8), 16, 0, 0);
        }
    };
    auto stageB = [&](int t, int kk) {
        int ko = koffB(t) + kk * 32;
        unsigned short* dst = &BS[t & 1][kk][0][0];
        #pragma unroll
        for (int i = 0; i < 2; ++i) {
            int s = i * 512 + tid;
            int row = s >> 2, sl = s & 3, lsl = sl ^ SWZ(row);
            const unsigned short* src = W + (size_t)(bnn + row) * ldg + ko + lsl * 8;
            __builtin_amdgcn_global_load_lds(
                (const __attribute__((address_space(1))) void*)src,
                (__attribute__((address_space(3))) void*)(dst + s * 8), 16, 0, 0);
        }
    };

    // prologue: 7 half-tiles (K-tile 0 complete + 3/4 of K-tile 1)
    stageB(0, 0); stageA(0, 0); stageB(0, 1); stageA(0, 1);
    stageB(1, 0); stageA(1, 0); stageB(1, 1);
    VMW(6);
    BARR();

    #pragma unroll 1
    for (int kt = 0; kt < NT - 2; ++kt) KTILE(0, kt);
    KTILE(1, NT - 2);
    KTILE(2, NT - 1);

    if (PART) {
        float* P = part + (size_t)z * ((size_t)MROWS * N);
        #pragma unroll
        for (int i = 0; i < 8; ++i)
            #pragma unroll
            for (int j = 0; j < 4; ++j) {
                int coln = bnn + wn + j * 16 + fr;
                #pragma unroll
                for (int r = 0; r < 4; ++r) {
                    int rowm = bm + wm + i * 16 + fs * 4 + r;
                    P[(size_t)rowm * N + coln] = acc[i][j][r];
                }
            }
    } else {
        const float* bias = dn ? bias1 : bias0;
        float* C = dn ? C1 : C0;
        #pragma unroll
        for (int i = 0; i < 8; ++i)
            #pragma unroll
            for (int j = 0; j < 4; ++j) {
                int coln = bnn + wn + j * 16 + fr;
                float bv = bias ? bias[coln] : 0.f;
                #pragma unroll
                for (int r = 0; r < 4; ++r) {
                    int rowm = bm + wm + i * 16 + fs * 4 + r;
                    float v = acc[i][j][r] + bv;
                    if (ACT == 1) v = (v > 20.f) ? v : log1pf(__expf(v));
                    int crow = rowm;
                    if (DUALN && dn) { int bb = rowm >> 10, t = rowm & 1023; crow = (bb << 10) + 1023 - t; }
                    C[(size_t)crow * ldc + coln] = v;
                }
            }
    }
}

// ---------------------------------------------------------------------------
// 128x128 bf16x3 MFMA GEMM (2-barrier structure) for small shapes.
// ---------------------------------------------------------------------------
template<int ACT, bool PART>
__global__ __launch_bounds__(256)
void gemm_mfma(const unsigned short* __restrict__ A0,
               const unsigned short* __restrict__ A1,
               const unsigned short* __restrict__ W0,
               const unsigned short* __restrict__ W1,
               const float* __restrict__ bias0,
               const float* __restrict__ bias1,
               float* __restrict__ C0, float* __restrict__ C1,
               float* __restrict__ part,
               int ldc, int N, int K, int nks)
{
    __shared__ __align__(16) unsigned short As[128 * 32];
    __shared__ __align__(16) unsigned short Bs[128 * 32];

    const int tid = threadIdx.x;
    const int lane = tid & 63;
    const int wid = tid >> 6;

    const int z = blockIdx.z;
    const int dir = z / nks;
    const int ks = z - dir * nks;
    const unsigned short* A = dir ? A1 : A0;
    const unsigned short* W = dir ? W1 : W0;

    const int nbx = gridDim.x;
    const int nwg = nbx * gridDim.y;
    int bid = blockIdx.y * nbx + blockIdx.x;
    int q8 = nwg >> 3;
    int swz = (nwg >= 8) ? (bid & 7) * q8 + (bid >> 3) : bid;
    const int bm = (swz / nbx) * 128;
    const int bn = (swz % nbx) * 128;

    const int ldg = 2 * K;
    const int Kc = K / nks;
    const int kbase = ks * Kc;

    f32x4 acc[4][4];
    #pragma unroll
    for (int i = 0; i < 4; ++i)
        #pragma unroll
        for (int j = 0; j < 4; ++j) {
            f32x4 zv = {0.f, 0.f, 0.f, 0.f};
            acc[i][j] = zv;
        }

    const int r0 = tid >> 2;
    const int k0s = (tid & 3) ^ ((r0 >> 1) & 3);
    const int r1 = (256 + tid) >> 2;
    const int k1s = (tid & 3) ^ ((r1 >> 1) & 3);

    unsigned short* As_w0 = &As[(wid << 6) * 8];
    unsigned short* As_w1 = &As[(256 + (wid << 6)) * 8];
    unsigned short* Bs_w0 = &Bs[(wid << 6) * 8];
    unsigned short* Bs_w1 = &Bs[(256 + (wid << 6)) * 8];

    const int wm = (wid >> 1) * 64;
    const int wn = (wid & 1) * 64;
    const int fr = lane & 15;
    const int fs = lane >> 4;

    const int KS = Kc >> 5;
    #pragma unroll 1
    for (int seg = 0; seg < 3; ++seg) {
        const int aoff = ((seg == 1) ? K : 0) + kbase;
        const int boff = ((seg == 2) ? K : 0) + kbase;
        #pragma unroll 1
        for (int kt = 0; kt < KS; ++kt) {
            const int kk = kt << 5;
            const unsigned short* ga0 = A + (size_t)(bm + r0) * ldg + aoff + kk + k0s * 8;
            const unsigned short* ga1 = A + (size_t)(bm + r1) * ldg + aoff + kk + k1s * 8;
            const unsigned short* gw0 = W + (size_t)(bn + r0) * ldg + boff + kk + k0s * 8;
            const unsigned short* gw1 = W + (size_t)(bn + r1) * ldg + boff + kk + k1s * 8;
            __builtin_amdgcn_global_load_lds(
                (const __attribute__((address_space(1))) void*)ga0,
                (__attribute__((address_space(3))) void*)As_w0, 16, 0, 0);
            __builtin_amdgcn_global_load_lds(
                (const __attribute__((address_space(1))) void*)ga1,
                (__attribute__((address_space(3))) void*)As_w1, 16, 0, 0);
            __builtin_amdgcn_global_load_lds(
                (const __attribute__((address_space(1))) void*)gw0,
                (__attribute__((address_space(3))) void*)Bs_w0, 16, 0, 0);
            __builtin_amdgcn_global_load_lds(
                (const __attribute__((address_space(1))) void*)gw1,
                (__attribute__((address_space(3))) void*)Bs_w1, 16, 0, 0);
            __syncthreads();

            bf16x8 aF[4], bF[4];
            #pragma unroll
            for (int f = 0; f < 4; ++f) {
                int ra = wm + f * 16 + fr;
                int sa = fs ^ ((ra >> 1) & 3);
                aF[f] = *(const bf16x8*)&As[ra * 32 + sa * 8];
                int rb = wn + f * 16 + fr;
                int sb = fs ^ ((rb >> 1) & 3);
                bF[f] = *(const bf16x8*)&Bs[rb * 32 + sb * 8];
            }
            #pragma unroll
            for (int i = 0; i < 4; ++i)
                #pragma unroll
                for (int j = 0; j < 4; ++j)
                    acc[i][j] = __builtin_amdgcn_mfma_f32_16x16x32_bf16(
                        aF[i], bF[j], acc[i][j], 0, 0, 0);
            __syncthreads();
        }
    }

    if (PART) {
        float* P = part + (size_t)z * ((size_t)MROWS * N);
        #pragma unroll
        for (int i = 0; i < 4; ++i)
            #pragma unroll
            for (int j = 0; j < 4; ++j) {
                int coln = bn + wn + j * 16 + fr;
                #pragma unroll
                for (int r = 0; r < 4; ++r) {
                    int rowm = bm + wm + i * 16 + fs * 4 + r;
                    P[(size_t)rowm * N + coln] = acc[i][j][r];
                }
            }
    } else {
        const float* bias = dir ? bias1 : bias0;
        float* C = dir ? C1 : C0;
        #pragma unroll
        for (int i = 0; i < 4; ++i)
            #pragma unroll
            for (int j = 0; j < 4; ++j) {
                int coln = bn + wn + j * 16 + fr;
                float bv = bias ? bias[coln] : 0.f;
                #pragma unroll
                for (int r = 0; r < 4; ++r) {
                    int rowm = bm + wm + i * 16 + fs * 4 + r;
                    float v = acc[i][j][r] + bv;
                    if (ACT == 1) v = (v > 20.f) ? v : log1pf(__expf(v));
                    C[(size_t)rowm * ldc + coln] = v;
                }
            }
    }
}

// ---------------------------------------------------------------------------
// Split-K reduces with fused epilogues (z-batched over dir).
// ---------------------------------------------------------------------------
__global__ __launch_bounds__(256)
void reduce_xdbl_k(const float* __restrict__ part,
                   float* __restrict__ xdbl0, float* __restrict__ xdbl1,
                   unsigned short* __restrict__ dtb0, unsigned short* __restrict__ dtb1)
{
    const int dz = blockIdx.z;
    const float* P = part + (size_t)dz * 16 * MROWS * XDBL_LD;
    float* xdbl = dz ? xdbl1 : xdbl0;
    unsigned short* dtb = dz ? dtb1 : dtb0;
    int i = blockIdx.x * 256 + threadIdx.x;
    int row = i >> 5;
    int c4 = (i & 31) << 2;
    float4 s = make_float4(0.f, 0.f, 0.f, 0.f);
    #pragma unroll
    for (int k = 0; k < 16; ++k) {
        float4 v = *(const float4*)(P + (size_t)k * MROWS * XDBL_LD + (size_t)row * XDBL_LD + c4);
        s.x += v.x; s.y += v.y; s.z += v.z; s.w += v.w;
    }
    *(float4*)(xdbl + (size_t)row * XDBL_LD + c4) = s;
    if (c4 < DT_RANK) {
        float f[4] = {s.x, s.y, s.z, s.w};
        unsigned short h[4], l[4];
        #pragma unroll
        for (int j = 0; j < 4; ++j) hl_split(f[j], h[j], l[j]);
        *(ushort4*)(dtb + (size_t)row * (2 * DT_RANK) + c4) = make_ushort4(h[0], h[1], h[2], h[3]);
        *(ushort4*)(dtb + (size_t)row * (2 * DT_RANK) + DT_RANK + c4) = make_ushort4(l[0], l[1], l[2], l[3]);
    }
}

// mid: z=0/1 -> reduce out-proj partials + bias + flip -> tmpb; z=2 -> proj_W split.
__global__ __launch_bounds__(256)
void mid_kernel(const float* __restrict__ part2,
                const float* __restrict__ bout0, const float* __restrict__ bout1,
                unsigned short* __restrict__ tmpb,
                const float* __restrict__ projW, unsigned short* __restrict__ pWb)
{
    const int dz = blockIdx.z;
    const int tid = threadIdx.x;
    if (dz == 2) {
        split_block(projW, D_MODEL, 2 * D_MODEL, 2 * D_MODEL, pWb, D_MODEL, false, blockIdx.x, tid);
        return;
    }
    const float* P = part2 + (size_t)dz * 4 * MROWS * D_MODEL;
    const float* bias = dz ? bout1 : bout0;
    const int colofs = dz ? D_MODEL : 0;
    int i = blockIdx.x * 256 + tid;
    int row = i >> 8;
    int c4 = (i & 255) << 2;
    float4 s = make_float4(bias[c4], bias[c4 + 1], bias[c4 + 2], bias[c4 + 3]);
    #pragma unroll
    for (int k = 0; k < 4; ++k) {
        float4 v = *(const float4*)(P + (size_t)k * MROWS * D_MODEL + (size_t)row * D_MODEL + c4);
        s.x += v.x; s.y += v.y; s.z += v.z; s.w += v.w;
    }
    int orow = row;
    if (dz) { int bb = row >> 10, t = row & 1023; orow = (bb << 10) + 1023 - t; }
    float f[4] = {s.x, s.y, s.z, s.w};
    unsigned short h[4], l[4];
    #pragma unroll
    for (int j = 0; j < 4; ++j) hl_split(f[j], h[j], l[j]);
    *(ushort4*)(tmpb + (size_t)orow * 4096 + colofs + c4) = make_ushort4(h[0], h[1], h[2], h[3]);
    *(ushort4*)(tmpb + (size_t)orow * 4096 + 2048 + colofs + c4) = make_ushort4(l[0], l[1], l[2], l[3]);
}

__global__ __launch_bounds__(256)
void reduce_out_k(const float* __restrict__ part, const float* __restrict__ bias,
                  float* __restrict__ out)
{
    int i = blockIdx.x * 256 + threadIdx.x;
    int row = i >> 8;
    int c4 = (i & 255) << 2;
    float4 s = make_float4(bias[c4], bias[c4 + 1], bias[c4 + 2], bias[c4 + 3]);
    #pragma unroll
    for (int k = 0; k < 8; ++k) {
        float4 v = *(const float4*)(part + (size_t)k * MROWS * D_MODEL + (size_t)row * D_MODEL + c4);
        s.x += v.x; s.y += v.y; s.z += v.z; s.w += v.w;
    }
    *(float4*)(out + (size_t)row * D_MODEL + c4) = s;
}

// ---------------------------------------------------------------------------
// conv+prep2: z=0/1 -> causal depthwise conv + SiLU -> ub hi/lo (per dir);
// z=2 -> Wout splits (blocks < 4096 active).
// ---------------------------------------------------------------------------
__global__ __launch_bounds__(256)
void conv_prep_kernel(const float* __restrict__ xz0, const float* __restrict__ xz1,
                      const float* __restrict__ cw0, const float* __restrict__ cw1,
                      const float* __restrict__ cb0, const float* __restrict__ cb1,
                      unsigned short* __restrict__ ub0, unsigned short* __restrict__ ub1,
                      const float* __restrict__ Wout0, const float* __restrict__ Wout1,
                      unsigned short* __restrict__ Woutb0, unsigned short* __restrict__ Woutb1)
{
    const int dz = blockIdx.z;
    const int tid = threadIdx.x;
    if (dz == 2) {
        int b = blockIdx.x;
        if (b < 2048) split_block(Wout0, D_MODEL, D_INNER, D_INNER, Woutb0, D_MODEL, false, b, tid);
        else if (b < 4096) split_block(Wout1, D_MODEL, D_INNER, D_INNER, Woutb1, D_MODEL, false, b - 2048, tid);
        return;
    }
    const float* xz = dz ? xz1 : xz0;
    const float* convw = dz ? cw1 : cw0;
    const float* convb = dz ? cb1 : cb0;
    unsigned short* ub = dz ? ub1 : ub0;
    int idx = blockIdx.x * 256 + tid;
    int d = idx % D_INNER;
    int r = idx / D_INNER;
    int t = r % SEQLEN;
    float acc = convb[d];
    #pragma unroll
    for (int k = 0; k < D_CONV; ++k) {
        int back = D_CONV - 1 - k;
        if (t - back >= 0)
            acc += xz[(size_t)(r - back) * (2 * D_INNER) + d] * convw[d * D_CONV + k];
    }
    float v = acc * sigmoidf_(acc);
    unsigned short h, l;
    hl_split(v, h, l);
    ub[(size_t)r * (2 * D_INNER) + d] = h;
    ub[(size_t)r * (2 * D_INNER) + D_INNER + d] = l;
}

// ---------------------------------------------------------------------------
// Chunked selective scan, thread-per-channel (16 states in registers).
// ---------------------------------------------------------------------------
__global__ __launch_bounds__(256)
void scan_phase1(const float* __restrict__ delta0, const float* __restrict__ delta1,
                 const unsigned short* __restrict__ ub0, const unsigned short* __restrict__ ub1,
                 const float* __restrict__ xdbl0, const float* __restrict__ xdbl1,
                 const float* __restrict__ Alog0, const float* __restrict__ Alog1,
                 float* __restrict__ aprod, float* __restrict__ hfin)
{
    const int gid = blockIdx.x * 256 + threadIdx.x;
    const int chg = gid & (NCHG - 1);
    const int chunk = gid >> 13;
    const int dir = chg >> 12;
    const int bd = chg & 4095;
    const int b = bd >> 11, d = bd & 2047;
    const float* delta = dir ? delta1 : delta0;
    const unsigned short* ub = dir ? ub1 : ub0;
    const float* xdbl = dir ? xdbl1 : xdbl0;
    const float* Alog = dir ? Alog1 : Alog0;

    float Av[16], h[16], ap[16];
    #pragma unroll
    for (int n = 0; n < 16; ++n) {
        Av[n] = -__expf(Alog[d * D_STATE + n]);
        h[n] = 0.f; ap[n] = 1.f;
    }
    const int t0 = chunk * CLEN;
    for (int t = t0; t < t0 + CLEN; ++t) {
        const size_t r = (size_t)b * SEQLEN + t;
        float dlt = delta[r * D_INNER + d];
        float uu = us2f(ub[r * 4096 + d]) + us2f(ub[r * 4096 + 2048 + d]);
        float du = dlt * uu;
        float4 bq[4];
        #pragma unroll
        for (int q = 0; q < 4; ++q)
            bq[q] = *(const float4*)(xdbl + r * XDBL_LD + DT_RANK + q * 4);
        #pragma unroll
        for (int n = 0; n < 16; ++n) {
            float Bv = ((const float*)&bq[n >> 2])[n & 3];
            float dA = __expf(dlt * Av[n]);
            h[n] = h[n] * dA + du * Bv;
            ap[n] *= dA;
        }
    }
    float* pa = aprod + (size_t)chunk * (NCHG * 16) + (size_t)chg * 16;
    float* pf = hfin  + (size_t)chunk * (NCHG * 16) + (size_t)chg * 16;
    #pragma unroll
    for (int q = 0; q < 4; ++q) {
        *(float4*)(pa + q * 4) = make_float4(ap[q*4], ap[q*4+1], ap[q*4+2], ap[q*4+3]);
        *(float4*)(pf + q * 4) = make_float4(h[q*4], h[q*4+1], h[q*4+2], h[q*4+3]);
    }
}

__global__ __launch_bounds__(256)
void scan_phase2(float* __restrict__ aprod /* in: A, out: hin */,
                 const float* __restrict__ hfin)
{
    const int gid = blockIdx.x * 256 + threadIdx.x;
    float h = 0.f;
    for (int c = 0; c < NCHUNK; ++c) {
        const size_t idx = (size_t)c * (NCHG * 16) + gid;
        float a = aprod[idx];
        float f = hfin[idx];
        aprod[idx] = h;
        h = a * h + f;
    }
}

__global__ __launch_bounds__(256)
void scan_phase3(const float* __restrict__ delta0, const float* __restrict__ delta1,
                 unsigned short* __restrict__ ub0, unsigned short* __restrict__ ub1,
                 const float* __restrict__ xdbl0, const float* __restrict__ xdbl1,
                 const float* __restrict__ Alog0, const float* __restrict__ Alog1,
                 const float* __restrict__ Dsk0, const float* __restrict__ Dsk1,
                 const float* __restrict__ xz0, const float* __restrict__ xz1,
                 const float* __restrict__ hin)
{
    const int gid = blockIdx.x * 256 + threadIdx.x;
    const int chg = gid & (NCHG - 1);
    const int chunk = gid >> 13;
    const int dir = chg >> 12;
    const int bd = chg & 4095;
    const int b = bd >> 11, d = bd & 2047;
    const float* delta = dir ? delta1 : delta0;
    unsigned short* ub = dir ? ub1 : ub0;
    const float* xdbl = dir ? xdbl1 : xdbl0;
    const float* Alog = dir ? Alog1 : Alog0;
    const float* Dsk = dir ? Dsk1 : Dsk0;
    const float* xz = dir ? xz1 : xz0;

    float Av[16], h[16];
    const float* ph = hin + (size_t)chunk * (NCHG * 16) + (size_t)chg * 16;
    #pragma unroll
    for (int n = 0; n < 16; ++n) {
        Av[n] = -__expf(Alog[d * D_STATE + n]);
        h[n] = ph[n];
    }
    const float Dv = Dsk[d];
    const int t0 = chunk * CLEN;
    for (int t = t0; t < t0 + CLEN; ++t) {
        const size_t r = (size_t)b * SEQLEN + t;
        float dlt = delta[r * D_INNER + d];
        float uu = us2f(ub[r * 4096 + d]) + us2f(ub[r * 4096 + 2048 + d]);
        float du = dlt * uu;
        float4 bq[4], cq[4];
        #pragma unroll
        for (int q = 0; q < 4; ++q) {
            bq[q] = *(const float4*)(xdbl + r * XDBL_LD + DT_RANK + q * 4);
            cq[q] = *(const float4*)(xdbl + r * XDBL_LD + DT_RANK + D_STATE + q * 4);
        }
        float p0 = 0.f, p1 = 0.f, p2 = 0.f, p3 = 0.f;
        #pragma unroll
        for (int n = 0; n < 16; ++n) {
            float Bv = ((const float*)&bq[n >> 2])[n & 3];
            float Cv = ((const float*)&cq[n >> 2])[n & 3];
            float dA = __expf(dlt * Av[n]);
            h[n] = h[n] * dA + du * Bv;
            if ((n & 3) == 0) p0 += h[n] * Cv;
            else if ((n & 3) == 1) p1 += h[n] * Cv;
            else if ((n & 3) == 2) p2 += h[n] * Cv;
            else p3 += h[n] * Cv;
        }
        float y = ((p0 + p1) + (p2 + p3)) + uu * Dv;
        float zv = xz[r * (2 * D_INNER) + D_INNER + d];
        float v = y * (zv * sigmoidf_(zv));
        unsigned short hh, ll;
        hl_split(v, hh, ll);
        ub[r * 4096 + d] = hh;
        ub[r * 4096 + 2048 + d] = ll;
    }
}

// ---------------------------------------------------------------------------
extern "C" void kernel_launch(void* const* d_in, const int* in_sizes, int n_in,
                              void* d_out, int out_size, void* d_ws, size_t ws_size,
                              hipStream_t stream)
{
    const float* x = (const float*)d_in[0];
    const float* proj_W = (const float*)d_in[23];
    const float* proj_b = (const float*)d_in[24];
    float* out = (float*)d_out;

    const float *Win[2], *bin_[2], *convw[2], *convb[2], *Wx[2], *Wdt[2], *bdt[2],
                *Alog[2], *Dsk[2], *Wout[2], *bout[2];
    for (int dir = 0; dir < 2; ++dir) {
        const int base = 1 + dir * 11;
        Win[dir]   = (const float*)d_in[base + 0];
        bin_[dir]  = (const float*)d_in[base + 1];
        convw[dir] = (const float*)d_in[base + 2];
        convb[dir] = (const float*)d_in[base + 3];
        Wx[dir]    = (const float*)d_in[base + 4];
        Wdt[dir]   = (const float*)d_in[base + 5];
        bdt[dir]   = (const float*)d_in[base + 6];
        Alog[dir]  = (const float*)d_in[base + 7];
        Dsk[dir]   = (const float*)d_in[base + 8];
        Wout[dir]  = (const float*)d_in[base + 9];
        bout[dir]  = (const float*)d_in[base + 10];
    }

    // ---- explicit arena (lifetime-checked overlays; high-water ~184 MiB) ----
    char* ws = (char*)d_ws;
    const size_t MB = 1ull << 20;
    float* xz[2]            = {(float*)(ws + 0 * MB),   (float*)(ws + 32 * MB)};   // [0,64)
    unsigned short* ub[2]   = {(unsigned short*)(ws + 64 * MB),
                               (unsigned short*)(ws + 80 * MB)};                   // [64,96)
    unsigned short* Winb[2] = {(unsigned short*)(ws + 96 * MB),
                               (unsigned short*)(ws + 112 * MB)};                  // [96,128)
    unsigned short* xc0     = (unsigned short*)(ws + 128 * MB);                    // [128,136)
    // overlays:
    float* part             = (float*)(ws + 112 * MB);          // xproj partials after gemm1
    float* part2            = (float*)(ws + 0 * MB);            // after scan3 (xz dead)
    float* delta[2]         = {(float*)(ws + 112 * MB), (float*)(ws + 128 * MB)};
    unsigned short* Woutb[2]= {(unsigned short*)(ws + 96 * MB),
                               (unsigned short*)(ws + 104 * MB)};                  // in Winb0
    unsigned short* yzb[2]  = {ub[0], ub[1]};                   // in-place scan3
    unsigned short* tmpb    = ub[0];                            // after out-proj
    unsigned short* pWb     = ub[1];                            // after out-proj
    // smalls [144,150):
    unsigned short* Wxb[2]  = {(unsigned short*)(ws + 144 * MB), (unsigned short*)(ws + 145 * MB)};
    unsigned short* Wdtb[2] = {(unsigned short*)(ws + 146 * MB), (unsigned short*)(ws + 146 * MB + 512 * 1024)};
    unsigned short* dtb[2]  = {(unsigned short*)(ws + 147 * MB), (unsigned short*)(ws + 147 * MB + 512 * 1024)};
    float* xdbl[2]          = {(float*)(ws + 148 * MB), (float*)(ws + 149 * MB)};
    // scan buffers [150,184): [NCHUNK][NCHG][16] floats = 16.78 MB each
    float* aprod            = (float*)(ws + 150 * MB);          // becomes hin in phase2
    float* hfin             = (float*)(ws + 167 * MB);

    dim3 blk(256);

    // 1. prep1: all pre-GEMM splits (no flipped x)
    prep1_kernel<<<11008, blk, 0, stream>>>(
        x, Win[0], Win[1], Wx[0], Wx[1], Wdt[0], Wdt[1],
        xc0, Winb[0], Winb[1], Wxb[0], Wxb[1], Wdtb[0], Wdtb[1]);

    // 2. input proj (8-phase 256², DUALN: one A, N=8192 over both dirs;
    //    dir-1 rows written flipped in epilogue)
    gemm256<0, false, 16, true><<<dim3(32, 8, 1), dim3(512), 0, stream>>>(
        xc0, nullptr, Winb[0], Winb[1], bin_[0], bin_[1], xz[0], xz[1],
        nullptr, 4096, 8192, D_MODEL, 1);

    // 3. conv + silu -> ub hi/lo (z=0,1) and Wout splits (z=2)
    conv_prep_kernel<<<dim3((MROWS * D_INNER) / 256, 1, 3), blk, 0, stream>>>(
        xz[0], xz[1], convw[0], convw[1], convb[0], convb[1], ub[0], ub[1],
        Wout[0], Wout[1], Woutb[0], Woutb[1]);

    // 4. xproj split-K (128², nks=16, both dirs) -> part
    gemm_mfma<0, true><<<dim3(1, 16, 32), blk, 0, stream>>>(
        ub[0], ub[1], Wxb[0], Wxb[1], nullptr, nullptr, nullptr, nullptr,
        part, XDBL_LD, XDBL_LD, D_INNER, 16);

    // 5. reduce -> xdbl fp32 + dtb hi/lo (both dirs)
    reduce_xdbl_k<<<dim3(256, 1, 2), blk, 0, stream>>>(
        part, xdbl[0], xdbl[1], dtb[0], dtb[1]);

    // 6. dt proj (128², both dirs)
    gemm_mfma<1, false><<<dim3(16, 16, 2), blk, 0, stream>>>(
        dtb[0], dtb[1], Wdtb[0], Wdtb[1], bdt[0], bdt[1], delta[0], delta[1],
        nullptr, D_INNER, D_INNER, DT_RANK, 1);

    // 7-9. thread-per-channel chunked scan
    scan_phase1<<<NCHUNK * NCHG / 256, blk, 0, stream>>>(
        delta[0], delta[1], ub[0], ub[1], xdbl[0], xdbl[1], Alog[0], Alog[1],
        aprod, hfin);
    scan_phase2<<<NCHG * 16 / 256, blk, 0, stream>>>(aprod, hfin);
    scan_phase3<<<NCHUNK * NCHG / 256, blk, 0, stream>>>(
        delta[0], delta[1], ub[0], ub[1], xdbl[0], xdbl[1], Alog[0], Alog[1],
        Dsk[0], Dsk[1], xz[0], xz[1], aprod);

    // 10. out proj (8-phase 256², nks=4, both dirs) -> part2 [xz dead]
    gemm256<0, true, 8, false><<<dim3(4, 8, 8), dim3(512), 0, stream>>>(
        yzb[0], yzb[1], Woutb[0], Woutb[1], nullptr, nullptr, nullptr, nullptr,
        part2, D_MODEL, D_MODEL, D_INNER, 4);

    // 11. mid: reduce out-proj partials -> tmpb + split proj_W -> pWb
    mid_kernel<<<dim3(2048, 1, 3), blk, 0, stream>>>(
        part2, bout[0], bout[1], tmpb, proj_W, pWb);

    // 12. final proj (8-phase 256², nks=8) -> part2
    gemm256<0, true, 4, false><<<dim3(4, 8, 8), dim3(512), 0, stream>>>(
        tmpb, nullptr, pWb, nullptr, nullptr, nullptr, nullptr, nullptr,
        part2, D_MODEL, D_MODEL, 2 * D_MODEL, 8);

    // 13. reduce -> out
    reduce_out_k<<<2048, blk, 0, stream>>>(part2, proj_b, out);
}